// Round 21
// baseline (3056.666 us; speedup 1.0000x reference)
//
#include <hip/hip_runtime.h>
#include <math.h>

typedef unsigned short u16;
typedef __attribute__((ext_vector_type(8))) short short8;
typedef __attribute__((ext_vector_type(4))) short short4v;
typedef __attribute__((ext_vector_type(4))) float f32x4;

// ---------------- problem constants ----------------
constexpr int B_    = 32;
constexpr int HIST_ = 10, C_ = 11, H_ = 15, W_ = 20;
constexpr int D_    = 256, NH_ = 4, NL_ = 4, HD_ = 64;
constexpr int OUT_  = 256, ADIM_ = 20;
constexpr int L_    = HIST_*H_*W_ + 1;      // 3001
constexpr int VIS_  = HIST_*C_*H_*W_;       // 33000
constexpr int NTOK  = B_*L_;                // 96032
constexpr int OBSROW = VIS_ + ADIM_;        // 33020
constexpr int PADR  = 128;                  // pad rows so tile DMA stays in-bounds

// ---------------- bf16 helpers ----------------
__device__ __forceinline__ float bf2f(u16 u) {
    return __uint_as_float(((unsigned)u) << 16);
}
__device__ __forceinline__ u16 f2bf(float f) {
    unsigned u = __float_as_uint(f);
    u = u + 0x7FFFu + ((u >> 16) & 1u);
    return (u16)(u >> 16);
}
__device__ __forceinline__ f32x4 mfma16(short8 a, short8 b, f32x4 c) {
    return __builtin_amdgcn_mfma_f32_16x16x32_bf16(a, b, c, 0, 0, 0);
}
__device__ __forceinline__ void gload16(const u16* gsrc, u16* ldsdst) {
    __builtin_amdgcn_global_load_lds(
        (const __attribute__((address_space(1))) unsigned int*)gsrc,
        (__attribute__((address_space(3))) unsigned int*)ldsdst,
        16, 0, 0);
}
// tanh-form GELU: ~9 VALU ops (one v_exp). |err| <= ~3e-4.
__device__ __forceinline__ float gelu_fast(float v) {
    float t2 = 1.5957691216f*(v + 0.044715f*v*v*v);
    return v / (1.f + __expf(-t2));
}

// ---------------- setup kernels ----------------
__global__ void zero_kernel(float* __restrict__ p, int n) {
    int i = blockIdx.x*256 + threadIdx.x;
    if (i < n) p[i] = 0.f;
}

// dst[l][dstOff+n][k] = bf16(src[l][k][n]); dst layer stride dstLS
__global__ void wcvt_kernel(const float* __restrict__ src, u16* __restrict__ dst,
                            int Nn, int Kk, int dstLS, int dstOff) {
    int idx = blockIdx.x*256 + threadIdx.x;
    int tot = NL_*Nn*Kk;
    if (idx >= tot) return;
    int l = idx / (Nn*Kk);
    int rem = idx % (Nn*Kk);
    int n = rem / Kk, k = rem % Kk;
    dst[(size_t)l*dstLS + (size_t)(dstOff+n)*Kk + k] = f2bf(src[(size_t)l*Kk*Nn + (size_t)k*Nn + n]);
}

__global__ void rope_table_kernel(float* __restrict__ tab) {
    int idx = blockIdx.x*256 + threadIdx.x;
    if (idx >= L_*32) return;
    int t = idx >> 5, i = idx & 31;
    float freq = powf(10000.f, -2.f*(float)i/(float)HD_);
    float ang = (float)t * freq;
    tab[idx*2]   = cosf(ang);
    tab[idx*2+1] = sinf(ang);
}

// 4 tokens/block (1 per wave); lane owns 4 cols; float4 loads/stores.
__global__ __launch_bounds__(256) void proj_kernel(const float* __restrict__ obs,
        const float* __restrict__ pw, const float* __restrict__ pb,
        const float* __restrict__ cls, float* __restrict__ x) {
    int wave = threadIdx.x >> 6, lane = threadIdx.x & 63;
    int n = blockIdx.x*4 + wave;
    if (n >= NTOK) return;
    int b = n / L_, l = n % L_;
    float4 acc;
    if (l == 0) {
        acc = ((const float4*)cls)[lane];
    } else {
        int t = l - 1;
        int hist = t / (H_*W_);
        int rem  = t % (H_*W_);
        float vv = 0.f;
        if (lane < C_) vv = obs[(size_t)b*OBSROW + hist*(C_*H_*W_) + lane*(H_*W_) + rem];
        acc = ((const float4*)pb)[lane];
        #pragma unroll
        for (int c = 0; c < C_; ++c) {
            float vc = __shfl(vv, c);
            float4 w4 = ((const float4*)(pw + c*D_))[lane];
            acc.x += vc*w4.x; acc.y += vc*w4.y; acc.z += vc*w4.z; acc.w += vc*w4.w;
        }
    }
    ((float4*)(x + (size_t)n*D_))[lane] = acc;
}

// ---------------- LayerNorm fp32 -> bf16 (layer-0 LN1 per chunk) ----------------
__global__ __launch_bounds__(256) void ln_f2b_kernel(const float* __restrict__ in,
        const float* __restrict__ g, const float* __restrict__ bt,
        u16* __restrict__ out, int ntok) {
    int wave = threadIdx.x >> 6, lane = threadIdx.x & 63;
    int n = blockIdx.x*4 + wave;
    if (n >= ntok) return;
    float4 v = ((const float4*)(in + (size_t)n*D_))[lane];
    float s  = v.x + v.y + v.z + v.w;
    float sq = v.x*v.x + v.y*v.y + v.z*v.z + v.w*v.w;
    #pragma unroll
    for (int off = 32; off; off >>= 1) { s += __shfl_xor(s, off); sq += __shfl_xor(sq, off); }
    float mean = s * (1.f/D_);
    float var  = sq * (1.f/D_) - mean*mean;
    float r = rsqrtf(var + 1e-5f);
    float4 gg = ((const float4*)g)[lane];
    float4 bb = ((const float4*)bt)[lane];
    short4v o;
    o.x = (short)f2bf((v.x-mean)*r*gg.x + bb.x);
    o.y = (short)f2bf((v.y-mean)*r*gg.y + bb.y);
    o.z = (short)f2bf((v.z-mean)*r*gg.z + bb.z);
    o.w = (short)f2bf((v.w-mean)*r*gg.w + bb.w);
    *(short4v*)(out + (size_t)n*D_ + lane*4) = o;
}

// ---------------- fused LN + RoPE + SiLU (bf16 in-place, row stride ld) ----------------
__global__ __launch_bounds__(256) void lnrope_kernel(u16* __restrict__ q,
        const float* __restrict__ g, const float* __restrict__ bt,
        const float* __restrict__ tab, int ntok, int ld) {
    int wave = threadIdx.x >> 6, lane = threadIdx.x & 63;
    int n = blockIdx.x*4 + wave;
    if (n >= ntok) return;
    int l = n % L_;
    short4v raw = *(const short4v*)(q + (size_t)n*ld + lane*4);
    float v0 = bf2f((u16)raw.x), v1 = bf2f((u16)raw.y), v2 = bf2f((u16)raw.z), v3 = bf2f((u16)raw.w);
    float s  = v0+v1+v2+v3;
    float sq = v0*v0+v1*v1+v2*v2+v3*v3;
    #pragma unroll
    for (int off = 32; off; off >>= 1) { s += __shfl_xor(s, off); sq += __shfl_xor(sq, off); }
    float mean = s * (1.f/D_);
    float var  = sq * (1.f/D_) - mean*mean;
    float r = rsqrtf(var + 1e-5f);
    float4 gg = ((const float4*)g)[lane];
    float4 bb = ((const float4*)bt)[lane];
    float o0 = (v0-mean)*r*gg.x + bb.x;
    float o1 = (v1-mean)*r*gg.y + bb.y;
    float o2 = (v2-mean)*r*gg.z + bb.z;
    float o3 = (v3-mean)*r*gg.w + bb.w;
    float p0 = __shfl_xor(o0, 8), p1 = __shfl_xor(o1, 8);
    float p2 = __shfl_xor(o2, 8), p3 = __shfl_xor(o3, 8);
    bool first = (lane & 15) < 8;
    const float4* tp = (const float4*)(tab + ((size_t)l*32 + (lane&7)*4)*2);
    float4 t01 = tp[0], t23 = tp[1];
    float r0 = first ? o0*t01.x - p0*t01.y : o0*t01.x + p0*t01.y;
    float r1 = first ? o1*t01.z - p1*t01.w : o1*t01.z + p1*t01.w;
    float r2 = first ? o2*t23.x - p2*t23.y : o2*t23.x + p2*t23.y;
    float r3 = first ? o3*t23.z - p3*t23.w : o3*t23.z + p3*t23.w;
    r0 = r0 / (1.f + expf(-r0));
    r1 = r1 / (1.f + expf(-r1));
    r2 = r2 / (1.f + expf(-r2));
    r3 = r3 / (1.f + expf(-r3));
    short4v o;
    o.x = (short)f2bf(r0); o.y = (short)f2bf(r1);
    o.z = (short)f2bf(r2); o.w = (short)f2bf(r3);
    *(short4v*)(q + (size_t)n*ld + lane*4) = o;
}

// ---------------- bf16 MFMA GEMM (PROVEN core): 128x128, BK=64, single-buffer ----------------
// EPI: 0 bf16 out; 1 +bias,GELU,bf16; 4 +bias, bf16 out
template<int EPI, bool PB>
__global__ __launch_bounds__(256) void gemm_bf16(const u16* __restrict__ A, int lda,
        const u16* __restrict__ Wt, const float* __restrict__ bias,
        u16* __restrict__ Cb, float* __restrict__ Xres, int M, int N, int K, int ldc) {
    __shared__ u16 As[2*128*32];
    __shared__ u16 Bs[2*128*32];
    const int gx = gridDim.x;
    int n = blockIdx.y * gx + blockIdx.x;
    const int nwg = gx * gridDim.y;
    if ((nwg & 7) == 0) n = (n & 7) * (nwg >> 3) + (n >> 3);
    const int bx = n % gx, by = n / gx;
    const int row0 = by*128, col0 = bx*128;

    size_t zrow = 0;
    if (PB) {
        int z = blockIdx.z;
        A  += (size_t)z * M * lda;
        Wt += (size_t)z * N * K;
        zrow = (size_t)z * M;
    }

    const int tid = threadIdx.x;
    const int wid = tid >> 6, lane = tid & 63;
    const int wr = wid >> 1, wc = wid & 1;

    f32x4 acc[4][4];
    #pragma unroll
    for (int i = 0; i < 4; ++i)
        #pragma unroll
        for (int j = 0; j < 4; ++j) {
            f32x4 z; z.x = 0.f; z.y = 0.f; z.z = 0.f; z.w = 0.f;
            acc[i][j] = z;
        }

    const int r0s = wid*32 + (lane>>2);
    const int r1s = r0s + 16;
    const int s0 = ((lane&3) - (r0s>>1)) & 3;
    const int s1 = ((lane&3) - (r1s>>1)) & 3;
    const u16* a0p = A  + (size_t)(row0 + r0s)*lda + s0*8;
    const u16* a1p = A  + (size_t)(row0 + r1s)*lda + s1*8;
    const u16* b0p = Wt + (size_t)(col0 + r0s)*K + s0*8;
    const u16* b1p = Wt + (size_t)(col0 + r1s)*K + s1*8;
    u16* lA0 = As + (wid*2+0)*512;
    u16* lA1 = As + (wid*2+1)*512;
    u16* lB0 = Bs + (wid*2+0)*512;
    u16* lB1 = Bs + (wid*2+1)*512;

    const int kg = lane >> 4, li = lane & 15;
    int aoff[4], boff[4];
    #pragma unroll
    for (int mi = 0; mi < 4; ++mi) {
        int row = wr*64 + mi*16 + li;
        aoff[mi] = row*32 + ((kg + (row>>1)) & 3)*8;
    }
    #pragma unroll
    for (int ni = 0; ni < 4; ++ni) {
        int row = wc*64 + ni*16 + li;
        boff[ni] = row*32 + ((kg + (row>>1)) & 3)*8;
    }

    auto stage = [&](int k0) {
        #pragma unroll
        for (int t = 0; t < 2; ++t) {
            const int ko = k0 + t*32;
            const int lo = t*4096;
            gload16(a0p + ko, lA0 + lo); gload16(a1p + ko, lA1 + lo);
            gload16(b0p + ko, lB0 + lo); gload16(b1p + ko, lB1 + lo);
        }
    };

    stage(0);
    const int nk2 = K >> 6;
    for (int ks = 0; ks < nk2; ++ks) {
        __syncthreads();
        short8 af[2][4], bfr[2][4];
        #pragma unroll
        for (int t = 0; t < 2; ++t) {
            #pragma unroll
            for (int mi = 0; mi < 4; ++mi) af[t][mi] = *(const short8*)(As + t*4096 + aoff[mi]);
            #pragma unroll
            for (int ni = 0; ni < 4; ++ni) bfr[t][ni] = *(const short8*)(Bs + t*4096 + boff[ni]);
        }
        __syncthreads();
        if (ks + 1 < nk2) stage((ks + 1) << 6);
        #pragma unroll
        for (int t = 0; t < 2; ++t)
            #pragma unroll
            for (int mi = 0; mi < 4; ++mi)
                #pragma unroll
                for (int ni = 0; ni < 4; ++ni)
                    acc[mi][ni] = mfma16(af[t][mi], bfr[t][ni], acc[mi][ni]);
    }

    #pragma unroll
    for (int mi = 0; mi < 4; ++mi) {
        int rbase = row0 + wr*64 + mi*16 + kg*4;
        #pragma unroll
        for (int ni = 0; ni < 4; ++ni) {
            int col = col0 + wc*64 + ni*16 + li;
            #pragma unroll
            for (int r = 0; r < 4; ++r) {
                int row = rbase + r;
                if (row >= M) continue;
                float v = acc[mi][ni][r];
                if (EPI == 1 || EPI == 4) v += bias[col];
                if (EPI == 1) v = gelu_fast(v);
                Cb[(zrow + row)*(size_t)ldc + col] = f2bf(v);
            }
        }
    }
}

// ---------------- WIDE GEMM: 128x256 tile, 512 thr (used where grid stays large) ----------------
// Stat-free epilogues. BK=64 (2 subtiles), single-buffered (48 KB LDS).
// EPI: 0 bf16; 1 +bias,GELU.
template<int EPI, bool PB>
__global__ __launch_bounds__(512) void gemm_wide(const u16* __restrict__ A, int lda,
        const u16* __restrict__ Wt, const float* __restrict__ bias,
        u16* __restrict__ Cb, int M, int N, int K, int ldc) {
    __shared__ u16 As[2*4096];             // [subtile][128*32]
    __shared__ u16 Bs[2*8192];             // [subtile][256*32]
    const int gx = gridDim.x;
    int n = blockIdx.y * gx + blockIdx.x;
    const int nwg = gx * gridDim.y;
    if ((nwg & 7) == 0) n = (n & 7) * (nwg >> 3) + (n >> 3);
    const int bx = n % gx, by = n / gx;
    const int row0 = by*128, col0 = bx*256;

    size_t zrow = 0;
    if (PB) {
        int z = blockIdx.z;
        A  += (size_t)z * M * lda;
        Wt += (size_t)z * N * K;
        zrow = (size_t)z * M;
    }

    const int tid = threadIdx.x;
    const int wid = tid >> 6, lane = tid & 63;
    const int kg = lane >> 4, li = lane & 15;

    f32x4 acc[16];
    #pragma unroll
    for (int i = 0; i < 16; ++i) { f32x4 z; z.x=0.f; z.y=0.f; z.z=0.f; z.w=0.f; acc[i]=z; }

    const int ra = wid*16 + (lane>>2);
    const int sa = ((lane&3) - (ra>>1)) & 3;
    const u16* agp = A + (size_t)(row0 + ra)*lda + sa*8;
    const int lAo = wid*512;
    const int rb0 = (wid*2+0)*16 + (lane>>2);
    const int rb1 = (wid*2+1)*16 + (lane>>2);
    const int sb0 = ((lane&3) - (rb0>>1)) & 3;
    const int sb1 = ((lane&3) - (rb1>>1)) & 3;
    const u16* bgp0 = Wt + (size_t)(col0 + rb0)*K + sb0*8;
    const u16* bgp1 = Wt + (size_t)(col0 + rb1)*K + sb1*8;
    const int lB0o = (wid*2+0)*512;
    const int lB1o = (wid*2+1)*512;

    const int arow = wid*16 + li;
    const int aoff = arow*32 + ((kg + (arow>>1)) & 3)*8;
    int boff[16];
    #pragma unroll
    for (int ni = 0; ni < 16; ++ni) {
        int row = ni*16 + li;
        boff[ni] = row*32 + ((kg + (row>>1)) & 3)*8;
    }

    auto stage = [&](int k0) {
        #pragma unroll
        for (int t = 0; t < 2; ++t) {
            const int ko = k0 + t*32;
            gload16(agp  + ko, As + t*4096 + lAo);
            gload16(bgp0 + ko, Bs + t*8192 + lB0o);
            gload16(bgp1 + ko, Bs + t*8192 + lB1o);
        }
    };

    stage(0);
    const int nk2 = K >> 6;
    for (int ks = 0; ks < nk2; ++ks) {
        __syncthreads();                    // DMA for this 64-K tile drained
        short8 af0 = *(const short8*)(As + aoff);
        short8 b0[8], b1[8];
        #pragma unroll
        for (int ni = 0; ni < 8; ++ni) b0[ni] = *(const short8*)(Bs + boff[ni]);
        #pragma unroll
        for (int ni = 0; ni < 8; ++ni) acc[ni] = mfma16(af0, b0[ni], acc[ni]);
        #pragma unroll
        for (int ni = 0; ni < 8; ++ni) b1[ni] = *(const short8*)(Bs + boff[8+ni]);
        #pragma unroll
        for (int ni = 0; ni < 8; ++ni) acc[8+ni] = mfma16(af0, b1[ni], acc[8+ni]);
        short8 af1 = *(const short8*)(As + 4096 + aoff);
        #pragma unroll
        for (int ni = 0; ni < 8; ++ni) b0[ni] = *(const short8*)(Bs + 8192 + boff[ni]);
        #pragma unroll
        for (int ni = 0; ni < 8; ++ni) b1[ni] = *(const short8*)(Bs + 8192 + boff[8+ni]);
        __syncthreads();                    // reads done; LDS reusable
        if (ks + 1 < nk2) stage((ks + 1) << 6);
        #pragma unroll
        for (int ni = 0; ni < 8; ++ni) acc[ni]   = mfma16(af1, b0[ni], acc[ni]);
        #pragma unroll
        for (int ni = 0; ni < 8; ++ni) acc[8+ni] = mfma16(af1, b1[ni], acc[8+ni]);
    }

    #pragma unroll
    for (int r = 0; r < 4; ++r) {
        const int row = row0 + wid*16 + kg*4 + r;
        if (row >= M) continue;
        #pragma unroll
        for (int ni = 0; ni < 16; ++ni) {
            int col = col0 + ni*16 + li;
            float v = acc[ni][r];
            if (EPI == 1) { v += bias[col]; v = gelu_fast(v); }
            Cb[(zrow + row)*(size_t)ldc + col] = f2bf(v);
        }
    }
}

// ---------------- FUSED GEMM+RES+LN: 64x256 tile, 256 thr, 4 waves ----------------
// Each wave owns 16 FULL rows (kg*4+r) x 256 cols -> row stats need only
// in-thread sum + 16-lane shfl (same lane group shares a row). N must be 256,
// gridDim.x == 1. Epilogue: [+bias] ; x += v (fp32 RMW) ; Xn = LN(x) bf16.
// EPI: 5 = no bias; 6 = +bias. PB: per-batch (proven offset logic).
template<int EPI, bool PB>
__global__ __launch_bounds__(256) void gemm_w64(const u16* __restrict__ A, int lda,
        const u16* __restrict__ Wt, const float* __restrict__ bias,
        float* __restrict__ Xres, u16* __restrict__ Xn,
        const float* __restrict__ g, const float* __restrict__ bt,
        int M, int K) {
    __shared__ u16 As[2*2048];             // [subtile][64*32]
    __shared__ u16 Bs[2*8192];             // [subtile][256*32]
    const int by = blockIdx.y;
    const int row0 = by*64, col0 = 0;

    size_t zrow = 0;
    if (PB) {
        int z = blockIdx.z;
        A  += (size_t)z * M * lda;
        Wt += (size_t)z * 256 * K;
        zrow = (size_t)z * M;
    }

    const int tid = threadIdx.x;
    const int wid = tid >> 6, lane = tid & 63;
    const int kg = lane >> 4, li = lane & 15;

    f32x4 acc[16];
    #pragma unroll
    for (int i = 0; i < 16; ++i) { f32x4 z; z.x=0.f; z.y=0.f; z.z=0.f; z.w=0.f; acc[i]=z; }

    // A staging: 4 instrs (1/wave) cover 64 rows x 32
    const int ra = wid*16 + (lane>>2);
    const int sa = ((lane&3) - (ra>>1)) & 3;
    const u16* agp = A + (size_t)(row0 + ra)*lda + sa*8;
    const int lAo = wid*512;
    // B staging: 16 instrs (4/wave) cover 256 rows x 32
    const u16* bgp[4];
    int lBo[4];
    #pragma unroll
    for (int i = 0; i < 4; ++i) {
        int rb = (wid*4+i)*16 + (lane>>2);
        int sb = ((lane&3) - (rb>>1)) & 3;
        bgp[i] = Wt + (size_t)(col0 + rb)*K + sb*8;
        lBo[i] = (wid*4+i)*512;
    }

    const int arow = wid*16 + li;
    const int aoff = arow*32 + ((kg + (arow>>1)) & 3)*8;
    int boff[16];
    #pragma unroll
    for (int ni = 0; ni < 16; ++ni) {
        int row = ni*16 + li;
        boff[ni] = row*32 + ((kg + (row>>1)) & 3)*8;
    }

    auto stage = [&](int k0) {
        #pragma unroll
        for (int t = 0; t < 2; ++t) {
            const int ko = k0 + t*32;
            gload16(agp + ko, As + t*2048 + lAo);
            #pragma unroll
            for (int i = 0; i < 4; ++i)
                gload16(bgp[i] + ko, Bs + t*8192 + lBo[i]);
        }
    };

    stage(0);
    const int nk2 = K >> 6;
    for (int ks = 0; ks < nk2; ++ks) {
        __syncthreads();                    // DMA for this 64-K tile drained
        short8 af0 = *(const short8*)(As + aoff);
        short8 b0[8], b1[8];
        #pragma unroll
        for (int ni = 0; ni < 8; ++ni) b0[ni] = *(const short8*)(Bs + boff[ni]);
        #pragma unroll
        for (int ni = 0; ni < 8; ++ni) acc[ni] = mfma16(af0, b0[ni], acc[ni]);
        #pragma unroll
        for (int ni = 0; ni < 8; ++ni) b1[ni] = *(const short8*)(Bs + boff[8+ni]);
        #pragma unroll
        for (int ni = 0; ni < 8; ++ni) acc[8+ni] = mfma16(af0, b1[ni], acc[8+ni]);
        short8 af1 = *(const short8*)(As + 2048 + aoff);
        #pragma unroll
        for (int ni = 0; ni < 8; ++ni) b0[ni] = *(const short8*)(Bs + 8192 + boff[ni]);
        #pragma unroll
        for (int ni = 0; ni < 8; ++ni) b1[ni] = *(const short8*)(Bs + 8192 + boff[8+ni]);
        __syncthreads();                    // reads done; LDS reusable
        if (ks + 1 < nk2) stage((ks + 1) << 6);
        #pragma unroll
        for (int ni = 0; ni < 8; ++ni) acc[ni]   = mfma16(af1, b0[ni], acc[ni]);
        #pragma unroll
        for (int ni = 0; ni < 8; ++ni) acc[8+ni] = mfma16(af1, b1[ni], acc[8+ni]);
    }

    // ---- fused epilogue: bias -> x RMW (fp32) -> row LN -> Xn (bf16) ----
    #pragma unroll
    for (int r = 0; r < 4; ++r) {
        const int row = row0 + wid*16 + kg*4 + r;
        const bool ok = row < M;
        float vv[16];
        float s = 0.f, sq = 0.f;
        #pragma unroll
        for (int ni = 0; ni < 16; ++ni) {
            int col = ni*16 + li;
            float v = acc[ni][r];
            if (EPI == 6) v += bias[col];
            if (ok) {
                size_t xi = (zrow + row)*(size_t)256 + col;
                v += Xres[xi];
                Xres[xi] = v;
            }
            vv[ni] = v;
            s += v; sq += v*v;
        }
        // reduce across the 16 lanes (same kg group = same row)
        s += __shfl_xor(s, 1); sq += __shfl_xor(sq, 1);
        s += __shfl_xor(s, 2); sq += __shfl_xor(sq, 2);
        s += __shfl_xor(s, 4); sq += __shfl_xor(sq, 4);
        s += __shfl_xor(s, 8); sq += __shfl_xor(sq, 8);
        float mean = s * (1.f/256.f);
        float var  = sq * (1.f/256.f) - mean*mean;
        float rstd = rsqrtf(var + 1e-5f);
        if (ok) {
            #pragma unroll
            for (int ni = 0; ni < 16; ++ni) {
                int col = ni*16 + li;
                float xn = (vv[ni] - mean)*rstd*g[col] + bt[col];
                Xn[(zrow + row)*(size_t)256 + col] = f2bf(xn);
            }
        }
    }
}

// ---------------- kv = K^T V per (b,h) via MFMA (atomic merge, proven) ----------------
constexpr int KV_LSPLIT = 4;
constexpr int KV_PART   = 768;            // 24 tiles of 32; 4*768 >= L_
__global__ __launch_bounds__(256) void kv_mfma_kernel(const u16* __restrict__ Kt,
        const u16* __restrict__ Vt, float* __restrict__ kvf, int ld) {
    __shared__ u16 kT[64][34];            // [d][l'] transposed, pad 2
    __shared__ u16 vT[64][34];
    const int bh = blockIdx.x;
    const int b = bh >> 2, h = bh & 3;
    const int tid = threadIdx.x;
    const int wid = tid >> 6, lane = tid & 63;
    const int kg = lane >> 4, li = lane & 15;
    const int wm = (wid >> 1)*32, wn = (wid & 1)*32;
    const int sl = tid >> 3;              // 0..31
    const int sd = (tid & 7) * 8;
    const u16* kbase = Kt + ((size_t)b*L_)*ld + h*HD_ + sd;
    const u16* vbase = Vt + ((size_t)b*L_)*ld + h*HD_ + sd;

    f32x4 acc[2][2];
    #pragma unroll
    for (int i = 0; i < 2; ++i)
        #pragma unroll
        for (int j = 0; j < 2; ++j) {
            f32x4 z; z.x=0.f; z.y=0.f; z.z=0.f; z.w=0.f; acc[i][j] = z;
        }

    const int l0p = blockIdx.y * KV_PART;
    for (int t = 0; t < KV_PART/32; ++t) {
        int gl = l0p + t*32 + sl;
        short8 kk = {0,0,0,0,0,0,0,0}, vv = {0,0,0,0,0,0,0,0};
        if (gl < L_) {
            kk = *(const short8*)(kbase + (size_t)gl*ld);
            vv = *(const short8*)(vbase + (size_t)gl*ld);
        }
        __syncthreads();
        #pragma unroll
        for (int j = 0; j < 8; ++j) {
            kT[sd+j][sl] = (u16)kk[j];
            vT[sd+j][sl] = (u16)vv[j];
        }
        __syncthreads();
        short8 a0, a1, b0, b1;
        {
            uint* d0 = (uint*)&a0; const uint* p0 = (const uint*)&kT[wm + li][kg*8];
            uint* d1 = (uint*)&a1; const uint* p1 = (const uint*)&kT[wm + 16 + li][kg*8];
            uint* d2 = (uint*)&b0; const uint* p2 = (const uint*)&vT[wn + li][kg*8];
            uint* d3 = (uint*)&b1; const uint* p3 = (const uint*)&vT[wn + 16 + li][kg*8];
            #pragma unroll
            for (int j = 0; j < 4; ++j) { d0[j]=p0[j]; d1[j]=p1[j]; d2[j]=p2[j]; d3[j]=p3[j]; }
        }
        acc[0][0] = mfma16(a0, b0, acc[0][0]);
        acc[0][1] = mfma16(a0, b1, acc[0][1]);
        acc[1][0] = mfma16(a1, b0, acc[1][0]);
        acc[1][1] = mfma16(a1, b1, acc[1][1]);
    }
    float* base = kvf + (size_t)bh*4096;
    #pragma unroll
    for (int mi = 0; mi < 2; ++mi)
        #pragma unroll
        for (int ni = 0; ni < 2; ++ni)
            #pragma unroll
            for (int r = 0; r < 4; ++r)
                atomicAdd(base + (wm + mi*16 + kg*4 + r)*64 + wn + ni*16 + li,
                          acc[mi][ni][r]);
}

// ---------------- M2T[b][n][h*64+d] = bf16( (1/8) sum_e kv[b,h,d,e] * ow[h*64+e][n] ) ----------------
__global__ __launch_bounds__(256) void m2_kernel(const float* __restrict__ kvf,
        const float* __restrict__ ow, u16* __restrict__ m2t) {
    __shared__ float kvs[64][64];
    const int bh = blockIdx.x;
    const int b = bh >> 2, h = bh & 3;
    const int tid = threadIdx.x;          // n = tid
    #pragma unroll
    for (int p = 0; p < 16; ++p)
        ((float*)kvs)[p*256 + tid] = kvf[(size_t)bh*4096 + p*256 + tid];
    __syncthreads();
    float acc[64];
    #pragma unroll
    for (int d = 0; d < 64; ++d) acc[d] = 0.f;
    for (int e = 0; e < 64; ++e) {
        float w = ow[(size_t)(h*64 + e)*256 + tid];
        #pragma unroll
        for (int d = 0; d < 64; ++d) acc[d] += kvs[d][e] * w;
    }
    u16* dst = m2t + ((size_t)b*256 + tid)*256 + h*64;
    #pragma unroll
    for (int d = 0; d < 64; ++d) dst[d] = f2bf(acc[d]*0.125f);
}

// ---------------- head ----------------
__global__ void head_kernel(const float* __restrict__ x, const float* __restrict__ obs,
                            const float* __restrict__ fng, const float* __restrict__ fnb,
                            const float* __restrict__ ow, const float* __restrict__ ob,
                            float* __restrict__ out) {
    __shared__ float row[D_ + ADIM_];
    __shared__ float red[8];
    int b = blockIdx.x, tid = threadIdx.x;
    float v = x[((size_t)b*L_)*D_ + tid];
    float s = v, sq = v*v;
    #pragma unroll
    for (int off = 32; off; off >>= 1) { s += __shfl_xor(s, off); sq += __shfl_xor(sq, off); }
    int wave = tid >> 6, lane = tid & 63;
    if (lane == 0) { red[wave] = s; red[4+wave] = sq; }
    __syncthreads();
    s  = red[0]+red[1]+red[2]+red[3];
    sq = red[4]+red[5]+red[6]+red[7];
    float mean = s*(1.f/D_), var = sq*(1.f/D_) - mean*mean;
    float r = rsqrtf(var + 1e-5f);
    row[tid] = (v-mean)*r*fng[tid] + fnb[tid];
    if (tid < ADIM_) row[D_+tid] = obs[(size_t)b*OBSROW + VIS_ + tid];
    __syncthreads();
    float acc = ob[tid];
    for (int j = 0; j < D_+ADIM_; ++j) acc += row[j]*ow[j*OUT_ + tid];
    out[(size_t)b*OUT_ + tid] = acc;
}

// ---------------- launch ----------------
extern "C" void kernel_launch(void* const* d_in, const int* in_sizes, int n_in,
                              void* d_out, int out_size, void* d_ws, size_t ws_size,
                              hipStream_t stream) {
    const float* obs   = (const float*)d_in[0];
    const float* pw    = (const float*)d_in[1];
    const float* pb    = (const float*)d_in[2];
    const float* cls   = (const float*)d_in[3];
    const float* qw    = (const float*)d_in[4];
    const float* kw    = (const float*)d_in[5];
    const float* vw    = (const float*)d_in[6];
    const float* oww   = (const float*)d_in[7];
    const float* gq    = (const float*)d_in[8];
    const float* bq    = (const float*)d_in[9];
    const float* gk    = (const float*)d_in[10];
    const float* bk    = (const float*)d_in[11];
    const float* n1g   = (const float*)d_in[12];
    const float* n1b   = (const float*)d_in[13];
    const float* n2g   = (const float*)d_in[14];
    const float* n2b   = (const float*)d_in[15];
    const float* w1    = (const float*)d_in[16];
    const float* b1    = (const float*)d_in[17];
    const float* w2    = (const float*)d_in[18];
    const float* b2    = (const float*)d_in[19];
    const float* fng   = (const float*)d_in[20];
    const float* fnb   = (const float*)d_in[21];
    const float* outw  = (const float*)d_in[22];
    const float* outb  = (const float*)d_in[23];

    // ---- workspace layout ----
    float* x = (float*)d_ws;                               // NTOK*256 fp32
    u16* qkvT = (u16*)(x + (size_t)NTOK*D_);               // [NL][768][256]
    u16* w1T  = qkvT + (size_t)NL_*768*256;                // [NL][1024][256]
    u16* w2T  = w1T  + (size_t)NL_*262144;                 // [NL][256][1024]
    float* tab = (float*)(w2T + (size_t)NL_*262144);       // L*32*2 fp32
    u16* bufs = (u16*)(tab + (size_t)L_*32*2);

    size_t fixedB = (size_t)((char*)bufs - (char*)d_ws);
    auto needed = [&](int nb) -> size_t {
        size_t t = (size_t)nb * L_;
        return fixedB + (t*256 + (size_t)PADR*256)*2 + (t*1024 + (size_t)PADR*1024)*2
               + (size_t)nb*65536*2 + (size_t)nb*NH_*4096*4;
    };
    int nbc = 32;
    while (nbc > 1 && needed(nbc) > ws_size) nbc >>= 1;
    const int nch = B_ / nbc;
    const int RCn = nbc * L_;

    u16* Xn   = bufs;                                           // nb*L*256 (+pad)
    u16* QKVc = Xn + (size_t)RCn*256 + (size_t)PADR*256;        // ld=768 view
    u16* Hc   = QKVc;                                           // ld=1024 view (same region)
    u16* M2T  = QKVc + (size_t)RCn*1024 + (size_t)PADR*1024;    // nb*256*256
    float* kvf = (float*)(M2T + (size_t)nbc*65536);             // nb*4*4096 f32

    // ---- setup ----
    wcvt_kernel<<<(NL_*65536 + 255)/256, 256, 0, stream>>>(qw,  qkvT, 256, 256, 768*256, 0);
    wcvt_kernel<<<(NL_*65536 + 255)/256, 256, 0, stream>>>(kw,  qkvT, 256, 256, 768*256, 256);
    wcvt_kernel<<<(NL_*65536 + 255)/256, 256, 0, stream>>>(vw,  qkvT, 256, 256, 768*256, 512);
    wcvt_kernel<<<(NL_*262144 + 255)/256, 256, 0, stream>>>(w1, w1T, 1024, 256, 262144, 0);
    wcvt_kernel<<<(NL_*262144 + 255)/256, 256, 0, stream>>>(w2, w2T, 256, 1024, 262144, 0);
    rope_table_kernel<<<(L_*32 + 255)/256, 256, 0, stream>>>(tab);
    proj_kernel<<<(NTOK + 3)/4, 256, 0, stream>>>(obs, pw, pb, cls, x);

    const int gy  = (RCn + 127)/128;
    const int gy64 = (RCn + 63)/64;
    const int gy64b = (L_ + 63)/64;        // 47
    const int lnb = (RCn + 3)/4;
    const int nbh = nbc*NH_;

    // chunk OUTER, layer INNER: all Xn/QKVc/Hc/M2T/kvf state is consumed within
    // one chunk iteration, so the cross-layer Xn carry is race-free.
    for (int c = 0; c < nch; ++c) {
        float* xc = x + (size_t)c*RCn*D_;
        ln_f2b_kernel<<<lnb, 256, 0, stream>>>(xc, n1g, n1b, Xn, RCn);

        for (int layer = 0; layer < NL_; ++layer) {
            const u16* qkvT_l = qkvT + (size_t)layer*768*256;
            const u16* w1T_l  = w1T  + (size_t)layer*262144;
            const u16* w2T_l  = w2T  + (size_t)layer*262144;
            const float* ow_l = oww + (size_t)layer*65536;
            const float* b1_l = b1 + (size_t)layer*1024;
            const float* b2_l = b2 + (size_t)layer*D_;

            // QKV: wide tile (3 x 256-col tiles, large grid)
            gemm_wide<0,false><<<dim3(3, gy), 512, 0, stream>>>(Xn, 256, qkvT_l, nullptr, QKVc, RCn, 768, 256, 768);
            lnrope_kernel<<<lnb, 256, 0, stream>>>(QKVc,       gq + layer*D_, bq + layer*D_, tab, RCn, 768);
            lnrope_kernel<<<lnb, 256, 0, stream>>>(QKVc + 256, gk + layer*D_, bk + layer*D_, tab, RCn, 768);
            zero_kernel<<<(nbh*4096 + 255)/256, 256, 0, stream>>>(kvf, nbh*4096);
            kv_mfma_kernel<<<dim3(nbh, KV_LSPLIT), 256, 0, stream>>>(QKVc + 256, QKVc + 512, kvf, 768);
            m2_kernel<<<nbh, 256, 0, stream>>>(kvf, ow_l, M2T);
            // attn+O-proj FUSED: x += Q @ M2T^T (fp32 RMW); Xn = LN2(x)
            gemm_w64<5,true><<<dim3(1, gy64b, nbc), 256, 0, stream>>>(QKVc, 768, M2T, nullptr, xc, Xn, n2g + layer*D_, n2b + layer*D_, L_, 256);
            // MLP: W1 wide (+bias,GELU) -> Hc; W2 FUSED: x += Hc@W2^T + b2; Xn = LN1(next)
            gemm_wide<1,false><<<dim3(4, gy), 512, 0, stream>>>(Xn, 256, w1T_l, b1_l, Hc, RCn, 1024, 256, 1024);
            const float* gN = (layer < NL_-1) ? (n1g + (layer+1)*D_) : fng;
            const float* bN = (layer < NL_-1) ? (n1b + (layer+1)*D_) : fnb;
            gemm_w64<6,false><<<dim3(1, gy64), 256, 0, stream>>>(Hc, 1024, w2T_l, b2_l, xc, Xn, gN, bN, RCn, 1024);
        }
    }

    head_kernel<<<B_, 256, 0, stream>>>(x, obs, fng, fnb, outw, outb, (float*)d_out);
}

// Round 22
// 2488.419 us; speedup vs baseline: 1.2284x; 1.2284x over previous
//
#include <hip/hip_runtime.h>
#include <math.h>

typedef unsigned short u16;
typedef __attribute__((ext_vector_type(8))) short short8;
typedef __attribute__((ext_vector_type(4))) short short4v;
typedef __attribute__((ext_vector_type(4))) float f32x4;

// ---------------- problem constants ----------------
constexpr int B_    = 32;
constexpr int HIST_ = 10, C_ = 11, H_ = 15, W_ = 20;
constexpr int D_    = 256, NH_ = 4, NL_ = 4, HD_ = 64;
constexpr int OUT_  = 256, ADIM_ = 20;
constexpr int L_    = HIST_*H_*W_ + 1;      // 3001
constexpr int VIS_  = HIST_*C_*H_*W_;       // 33000
constexpr int NTOK  = B_*L_;                // 96032
constexpr int OBSROW = VIS_ + ADIM_;        // 33020
constexpr int PADR  = 128;                  // pad rows so tile DMA stays in-bounds

// ---------------- bf16 helpers ----------------
__device__ __forceinline__ float bf2f(u16 u) {
    return __uint_as_float(((unsigned)u) << 16);
}
__device__ __forceinline__ u16 f2bf(float f) {
    unsigned u = __float_as_uint(f);
    u = u + 0x7FFFu + ((u >> 16) & 1u);
    return (u16)(u >> 16);
}
__device__ __forceinline__ f32x4 mfma16(short8 a, short8 b, f32x4 c) {
    return __builtin_amdgcn_mfma_f32_16x16x32_bf16(a, b, c, 0, 0, 0);
}
__device__ __forceinline__ void gload16(const u16* gsrc, u16* ldsdst) {
    __builtin_amdgcn_global_load_lds(
        (const __attribute__((address_space(1))) unsigned int*)gsrc,
        (__attribute__((address_space(3))) unsigned int*)ldsdst,
        16, 0, 0);
}
// tanh-form GELU: ~9 VALU ops (one v_exp). |err| <= ~3e-4.
__device__ __forceinline__ float gelu_fast(float v) {
    float t2 = 1.5957691216f*(v + 0.044715f*v*v*v);
    return v / (1.f + __expf(-t2));
}

// ---------------- setup kernels ----------------
__global__ void zero_kernel(float* __restrict__ p, int n) {
    int i = blockIdx.x*256 + threadIdx.x;
    if (i < n) p[i] = 0.f;
}

// dst[l][dstOff+n][k] = bf16(src[l][k][n]); dst layer stride dstLS
__global__ void wcvt_kernel(const float* __restrict__ src, u16* __restrict__ dst,
                            int Nn, int Kk, int dstLS, int dstOff) {
    int idx = blockIdx.x*256 + threadIdx.x;
    int tot = NL_*Nn*Kk;
    if (idx >= tot) return;
    int l = idx / (Nn*Kk);
    int rem = idx % (Nn*Kk);
    int n = rem / Kk, k = rem % Kk;
    dst[(size_t)l*dstLS + (size_t)(dstOff+n)*Kk + k] = f2bf(src[(size_t)l*Kk*Nn + (size_t)k*Nn + n]);
}

__global__ void rope_table_kernel(float* __restrict__ tab) {
    int idx = blockIdx.x*256 + threadIdx.x;
    if (idx >= L_*32) return;
    int t = idx >> 5, i = idx & 31;
    float freq = powf(10000.f, -2.f*(float)i/(float)HD_);
    float ang = (float)t * freq;
    tab[idx*2]   = cosf(ang);
    tab[idx*2+1] = sinf(ang);
}

// 4 tokens/block (1 per wave); lane owns 4 cols; float4 loads/stores.
__global__ __launch_bounds__(256) void proj_kernel(const float* __restrict__ obs,
        const float* __restrict__ pw, const float* __restrict__ pb,
        const float* __restrict__ cls, float* __restrict__ x) {
    int wave = threadIdx.x >> 6, lane = threadIdx.x & 63;
    int n = blockIdx.x*4 + wave;
    if (n >= NTOK) return;
    int b = n / L_, l = n % L_;
    float4 acc;
    if (l == 0) {
        acc = ((const float4*)cls)[lane];
    } else {
        int t = l - 1;
        int hist = t / (H_*W_);
        int rem  = t % (H_*W_);
        float vv = 0.f;
        if (lane < C_) vv = obs[(size_t)b*OBSROW + hist*(C_*H_*W_) + lane*(H_*W_) + rem];
        acc = ((const float4*)pb)[lane];
        #pragma unroll
        for (int c = 0; c < C_; ++c) {
            float vc = __shfl(vv, c);
            float4 w4 = ((const float4*)(pw + c*D_))[lane];
            acc.x += vc*w4.x; acc.y += vc*w4.y; acc.z += vc*w4.z; acc.w += vc*w4.w;
        }
    }
    ((float4*)(x + (size_t)n*D_))[lane] = acc;
}

// ---------------- LayerNorm fp32 -> bf16 (layer-0 LN1 per chunk) ----------------
__global__ __launch_bounds__(256) void ln_f2b_kernel(const float* __restrict__ in,
        const float* __restrict__ g, const float* __restrict__ bt,
        u16* __restrict__ out, int ntok) {
    int wave = threadIdx.x >> 6, lane = threadIdx.x & 63;
    int n = blockIdx.x*4 + wave;
    if (n >= ntok) return;
    float4 v = ((const float4*)(in + (size_t)n*D_))[lane];
    float s  = v.x + v.y + v.z + v.w;
    float sq = v.x*v.x + v.y*v.y + v.z*v.z + v.w*v.w;
    #pragma unroll
    for (int off = 32; off; off >>= 1) { s += __shfl_xor(s, off); sq += __shfl_xor(sq, off); }
    float mean = s * (1.f/D_);
    float var  = sq * (1.f/D_) - mean*mean;
    float r = rsqrtf(var + 1e-5f);
    float4 gg = ((const float4*)g)[lane];
    float4 bb = ((const float4*)bt)[lane];
    short4v o;
    o.x = (short)f2bf((v.x-mean)*r*gg.x + bb.x);
    o.y = (short)f2bf((v.y-mean)*r*gg.y + bb.y);
    o.z = (short)f2bf((v.z-mean)*r*gg.z + bb.z);
    o.w = (short)f2bf((v.w-mean)*r*gg.w + bb.w);
    *(short4v*)(out + (size_t)n*D_ + lane*4) = o;
}

// ---------------- residual add + LayerNorm: x += delta(bf16); Xn = LN(x) ----------------
// CHUNK-LOCAL only — safe under nch>1 with the chunk-OUTER loop.
__global__ __launch_bounds__(256) void lnres_kernel(float* __restrict__ x,
        u16* __restrict__ dx, const float* __restrict__ g, const float* __restrict__ bt,
        int ntok) {
    int wave = threadIdx.x >> 6, lane = threadIdx.x & 63;
    int n = blockIdx.x*4 + wave;
    if (n >= ntok) return;
    float4 v = ((const float4*)(x + (size_t)n*D_))[lane];
    short4v d = *(const short4v*)(dx + (size_t)n*D_ + lane*4);
    v.x += bf2f((u16)d.x); v.y += bf2f((u16)d.y);
    v.z += bf2f((u16)d.z); v.w += bf2f((u16)d.w);
    ((float4*)(x + (size_t)n*D_))[lane] = v;
    float s  = v.x + v.y + v.z + v.w;
    float sq = v.x*v.x + v.y*v.y + v.z*v.z + v.w*v.w;
    #pragma unroll
    for (int off = 32; off; off >>= 1) { s += __shfl_xor(s, off); sq += __shfl_xor(sq, off); }
    float mean = s * (1.f/D_);
    float var  = sq * (1.f/D_) - mean*mean;
    float r = rsqrtf(var + 1e-5f);
    float4 gg = ((const float4*)g)[lane];
    float4 bb = ((const float4*)bt)[lane];
    short4v o;
    o.x = (short)f2bf((v.x-mean)*r*gg.x + bb.x);
    o.y = (short)f2bf((v.y-mean)*r*gg.y + bb.y);
    o.z = (short)f2bf((v.z-mean)*r*gg.z + bb.z);
    o.w = (short)f2bf((v.w-mean)*r*gg.w + bb.w);
    *(short4v*)(dx + (size_t)n*D_ + lane*4) = o;
}

// ---------------- fused LN + RoPE + SiLU (merged Q/K: blockIdx.y selects) ----------------
__global__ __launch_bounds__(256) void lnrope_kernel(u16* __restrict__ qk,
        const float* __restrict__ gq, const float* __restrict__ bq,
        const float* __restrict__ gk, const float* __restrict__ bk,
        const float* __restrict__ tab, int ntok, int ld) {
    u16* q = qk + blockIdx.y*256;                  // y=0 -> Q, y=1 -> K
    const float* g  = blockIdx.y ? gk : gq;
    const float* bt = blockIdx.y ? bk : bq;
    int wave = threadIdx.x >> 6, lane = threadIdx.x & 63;
    int n = blockIdx.x*4 + wave;
    if (n >= ntok) return;
    int l = n % L_;
    short4v raw = *(const short4v*)(q + (size_t)n*ld + lane*4);
    float v0 = bf2f((u16)raw.x), v1 = bf2f((u16)raw.y), v2 = bf2f((u16)raw.z), v3 = bf2f((u16)raw.w);
    float s  = v0+v1+v2+v3;
    float sq = v0*v0+v1*v1+v2*v2+v3*v3;
    #pragma unroll
    for (int off = 32; off; off >>= 1) { s += __shfl_xor(s, off); sq += __shfl_xor(sq, off); }
    float mean = s * (1.f/D_);
    float var  = sq * (1.f/D_) - mean*mean;
    float r = rsqrtf(var + 1e-5f);
    float4 gg = ((const float4*)g)[lane];
    float4 bb = ((const float4*)bt)[lane];
    float o0 = (v0-mean)*r*gg.x + bb.x;
    float o1 = (v1-mean)*r*gg.y + bb.y;
    float o2 = (v2-mean)*r*gg.z + bb.z;
    float o3 = (v3-mean)*r*gg.w + bb.w;
    float p0 = __shfl_xor(o0, 8), p1 = __shfl_xor(o1, 8);
    float p2 = __shfl_xor(o2, 8), p3 = __shfl_xor(o3, 8);
    bool first = (lane & 15) < 8;
    const float4* tp = (const float4*)(tab + ((size_t)l*32 + (lane&7)*4)*2);
    float4 t01 = tp[0], t23 = tp[1];
    float r0 = first ? o0*t01.x - p0*t01.y : o0*t01.x + p0*t01.y;
    float r1 = first ? o1*t01.z - p1*t01.w : o1*t01.z + p1*t01.w;
    float r2 = first ? o2*t23.x - p2*t23.y : o2*t23.x + p2*t23.y;
    float r3 = first ? o3*t23.z - p3*t23.w : o3*t23.z + p3*t23.w;
    r0 = r0 / (1.f + expf(-r0));
    r1 = r1 / (1.f + expf(-r1));
    r2 = r2 / (1.f + expf(-r2));
    r3 = r3 / (1.f + expf(-r3));
    short4v o;
    o.x = (short)f2bf(r0); o.y = (short)f2bf(r1);
    o.z = (short)f2bf(r2); o.w = (short)f2bf(r3);
    *(short4v*)(q + (size_t)n*ld + lane*4) = o;
}

// ---------------- bf16 MFMA GEMM (PROVEN core): 128x128, BK=64, single-buffer ----------------
// EPI: 0 bf16 out; 1 +bias,GELU,bf16; 2 fp32 residual add; 3 +bias fp32 residual add;
//      4 +bias, bf16 out
template<int EPI, bool PB>
__global__ __launch_bounds__(256) void gemm_bf16(const u16* __restrict__ A, int lda,
        const u16* __restrict__ Wt, const float* __restrict__ bias,
        u16* __restrict__ Cb, float* __restrict__ Xres, int M, int N, int K, int ldc) {
    __shared__ u16 As[2*128*32];
    __shared__ u16 Bs[2*128*32];
    const int gx = gridDim.x;
    int n = blockIdx.y * gx + blockIdx.x;
    const int nwg = gx * gridDim.y;
    if ((nwg & 7) == 0) n = (n & 7) * (nwg >> 3) + (n >> 3);
    const int bx = n % gx, by = n / gx;
    const int row0 = by*128, col0 = bx*128;

    size_t zrow = 0;
    if (PB) {
        int z = blockIdx.z;
        A  += (size_t)z * M * lda;
        Wt += (size_t)z * N * K;
        zrow = (size_t)z * M;
    }

    const int tid = threadIdx.x;
    const int wid = tid >> 6, lane = tid & 63;
    const int wr = wid >> 1, wc = wid & 1;

    f32x4 acc[4][4];
    #pragma unroll
    for (int i = 0; i < 4; ++i)
        #pragma unroll
        for (int j = 0; j < 4; ++j) {
            f32x4 z; z.x = 0.f; z.y = 0.f; z.z = 0.f; z.w = 0.f;
            acc[i][j] = z;
        }

    const int r0s = wid*32 + (lane>>2);
    const int r1s = r0s + 16;
    const int s0 = ((lane&3) - (r0s>>1)) & 3;
    const int s1 = ((lane&3) - (r1s>>1)) & 3;
    const u16* a0p = A  + (size_t)(row0 + r0s)*lda + s0*8;
    const u16* a1p = A  + (size_t)(row0 + r1s)*lda + s1*8;
    const u16* b0p = Wt + (size_t)(col0 + r0s)*K + s0*8;
    const u16* b1p = Wt + (size_t)(col0 + r1s)*K + s1*8;
    u16* lA0 = As + (wid*2+0)*512;
    u16* lA1 = As + (wid*2+1)*512;
    u16* lB0 = Bs + (wid*2+0)*512;
    u16* lB1 = Bs + (wid*2+1)*512;

    const int kg = lane >> 4, li = lane & 15;
    int aoff[4], boff[4];
    #pragma unroll
    for (int mi = 0; mi < 4; ++mi) {
        int row = wr*64 + mi*16 + li;
        aoff[mi] = row*32 + ((kg + (row>>1)) & 3)*8;
    }
    #pragma unroll
    for (int ni = 0; ni < 4; ++ni) {
        int row = wc*64 + ni*16 + li;
        boff[ni] = row*32 + ((kg + (row>>1)) & 3)*8;
    }

    auto stage = [&](int k0) {
        #pragma unroll
        for (int t = 0; t < 2; ++t) {
            const int ko = k0 + t*32;
            const int lo = t*4096;
            gload16(a0p + ko, lA0 + lo); gload16(a1p + ko, lA1 + lo);
            gload16(b0p + ko, lB0 + lo); gload16(b1p + ko, lB1 + lo);
        }
    };

    stage(0);
    const int nk2 = K >> 6;
    for (int ks = 0; ks < nk2; ++ks) {
        __syncthreads();
        short8 af[2][4], bfr[2][4];
        #pragma unroll
        for (int t = 0; t < 2; ++t) {
            #pragma unroll
            for (int mi = 0; mi < 4; ++mi) af[t][mi] = *(const short8*)(As + t*4096 + aoff[mi]);
            #pragma unroll
            for (int ni = 0; ni < 4; ++ni) bfr[t][ni] = *(const short8*)(Bs + t*4096 + boff[ni]);
        }
        __syncthreads();
        if (ks + 1 < nk2) stage((ks + 1) << 6);
        #pragma unroll
        for (int t = 0; t < 2; ++t)
            #pragma unroll
            for (int mi = 0; mi < 4; ++mi)
                #pragma unroll
                for (int ni = 0; ni < 4; ++ni)
                    acc[mi][ni] = mfma16(af[t][mi], bfr[t][ni], acc[mi][ni]);
    }

    #pragma unroll
    for (int mi = 0; mi < 4; ++mi) {
        int rbase = row0 + wr*64 + mi*16 + kg*4;
        #pragma unroll
        for (int ni = 0; ni < 4; ++ni) {
            int col = col0 + wc*64 + ni*16 + li;
            #pragma unroll
            for (int r = 0; r < 4; ++r) {
                int row = rbase + r;
                if (row >= M) continue;
                float v = acc[mi][ni][r];
                if (EPI == 1 || EPI == 3 || EPI == 4) v += bias[col];
                if (EPI == 1) v = gelu_fast(v);
                if (EPI == 0 || EPI == 1 || EPI == 4)
                    Cb[(zrow + row)*(size_t)ldc + col] = f2bf(v);
                else
                    Xres[(zrow + row)*(size_t)ldc + col] += v;
            }
        }
    }
}

// ---------------- WIDE GEMM: 128x256 tile, 512 thr (used where grid stays large) ----------------
// Stat-free epilogues. BK=64 (2 subtiles), single-buffered (48 KB LDS).
// EPI: 0 bf16; 1 +bias,GELU.
template<int EPI, bool PB>
__global__ __launch_bounds__(512) void gemm_wide(const u16* __restrict__ A, int lda,
        const u16* __restrict__ Wt, const float* __restrict__ bias,
        u16* __restrict__ Cb, int M, int N, int K, int ldc) {
    __shared__ u16 As[2*4096];             // [subtile][128*32]
    __shared__ u16 Bs[2*8192];             // [subtile][256*32]
    const int gx = gridDim.x;
    int n = blockIdx.y * gx + blockIdx.x;
    const int nwg = gx * gridDim.y;
    if ((nwg & 7) == 0) n = (n & 7) * (nwg >> 3) + (n >> 3);
    const int bx = n % gx, by = n / gx;
    const int row0 = by*128, col0 = bx*256;

    size_t zrow = 0;
    if (PB) {
        int z = blockIdx.z;
        A  += (size_t)z * M * lda;
        Wt += (size_t)z * N * K;
        zrow = (size_t)z * M;
    }

    const int tid = threadIdx.x;
    const int wid = tid >> 6, lane = tid & 63;
    const int kg = lane >> 4, li = lane & 15;

    f32x4 acc[16];
    #pragma unroll
    for (int i = 0; i < 16; ++i) { f32x4 z; z.x=0.f; z.y=0.f; z.z=0.f; z.w=0.f; acc[i]=z; }

    const int ra = wid*16 + (lane>>2);
    const int sa = ((lane&3) - (ra>>1)) & 3;
    const u16* agp = A + (size_t)(row0 + ra)*lda + sa*8;
    const int lAo = wid*512;
    const int rb0 = (wid*2+0)*16 + (lane>>2);
    const int rb1 = (wid*2+1)*16 + (lane>>2);
    const int sb0 = ((lane&3) - (rb0>>1)) & 3;
    const int sb1 = ((lane&3) - (rb1>>1)) & 3;
    const u16* bgp0 = Wt + (size_t)(col0 + rb0)*K + sb0*8;
    const u16* bgp1 = Wt + (size_t)(col0 + rb1)*K + sb1*8;
    const int lB0o = (wid*2+0)*512;
    const int lB1o = (wid*2+1)*512;

    const int arow = wid*16 + li;
    const int aoff = arow*32 + ((kg + (arow>>1)) & 3)*8;
    int boff[16];
    #pragma unroll
    for (int ni = 0; ni < 16; ++ni) {
        int row = ni*16 + li;
        boff[ni] = row*32 + ((kg + (row>>1)) & 3)*8;
    }

    auto stage = [&](int k0) {
        #pragma unroll
        for (int t = 0; t < 2; ++t) {
            const int ko = k0 + t*32;
            gload16(agp  + ko, As + t*4096 + lAo);
            gload16(bgp0 + ko, Bs + t*8192 + lB0o);
            gload16(bgp1 + ko, Bs + t*8192 + lB1o);
        }
    };

    stage(0);
    const int nk2 = K >> 6;
    for (int ks = 0; ks < nk2; ++ks) {
        __syncthreads();                    // DMA for this 64-K tile drained
        short8 af0 = *(const short8*)(As + aoff);
        short8 b0[8], b1[8];
        #pragma unroll
        for (int ni = 0; ni < 8; ++ni) b0[ni] = *(const short8*)(Bs + boff[ni]);
        #pragma unroll
        for (int ni = 0; ni < 8; ++ni) acc[ni] = mfma16(af0, b0[ni], acc[ni]);
        #pragma unroll
        for (int ni = 0; ni < 8; ++ni) b1[ni] = *(const short8*)(Bs + boff[8+ni]);
        #pragma unroll
        for (int ni = 0; ni < 8; ++ni) acc[8+ni] = mfma16(af0, b1[ni], acc[8+ni]);
        short8 af1 = *(const short8*)(As + 4096 + aoff);
        #pragma unroll
        for (int ni = 0; ni < 8; ++ni) b0[ni] = *(const short8*)(Bs + 8192 + boff[ni]);
        #pragma unroll
        for (int ni = 0; ni < 8; ++ni) b1[ni] = *(const short8*)(Bs + 8192 + boff[8+ni]);
        __syncthreads();                    // reads done; LDS reusable
        if (ks + 1 < nk2) stage((ks + 1) << 6);
        #pragma unroll
        for (int ni = 0; ni < 8; ++ni) acc[ni]   = mfma16(af1, b0[ni], acc[ni]);
        #pragma unroll
        for (int ni = 0; ni < 8; ++ni) acc[8+ni] = mfma16(af1, b1[ni], acc[8+ni]);
    }

    #pragma unroll
    for (int r = 0; r < 4; ++r) {
        const int row = row0 + wid*16 + kg*4 + r;
        if (row >= M) continue;
        #pragma unroll
        for (int ni = 0; ni < 16; ++ni) {
            int col = col0 + ni*16 + li;
            float v = acc[ni][r];
            if (EPI == 1) { v += bias[col]; v = gelu_fast(v); }
            Cb[(zrow + row)*(size_t)ldc + col] = f2bf(v);
        }
    }
}

// ---------------- kv = K^T V per (b,h) via MFMA (atomic merge, proven) ----------------
constexpr int KV_LSPLIT = 4;
constexpr int KV_PART   = 768;            // 24 tiles of 32; 4*768 >= L_
__global__ __launch_bounds__(256) void kv_mfma_kernel(const u16* __restrict__ Kt,
        const u16* __restrict__ Vt, float* __restrict__ kvf, int ld) {
    __shared__ u16 kT[64][34];            // [d][l'] transposed, pad 2
    __shared__ u16 vT[64][34];
    const int bh = blockIdx.x;
    const int b = bh >> 2, h = bh & 3;
    const int tid = threadIdx.x;
    const int wid = tid >> 6, lane = tid & 63;
    const int kg = lane >> 4, li = lane & 15;
    const int wm = (wid >> 1)*32, wn = (wid & 1)*32;
    const int sl = tid >> 3;              // 0..31
    const int sd = (tid & 7) * 8;
    const u16* kbase = Kt + ((size_t)b*L_)*ld + h*HD_ + sd;
    const u16* vbase = Vt + ((size_t)b*L_)*ld + h*HD_ + sd;

    f32x4 acc[2][2];
    #pragma unroll
    for (int i = 0; i < 2; ++i)
        #pragma unroll
        for (int j = 0; j < 2; ++j) {
            f32x4 z; z.x=0.f; z.y=0.f; z.z=0.f; z.w=0.f; acc[i][j] = z;
        }

    const int l0p = blockIdx.y * KV_PART;
    for (int t = 0; t < KV_PART/32; ++t) {
        int gl = l0p + t*32 + sl;
        short8 kk = {0,0,0,0,0,0,0,0}, vv = {0,0,0,0,0,0,0,0};
        if (gl < L_) {
            kk = *(const short8*)(kbase + (size_t)gl*ld);
            vv = *(const short8*)(vbase + (size_t)gl*ld);
        }
        __syncthreads();
        #pragma unroll
        for (int j = 0; j < 8; ++j) {
            kT[sd+j][sl] = (u16)kk[j];
            vT[sd+j][sl] = (u16)vv[j];
        }
        __syncthreads();
        short8 a0, a1, b0, b1;
        {
            uint* d0 = (uint*)&a0; const uint* p0 = (const uint*)&kT[wm + li][kg*8];
            uint* d1 = (uint*)&a1; const uint* p1 = (const uint*)&kT[wm + 16 + li][kg*8];
            uint* d2 = (uint*)&b0; const uint* p2 = (const uint*)&vT[wn + li][kg*8];
            uint* d3 = (uint*)&b1; const uint* p3 = (const uint*)&vT[wn + 16 + li][kg*8];
            #pragma unroll
            for (int j = 0; j < 4; ++j) { d0[j]=p0[j]; d1[j]=p1[j]; d2[j]=p2[j]; d3[j]=p3[j]; }
        }
        acc[0][0] = mfma16(a0, b0, acc[0][0]);
        acc[0][1] = mfma16(a0, b1, acc[0][1]);
        acc[1][0] = mfma16(a1, b0, acc[1][0]);
        acc[1][1] = mfma16(a1, b1, acc[1][1]);
    }
    float* base = kvf + (size_t)bh*4096;
    #pragma unroll
    for (int mi = 0; mi < 2; ++mi)
        #pragma unroll
        for (int ni = 0; ni < 2; ++ni)
            #pragma unroll
            for (int r = 0; r < 4; ++r)
                atomicAdd(base + (wm + mi*16 + kg*4 + r)*64 + wn + ni*16 + li,
                          acc[mi][ni][r]);
}

// ---------------- M2T[b][n][h*64+d] = bf16( (1/8) sum_e kv[b,h,d,e] * ow[h*64+e][n] ) ----------------
__global__ __launch_bounds__(256) void m2_kernel(const float* __restrict__ kvf,
        const float* __restrict__ ow, u16* __restrict__ m2t) {
    __shared__ float kvs[64][64];
    const int bh = blockIdx.x;
    const int b = bh >> 2, h = bh & 3;
    const int tid = threadIdx.x;          // n = tid
    #pragma unroll
    for (int p = 0; p < 16; ++p)
        ((float*)kvs)[p*256 + tid] = kvf[(size_t)bh*4096 + p*256 + tid];
    __syncthreads();
    float acc[64];
    #pragma unroll
    for (int d = 0; d < 64; ++d) acc[d] = 0.f;
    for (int e = 0; e < 64; ++e) {
        float w = ow[(size_t)(h*64 + e)*256 + tid];
        #pragma unroll
        for (int d = 0; d < 64; ++d) acc[d] += kvs[d][e] * w;
    }
    u16* dst = m2t + ((size_t)b*256 + tid)*256 + h*64;
    #pragma unroll
    for (int d = 0; d < 64; ++d) dst[d] = f2bf(acc[d]*0.125f);
}

// ---------------- head ----------------
__global__ void head_kernel(const float* __restrict__ x, const float* __restrict__ obs,
                            const float* __restrict__ fng, const float* __restrict__ fnb,
                            const float* __restrict__ ow, const float* __restrict__ ob,
                            float* __restrict__ out) {
    __shared__ float row[D_ + ADIM_];
    __shared__ float red[8];
    int b = blockIdx.x, tid = threadIdx.x;
    float v = x[((size_t)b*L_)*D_ + tid];
    float s = v, sq = v*v;
    #pragma unroll
    for (int off = 32; off; off >>= 1) { s += __shfl_xor(s, off); sq += __shfl_xor(sq, off); }
    int wave = tid >> 6, lane = tid & 63;
    if (lane == 0) { red[wave] = s; red[4+wave] = sq; }
    __syncthreads();
    s  = red[0]+red[1]+red[2]+red[3];
    sq = red[4]+red[5]+red[6]+red[7];
    float mean = s*(1.f/D_), var = sq*(1.f/D_) - mean*mean;
    float r = rsqrtf(var + 1e-5f);
    row[tid] = (v-mean)*r*fng[tid] + fnb[tid];
    if (tid < ADIM_) row[D_+tid] = obs[(size_t)b*OBSROW + VIS_ + tid];
    __syncthreads();
    float acc = ob[tid];
    for (int j = 0; j < D_+ADIM_; ++j) acc += row[j]*ow[j*OUT_ + tid];
    out[(size_t)b*OUT_ + tid] = acc;
}

// ---------------- launch ----------------
extern "C" void kernel_launch(void* const* d_in, const int* in_sizes, int n_in,
                              void* d_out, int out_size, void* d_ws, size_t ws_size,
                              hipStream_t stream) {
    const float* obs   = (const float*)d_in[0];
    const float* pw    = (const float*)d_in[1];
    const float* pb    = (const float*)d_in[2];
    const float* cls   = (const float*)d_in[3];
    const float* qw    = (const float*)d_in[4];
    const float* kw    = (const float*)d_in[5];
    const float* vw    = (const float*)d_in[6];
    const float* oww   = (const float*)d_in[7];
    const float* gq    = (const float*)d_in[8];
    const float* bq    = (const float*)d_in[9];
    const float* gk    = (const float*)d_in[10];
    const float* bk    = (const float*)d_in[11];
    const float* n1g   = (const float*)d_in[12];
    const float* n1b   = (const float*)d_in[13];
    const float* n2g   = (const float*)d_in[14];
    const float* n2b   = (const float*)d_in[15];
    const float* w1    = (const float*)d_in[16];
    const float* b1    = (const float*)d_in[17];
    const float* w2    = (const float*)d_in[18];
    const float* b2    = (const float*)d_in[19];
    const float* fng   = (const float*)d_in[20];
    const float* fnb   = (const float*)d_in[21];
    const float* outw  = (const float*)d_in[22];
    const float* outb  = (const float*)d_in[23];

    // ---- workspace layout ----
    float* x = (float*)d_ws;                               // NTOK*256 fp32
    u16* qkvT = (u16*)(x + (size_t)NTOK*D_);               // [NL][768][256]
    u16* w1T  = qkvT + (size_t)NL_*768*256;                // [NL][1024][256]
    u16* w2T  = w1T  + (size_t)NL_*262144;                 // [NL][256][1024]
    float* tab = (float*)(w2T + (size_t)NL_*262144);       // L*32*2 fp32
    u16* bufs = (u16*)(tab + (size_t)L_*32*2);

    size_t fixedB = (size_t)((char*)bufs - (char*)d_ws);
    auto needed = [&](int nb) -> size_t {
        size_t t = (size_t)nb * L_;
        return fixedB + (t*256 + (size_t)PADR*256)*2 + (t*1024 + (size_t)PADR*1024)*2
               + (size_t)nb*65536*2 + (size_t)nb*NH_*4096*4;
    };
    int nbc = 32;
    while (nbc > 1 && needed(nbc) > ws_size) nbc >>= 1;
    const int nch = B_ / nbc;
    const int RCn = nbc * L_;

    u16* Xn   = bufs;                                           // nb*L*256 (+pad)
    u16* QKVc = Xn + (size_t)RCn*256 + (size_t)PADR*256;        // ld=768 view
    u16* Hc   = QKVc;                                           // ld=1024 view (same region)
    u16* M2T  = QKVc + (size_t)RCn*1024 + (size_t)PADR*1024;    // nb*256*256
    float* kvf = (float*)(M2T + (size_t)nbc*65536);             // nb*4*4096 f32

    // ---- setup ----
    wcvt_kernel<<<(NL_*65536 + 255)/256, 256, 0, stream>>>(qw,  qkvT, 256, 256, 768*256, 0);
    wcvt_kernel<<<(NL_*65536 + 255)/256, 256, 0, stream>>>(kw,  qkvT, 256, 256, 768*256, 256);
    wcvt_kernel<<<(NL_*65536 + 255)/256, 256, 0, stream>>>(vw,  qkvT, 256, 256, 768*256, 512);
    wcvt_kernel<<<(NL_*262144 + 255)/256, 256, 0, stream>>>(w1, w1T, 1024, 256, 262144, 0);
    wcvt_kernel<<<(NL_*262144 + 255)/256, 256, 0, stream>>>(w2, w2T, 256, 1024, 262144, 0);
    rope_table_kernel<<<(L_*32 + 255)/256, 256, 0, stream>>>(tab);
    proj_kernel<<<(NTOK + 3)/4, 256, 0, stream>>>(obs, pw, pb, cls, x);

    const int gy  = (RCn + 127)/128;
    const int lnb = (RCn + 3)/4;
    const int nbh = nbc*NH_;

    // chunk OUTER, layer INNER: all Xn/QKVc/Hc/M2T/kvf state is consumed within
    // one chunk iteration, so the cross-layer Xn carry is race-free.
    for (int c = 0; c < nch; ++c) {
        float* xc = x + (size_t)c*RCn*D_;
        ln_f2b_kernel<<<lnb, 256, 0, stream>>>(xc, n1g, n1b, Xn, RCn);

        for (int layer = 0; layer < NL_; ++layer) {
            const u16* qkvT_l = qkvT + (size_t)layer*768*256;
            const u16* w1T_l  = w1T  + (size_t)layer*262144;
            const u16* w2T_l  = w2T  + (size_t)layer*262144;
            const float* ow_l = oww + (size_t)layer*65536;
            const float* b1_l = b1 + (size_t)layer*1024;
            const float* b2_l = b2 + (size_t)layer*D_;

            // QKV: wide tile (3 x 256-col tiles, large grid)
            gemm_wide<0,false><<<dim3(3, gy), 512, 0, stream>>>(Xn, 256, qkvT_l, nullptr, QKVc, RCn, 768, 256, 768);
            lnrope_kernel<<<dim3(lnb, 2), 256, 0, stream>>>(QKVc, gq + layer*D_, bq + layer*D_,
                                                            gk + layer*D_, bk + layer*D_, tab, RCn, 768);
            zero_kernel<<<(nbh*4096 + 255)/256, 256, 0, stream>>>(kvf, nbh*4096);
            kv_mfma_kernel<<<dim3(nbh, KV_LSPLIT), 256, 0, stream>>>(QKVc + 256, QKVc + 512, kvf, 768);
            m2_kernel<<<nbh, 256, 0, stream>>>(kvf, ow_l, M2T);
            // attn+O-proj delta (narrow, per-batch — keeps grid at 768) -> Xn; x += delta; LN2
            gemm_bf16<0,true><<<dim3(2, 24, nbc), 256, 0, stream>>>(QKVc, 768, M2T, nullptr, Xn, nullptr, L_, 256, 256, 256);
            lnres_kernel<<<lnb, 256, 0, stream>>>(xc, Xn, n2g + layer*D_, n2b + layer*D_, RCn);
            // MLP: W1 wide (+bias,GELU, large grid) -> Hc; W2 narrow delta(+bias) -> Xn (752 blocks)
            gemm_wide<1,false><<<dim3(4, gy), 512, 0, stream>>>(Xn, 256, w1T_l, b1_l, Hc, RCn, 1024, 256, 1024);
            gemm_bf16<4,false><<<dim3(2, gy), 256, 0, stream>>>(Hc, 1024, w2T_l, b2_l, Xn, nullptr, RCn, 256, 1024, 256);
            const float* gN = (layer < NL_-1) ? (n1g + (layer+1)*D_) : fng;
            const float* bN = (layer < NL_-1) ? (n1b + (layer+1)*D_) : fnb;
            lnres_kernel<<<lnb, 256, 0, stream>>>(xc, Xn, gN, bN, RCn);
        }
    }

    head_kernel<<<B_, 256, 0, stream>>>(x, obs, fng, fnb, outw, outb, (float*)d_out);
}

// Round 23
// 2261.763 us; speedup vs baseline: 1.3515x; 1.1002x over previous
//
#include <hip/hip_runtime.h>
#include <math.h>

typedef unsigned short u16;
typedef __attribute__((ext_vector_type(8))) short short8;
typedef __attribute__((ext_vector_type(4))) short short4v;
typedef __attribute__((ext_vector_type(4))) float f32x4;

// ---------------- problem constants ----------------
constexpr int B_    = 32;
constexpr int HIST_ = 10, C_ = 11, H_ = 15, W_ = 20;
constexpr int D_    = 256, NH_ = 4, NL_ = 4, HD_ = 64;
constexpr int OUT_  = 256, ADIM_ = 20;
constexpr int L_    = HIST_*H_*W_ + 1;      // 3001
constexpr int VIS_  = HIST_*C_*H_*W_;       // 33000
constexpr int NTOK  = B_*L_;                // 96032
constexpr int OBSROW = VIS_ + ADIM_;        // 33020
constexpr int PADR  = 128;                  // pad rows so tile DMA stays in-bounds

// ---------------- bf16 helpers ----------------
__device__ __forceinline__ float bf2f(u16 u) {
    return __uint_as_float(((unsigned)u) << 16);
}
__device__ __forceinline__ u16 f2bf(float f) {
    unsigned u = __float_as_uint(f);
    u = u + 0x7FFFu + ((u >> 16) & 1u);
    return (u16)(u >> 16);
}
__device__ __forceinline__ f32x4 mfma16(short8 a, short8 b, f32x4 c) {
    return __builtin_amdgcn_mfma_f32_16x16x32_bf16(a, b, c, 0, 0, 0);
}
__device__ __forceinline__ void gload16(const u16* gsrc, u16* ldsdst) {
    __builtin_amdgcn_global_load_lds(
        (const __attribute__((address_space(1))) unsigned int*)gsrc,
        (__attribute__((address_space(3))) unsigned int*)ldsdst,
        16, 0, 0);
}
// tanh-form GELU: ~9 VALU ops (one v_exp). |err| <= ~3e-4.
__device__ __forceinline__ float gelu_fast(float v) {
    float t2 = 1.5957691216f*(v + 0.044715f*v*v*v);
    return v / (1.f + __expf(-t2));
}

// ---------------- setup kernels ----------------
__global__ void zero_kernel(float* __restrict__ p, int n) {
    int i = blockIdx.x*256 + threadIdx.x;
    if (i < n) p[i] = 0.f;
}

// dst[l][dstOff+n][k] = bf16(src[l][k][n]); dst layer stride dstLS
__global__ void wcvt_kernel(const float* __restrict__ src, u16* __restrict__ dst,
                            int Nn, int Kk, int dstLS, int dstOff) {
    int idx = blockIdx.x*256 + threadIdx.x;
    int tot = NL_*Nn*Kk;
    if (idx >= tot) return;
    int l = idx / (Nn*Kk);
    int rem = idx % (Nn*Kk);
    int n = rem / Kk, k = rem % Kk;
    dst[(size_t)l*dstLS + (size_t)(dstOff+n)*Kk + k] = f2bf(src[(size_t)l*Kk*Nn + (size_t)k*Nn + n]);
}

__global__ void rope_table_kernel(float* __restrict__ tab) {
    int idx = blockIdx.x*256 + threadIdx.x;
    if (idx >= L_*32) return;
    int t = idx >> 5, i = idx & 31;
    float freq = powf(10000.f, -2.f*(float)i/(float)HD_);
    float ang = (float)t * freq;
    tab[idx*2]   = cosf(ang);
    tab[idx*2+1] = sinf(ang);
}

// 4 tokens/block (1 per wave); lane owns 4 cols; float4 loads/stores.
__global__ __launch_bounds__(256) void proj_kernel(const float* __restrict__ obs,
        const float* __restrict__ pw, const float* __restrict__ pb,
        const float* __restrict__ cls, float* __restrict__ x) {
    int wave = threadIdx.x >> 6, lane = threadIdx.x & 63;
    int n = blockIdx.x*4 + wave;
    if (n >= NTOK) return;
    int b = n / L_, l = n % L_;
    float4 acc;
    if (l == 0) {
        acc = ((const float4*)cls)[lane];
    } else {
        int t = l - 1;
        int hist = t / (H_*W_);
        int rem  = t % (H_*W_);
        float vv = 0.f;
        if (lane < C_) vv = obs[(size_t)b*OBSROW + hist*(C_*H_*W_) + lane*(H_*W_) + rem];
        acc = ((const float4*)pb)[lane];
        #pragma unroll
        for (int c = 0; c < C_; ++c) {
            float vc = __shfl(vv, c);
            float4 w4 = ((const float4*)(pw + c*D_))[lane];
            acc.x += vc*w4.x; acc.y += vc*w4.y; acc.z += vc*w4.z; acc.w += vc*w4.w;
        }
    }
    ((float4*)(x + (size_t)n*D_))[lane] = acc;
}

// ---------------- LayerNorm fp32 -> bf16 (layer-0 LN1 per chunk) ----------------
__global__ __launch_bounds__(256) void ln_f2b_kernel(const float* __restrict__ in,
        const float* __restrict__ g, const float* __restrict__ bt,
        u16* __restrict__ out, int ntok) {
    int wave = threadIdx.x >> 6, lane = threadIdx.x & 63;
    int n = blockIdx.x*4 + wave;
    if (n >= ntok) return;
    float4 v = ((const float4*)(in + (size_t)n*D_))[lane];
    float s  = v.x + v.y + v.z + v.w;
    float sq = v.x*v.x + v.y*v.y + v.z*v.z + v.w*v.w;
    #pragma unroll
    for (int off = 32; off; off >>= 1) { s += __shfl_xor(s, off); sq += __shfl_xor(sq, off); }
    float mean = s * (1.f/D_);
    float var  = sq * (1.f/D_) - mean*mean;
    float r = rsqrtf(var + 1e-5f);
    float4 gg = ((const float4*)g)[lane];
    float4 bb = ((const float4*)bt)[lane];
    short4v o;
    o.x = (short)f2bf((v.x-mean)*r*gg.x + bb.x);
    o.y = (short)f2bf((v.y-mean)*r*gg.y + bb.y);
    o.z = (short)f2bf((v.z-mean)*r*gg.z + bb.z);
    o.w = (short)f2bf((v.w-mean)*r*gg.w + bb.w);
    *(short4v*)(out + (size_t)n*D_ + lane*4) = o;
}

// ---------------- residual add + LayerNorm: x += delta(bf16); Xn = LN(x) ----------------
// CHUNK-LOCAL only — safe under nch>1 with the chunk-OUTER loop.
__global__ __launch_bounds__(256) void lnres_kernel(float* __restrict__ x,
        u16* __restrict__ dx, const float* __restrict__ g, const float* __restrict__ bt,
        int ntok) {
    int wave = threadIdx.x >> 6, lane = threadIdx.x & 63;
    int n = blockIdx.x*4 + wave;
    if (n >= ntok) return;
    float4 v = ((const float4*)(x + (size_t)n*D_))[lane];
    short4v d = *(const short4v*)(dx + (size_t)n*D_ + lane*4);
    v.x += bf2f((u16)d.x); v.y += bf2f((u16)d.y);
    v.z += bf2f((u16)d.z); v.w += bf2f((u16)d.w);
    ((float4*)(x + (size_t)n*D_))[lane] = v;
    float s  = v.x + v.y + v.z + v.w;
    float sq = v.x*v.x + v.y*v.y + v.z*v.z + v.w*v.w;
    #pragma unroll
    for (int off = 32; off; off >>= 1) { s += __shfl_xor(s, off); sq += __shfl_xor(sq, off); }
    float mean = s * (1.f/D_);
    float var  = sq * (1.f/D_) - mean*mean;
    float r = rsqrtf(var + 1e-5f);
    float4 gg = ((const float4*)g)[lane];
    float4 bb = ((const float4*)bt)[lane];
    short4v o;
    o.x = (short)f2bf((v.x-mean)*r*gg.x + bb.x);
    o.y = (short)f2bf((v.y-mean)*r*gg.y + bb.y);
    o.z = (short)f2bf((v.z-mean)*r*gg.z + bb.z);
    o.w = (short)f2bf((v.w-mean)*r*gg.w + bb.w);
    *(short4v*)(dx + (size_t)n*D_ + lane*4) = o;
}

// ---------------- fused LN + RoPE + SiLU (merged Q/K: blockIdx.y selects) ----------------
__global__ __launch_bounds__(256) void lnrope_kernel(u16* __restrict__ qk,
        const float* __restrict__ gq, const float* __restrict__ bq,
        const float* __restrict__ gk, const float* __restrict__ bk,
        const float* __restrict__ tab, int ntok, int ld) {
    u16* q = qk + blockIdx.y*256;                  // y=0 -> Q, y=1 -> K
    const float* g  = blockIdx.y ? gk : gq;
    const float* bt = blockIdx.y ? bk : bq;
    int wave = threadIdx.x >> 6, lane = threadIdx.x & 63;
    int n = blockIdx.x*4 + wave;
    if (n >= ntok) return;
    int l = n % L_;
    short4v raw = *(const short4v*)(q + (size_t)n*ld + lane*4);
    float v0 = bf2f((u16)raw.x), v1 = bf2f((u16)raw.y), v2 = bf2f((u16)raw.z), v3 = bf2f((u16)raw.w);
    float s  = v0+v1+v2+v3;
    float sq = v0*v0+v1*v1+v2*v2+v3*v3;
    #pragma unroll
    for (int off = 32; off; off >>= 1) { s += __shfl_xor(s, off); sq += __shfl_xor(sq, off); }
    float mean = s * (1.f/D_);
    float var  = sq * (1.f/D_) - mean*mean;
    float r = rsqrtf(var + 1e-5f);
    float4 gg = ((const float4*)g)[lane];
    float4 bb = ((const float4*)bt)[lane];
    float o0 = (v0-mean)*r*gg.x + bb.x;
    float o1 = (v1-mean)*r*gg.y + bb.y;
    float o2 = (v2-mean)*r*gg.z + bb.z;
    float o3 = (v3-mean)*r*gg.w + bb.w;
    float p0 = __shfl_xor(o0, 8), p1 = __shfl_xor(o1, 8);
    float p2 = __shfl_xor(o2, 8), p3 = __shfl_xor(o3, 8);
    bool first = (lane & 15) < 8;
    const float4* tp = (const float4*)(tab + ((size_t)l*32 + (lane&7)*4)*2);
    float4 t01 = tp[0], t23 = tp[1];
    float r0 = first ? o0*t01.x - p0*t01.y : o0*t01.x + p0*t01.y;
    float r1 = first ? o1*t01.z - p1*t01.w : o1*t01.z + p1*t01.w;
    float r2 = first ? o2*t23.x - p2*t23.y : o2*t23.x + p2*t23.y;
    float r3 = first ? o3*t23.z - p3*t23.w : o3*t23.z + p3*t23.w;
    r0 = r0 / (1.f + expf(-r0));
    r1 = r1 / (1.f + expf(-r1));
    r2 = r2 / (1.f + expf(-r2));
    r3 = r3 / (1.f + expf(-r3));
    short4v o;
    o.x = (short)f2bf(r0); o.y = (short)f2bf(r1);
    o.z = (short)f2bf(r2); o.w = (short)f2bf(r3);
    *(short4v*)(q + (size_t)n*ld + lane*4) = o;
}

// ---------------- bf16 MFMA GEMM (PROVEN core): 128x128, BK=64, single-buffer ----------------
// EPI: 0 bf16 out; 1 +bias,GELU,bf16; 4 +bias, bf16 out
template<int EPI, bool PB>
__global__ __launch_bounds__(256) void gemm_bf16(const u16* __restrict__ A, int lda,
        const u16* __restrict__ Wt, const float* __restrict__ bias,
        u16* __restrict__ Cb, float* __restrict__ Xres, int M, int N, int K, int ldc) {
    __shared__ u16 As[2*128*32];
    __shared__ u16 Bs[2*128*32];
    const int gx = gridDim.x;
    int n = blockIdx.y * gx + blockIdx.x;
    const int nwg = gx * gridDim.y;
    if ((nwg & 7) == 0) n = (n & 7) * (nwg >> 3) + (n >> 3);
    const int bx = n % gx, by = n / gx;
    const int row0 = by*128, col0 = bx*128;

    size_t zrow = 0;
    if (PB) {
        int z = blockIdx.z;
        A  += (size_t)z * M * lda;
        Wt += (size_t)z * N * K;
        zrow = (size_t)z * M;
    }

    const int tid = threadIdx.x;
    const int wid = tid >> 6, lane = tid & 63;
    const int wr = wid >> 1, wc = wid & 1;

    f32x4 acc[4][4];
    #pragma unroll
    for (int i = 0; i < 4; ++i)
        #pragma unroll
        for (int j = 0; j < 4; ++j) {
            f32x4 z; z.x = 0.f; z.y = 0.f; z.z = 0.f; z.w = 0.f;
            acc[i][j] = z;
        }

    const int r0s = wid*32 + (lane>>2);
    const int r1s = r0s + 16;
    const int s0 = ((lane&3) - (r0s>>1)) & 3;
    const int s1 = ((lane&3) - (r1s>>1)) & 3;
    const u16* a0p = A  + (size_t)(row0 + r0s)*lda + s0*8;
    const u16* a1p = A  + (size_t)(row0 + r1s)*lda + s1*8;
    const u16* b0p = Wt + (size_t)(col0 + r0s)*K + s0*8;
    const u16* b1p = Wt + (size_t)(col0 + r1s)*K + s1*8;
    u16* lA0 = As + (wid*2+0)*512;
    u16* lA1 = As + (wid*2+1)*512;
    u16* lB0 = Bs + (wid*2+0)*512;
    u16* lB1 = Bs + (wid*2+1)*512;

    const int kg = lane >> 4, li = lane & 15;
    int aoff[4], boff[4];
    #pragma unroll
    for (int mi = 0; mi < 4; ++mi) {
        int row = wr*64 + mi*16 + li;
        aoff[mi] = row*32 + ((kg + (row>>1)) & 3)*8;
    }
    #pragma unroll
    for (int ni = 0; ni < 4; ++ni) {
        int row = wc*64 + ni*16 + li;
        boff[ni] = row*32 + ((kg + (row>>1)) & 3)*8;
    }

    auto stage = [&](int k0) {
        #pragma unroll
        for (int t = 0; t < 2; ++t) {
            const int ko = k0 + t*32;
            const int lo = t*4096;
            gload16(a0p + ko, lA0 + lo); gload16(a1p + ko, lA1 + lo);
            gload16(b0p + ko, lB0 + lo); gload16(b1p + ko, lB1 + lo);
        }
    };

    stage(0);
    const int nk2 = K >> 6;
    for (int ks = 0; ks < nk2; ++ks) {
        __syncthreads();
        short8 af[2][4], bfr[2][4];
        #pragma unroll
        for (int t = 0; t < 2; ++t) {
            #pragma unroll
            for (int mi = 0; mi < 4; ++mi) af[t][mi] = *(const short8*)(As + t*4096 + aoff[mi]);
            #pragma unroll
            for (int ni = 0; ni < 4; ++ni) bfr[t][ni] = *(const short8*)(Bs + t*4096 + boff[ni]);
        }
        __syncthreads();
        if (ks + 1 < nk2) stage((ks + 1) << 6);
        #pragma unroll
        for (int t = 0; t < 2; ++t)
            #pragma unroll
            for (int mi = 0; mi < 4; ++mi)
                #pragma unroll
                for (int ni = 0; ni < 4; ++ni)
                    acc[mi][ni] = mfma16(af[t][mi], bfr[t][ni], acc[mi][ni]);
    }

    #pragma unroll
    for (int mi = 0; mi < 4; ++mi) {
        int rbase = row0 + wr*64 + mi*16 + kg*4;
        #pragma unroll
        for (int ni = 0; ni < 4; ++ni) {
            int col = col0 + wc*64 + ni*16 + li;
            #pragma unroll
            for (int r = 0; r < 4; ++r) {
                int row = rbase + r;
                if (row >= M) continue;
                float v = acc[mi][ni][r];
                if (EPI == 1 || EPI == 4) v += bias[col];
                if (EPI == 1) v = gelu_fast(v);
                Cb[(zrow + row)*(size_t)ldc + col] = f2bf(v);
            }
        }
    }
}

// ---------------- WIDE GEMM: 128x256 tile, 512 thr (used where grid stays large) ----------------
// Stat-free epilogues. BK=64 (2 subtiles), single-buffered (48 KB LDS).
// EPI: 0 bf16; 1 +bias,GELU.
template<int EPI, bool PB>
__global__ __launch_bounds__(512) void gemm_wide(const u16* __restrict__ A, int lda,
        const u16* __restrict__ Wt, const float* __restrict__ bias,
        u16* __restrict__ Cb, int M, int N, int K, int ldc) {
    __shared__ u16 As[2*4096];             // [subtile][128*32]
    __shared__ u16 Bs[2*8192];             // [subtile][256*32]
    const int gx = gridDim.x;
    int n = blockIdx.y * gx + blockIdx.x;
    const int nwg = gx * gridDim.y;
    if ((nwg & 7) == 0) n = (n & 7) * (nwg >> 3) + (n >> 3);
    const int bx = n % gx, by = n / gx;
    const int row0 = by*128, col0 = bx*256;

    size_t zrow = 0;
    if (PB) {
        int z = blockIdx.z;
        A  += (size_t)z * M * lda;
        Wt += (size_t)z * N * K;
        zrow = (size_t)z * M;
    }

    const int tid = threadIdx.x;
    const int wid = tid >> 6, lane = tid & 63;
    const int kg = lane >> 4, li = lane & 15;

    f32x4 acc[16];
    #pragma unroll
    for (int i = 0; i < 16; ++i) { f32x4 z; z.x=0.f; z.y=0.f; z.z=0.f; z.w=0.f; acc[i]=z; }

    const int ra = wid*16 + (lane>>2);
    const int sa = ((lane&3) - (ra>>1)) & 3;
    const u16* agp = A + (size_t)(row0 + ra)*lda + sa*8;
    const int lAo = wid*512;
    const int rb0 = (wid*2+0)*16 + (lane>>2);
    const int rb1 = (wid*2+1)*16 + (lane>>2);
    const int sb0 = ((lane&3) - (rb0>>1)) & 3;
    const int sb1 = ((lane&3) - (rb1>>1)) & 3;
    const u16* bgp0 = Wt + (size_t)(col0 + rb0)*K + sb0*8;
    const u16* bgp1 = Wt + (size_t)(col0 + rb1)*K + sb1*8;
    const int lB0o = (wid*2+0)*512;
    const int lB1o = (wid*2+1)*512;

    const int arow = wid*16 + li;
    const int aoff = arow*32 + ((kg + (arow>>1)) & 3)*8;
    int boff[16];
    #pragma unroll
    for (int ni = 0; ni < 16; ++ni) {
        int row = ni*16 + li;
        boff[ni] = row*32 + ((kg + (row>>1)) & 3)*8;
    }

    auto stage = [&](int k0) {
        #pragma unroll
        for (int t = 0; t < 2; ++t) {
            const int ko = k0 + t*32;
            gload16(agp  + ko, As + t*4096 + lAo);
            gload16(bgp0 + ko, Bs + t*8192 + lB0o);
            gload16(bgp1 + ko, Bs + t*8192 + lB1o);
        }
    };

    stage(0);
    const int nk2 = K >> 6;
    for (int ks = 0; ks < nk2; ++ks) {
        __syncthreads();                    // DMA for this 64-K tile drained
        short8 af0 = *(const short8*)(As + aoff);
        short8 b0[8], b1[8];
        #pragma unroll
        for (int ni = 0; ni < 8; ++ni) b0[ni] = *(const short8*)(Bs + boff[ni]);
        #pragma unroll
        for (int ni = 0; ni < 8; ++ni) acc[ni] = mfma16(af0, b0[ni], acc[ni]);
        #pragma unroll
        for (int ni = 0; ni < 8; ++ni) b1[ni] = *(const short8*)(Bs + boff[8+ni]);
        #pragma unroll
        for (int ni = 0; ni < 8; ++ni) acc[8+ni] = mfma16(af0, b1[ni], acc[8+ni]);
        short8 af1 = *(const short8*)(As + 4096 + aoff);
        #pragma unroll
        for (int ni = 0; ni < 8; ++ni) b0[ni] = *(const short8*)(Bs + 8192 + boff[ni]);
        #pragma unroll
        for (int ni = 0; ni < 8; ++ni) b1[ni] = *(const short8*)(Bs + 8192 + boff[8+ni]);
        __syncthreads();                    // reads done; LDS reusable
        if (ks + 1 < nk2) stage((ks + 1) << 6);
        #pragma unroll
        for (int ni = 0; ni < 8; ++ni) acc[ni]   = mfma16(af1, b0[ni], acc[ni]);
        #pragma unroll
        for (int ni = 0; ni < 8; ++ni) acc[8+ni] = mfma16(af1, b1[ni], acc[8+ni]);
    }

    #pragma unroll
    for (int r = 0; r < 4; ++r) {
        const int row = row0 + wid*16 + kg*4 + r;
        if (row >= M) continue;
        #pragma unroll
        for (int ni = 0; ni < 16; ++ni) {
            int col = col0 + ni*16 + li;
            float v = acc[ni][r];
            if (EPI == 1) { v += bias[col]; v = gelu_fast(v); }
            Cb[(zrow + row)*(size_t)ldc + col] = f2bf(v);
        }
    }
}

// ---------------- kv = K^T V per (b,h) via MFMA (atomic merge, proven) ----------------
constexpr int KV_LSPLIT = 4;
constexpr int KV_PART   = 768;            // 24 tiles of 32; 4*768 >= L_
__global__ __launch_bounds__(256) void kv_mfma_kernel(const u16* __restrict__ Kt,
        const u16* __restrict__ Vt, float* __restrict__ kvf, int ld) {
    __shared__ u16 kT[64][34];            // [d][l'] transposed, pad 2
    __shared__ u16 vT[64][34];
    const int bh = blockIdx.x;
    const int b = bh >> 2, h = bh & 3;
    const int tid = threadIdx.x;
    const int wid = tid >> 6, lane = tid & 63;
    const int kg = lane >> 4, li = lane & 15;
    const int wm = (wid >> 1)*32, wn = (wid & 1)*32;
    const int sl = tid >> 3;              // 0..31
    const int sd = (tid & 7) * 8;
    const u16* kbase = Kt + ((size_t)b*L_)*ld + h*HD_ + sd;
    const u16* vbase = Vt + ((size_t)b*L_)*ld + h*HD_ + sd;

    f32x4 acc[2][2];
    #pragma unroll
    for (int i = 0; i < 2; ++i)
        #pragma unroll
        for (int j = 0; j < 2; ++j) {
            f32x4 z; z.x=0.f; z.y=0.f; z.z=0.f; z.w=0.f; acc[i][j] = z;
        }

    const int l0p = blockIdx.y * KV_PART;
    for (int t = 0; t < KV_PART/32; ++t) {
        int gl = l0p + t*32 + sl;
        short8 kk = {0,0,0,0,0,0,0,0}, vv = {0,0,0,0,0,0,0,0};
        if (gl < L_) {
            kk = *(const short8*)(kbase + (size_t)gl*ld);
            vv = *(const short8*)(vbase + (size_t)gl*ld);
        }
        __syncthreads();
        #pragma unroll
        for (int j = 0; j < 8; ++j) {
            kT[sd+j][sl] = (u16)kk[j];
            vT[sd+j][sl] = (u16)vv[j];
        }
        __syncthreads();
        short8 a0, a1, b0, b1;
        {
            uint* d0 = (uint*)&a0; const uint* p0 = (const uint*)&kT[wm + li][kg*8];
            uint* d1 = (uint*)&a1; const uint* p1 = (const uint*)&kT[wm + 16 + li][kg*8];
            uint* d2 = (uint*)&b0; const uint* p2 = (const uint*)&vT[wn + li][kg*8];
            uint* d3 = (uint*)&b1; const uint* p3 = (const uint*)&vT[wn + 16 + li][kg*8];
            #pragma unroll
            for (int j = 0; j < 4; ++j) { d0[j]=p0[j]; d1[j]=p1[j]; d2[j]=p2[j]; d3[j]=p3[j]; }
        }
        acc[0][0] = mfma16(a0, b0, acc[0][0]);
        acc[0][1] = mfma16(a0, b1, acc[0][1]);
        acc[1][0] = mfma16(a1, b0, acc[1][0]);
        acc[1][1] = mfma16(a1, b1, acc[1][1]);
    }
    float* base = kvf + (size_t)bh*4096;
    #pragma unroll
    for (int mi = 0; mi < 2; ++mi)
        #pragma unroll
        for (int ni = 0; ni < 2; ++ni)
            #pragma unroll
            for (int r = 0; r < 4; ++r)
                atomicAdd(base + (wm + mi*16 + kg*4 + r)*64 + wn + ni*16 + li,
                          acc[mi][ni][r]);
}

// ---------------- M2T[b][n][h*64+d] = bf16( (1/8) sum_e kv[b,h,d,e] * ow[h*64+e][n] ) ----------------
__global__ __launch_bounds__(256) void m2_kernel(const float* __restrict__ kvf,
        const float* __restrict__ ow, u16* __restrict__ m2t) {
    __shared__ float kvs[64][64];
    const int bh = blockIdx.x;
    const int b = bh >> 2, h = bh & 3;
    const int tid = threadIdx.x;          // n = tid
    #pragma unroll
    for (int p = 0; p < 16; ++p)
        ((float*)kvs)[p*256 + tid] = kvf[(size_t)bh*4096 + p*256 + tid];
    __syncthreads();
    float acc[64];
    #pragma unroll
    for (int d = 0; d < 64; ++d) acc[d] = 0.f;
    for (int e = 0; e < 64; ++e) {
        float w = ow[(size_t)(h*64 + e)*256 + tid];
        #pragma unroll
        for (int d = 0; d < 64; ++d) acc[d] += kvs[d][e] * w;
    }
    u16* dst = m2t + ((size_t)b*256 + tid)*256 + h*64;
    #pragma unroll
    for (int d = 0; d < 64; ++d) dst[d] = f2bf(acc[d]*0.125f);
}

// ---------------- LAST-LAYER TAIL: per CLS row (l=0), fused attnO + LN2 + MLP ----------------
// Only x[b*L+0] is read after the last layer (head uses the CLS row only), so the
// last layer's O-proj / LN2 / W1 / W2 are computed for ONE row per batch.
// One block per chunk-local batch; 256 threads.
__global__ __launch_bounds__(256) void tail_kernel(const u16* __restrict__ Q, int ldq,
        const u16* __restrict__ m2t, float* __restrict__ x,
        const float* __restrict__ g2, const float* __restrict__ bt2,
        const u16* __restrict__ w1T, const float* __restrict__ b1v,
        const u16* __restrict__ w2T, const float* __restrict__ b2v) {
    __shared__ float qrow[256];
    __shared__ float y[256];
    __shared__ float h[1024];
    __shared__ float red[8];
    const int bl = blockIdx.x;             // chunk-local batch
    const int tid = threadIdx.x;
    const size_t row = (size_t)bl * L_;    // chunk-local CLS token row
    // Q row (bf16, stride ldq)
    qrow[tid] = bf2f(Q[row*(size_t)ldq + tid]);
    __syncthreads();
    // attn delta for col tid: dot(Q row, M2T[bl][tid][:])
    const u16* mrow = m2t + ((size_t)bl*256 + tid)*256;
    float acc = 0.f;
    for (int d = 0; d < 256; d += 8) {
        short8 w = *(const short8*)(mrow + d);
        acc += qrow[d+0]*bf2f((u16)w[0]) + qrow[d+1]*bf2f((u16)w[1])
             + qrow[d+2]*bf2f((u16)w[2]) + qrow[d+3]*bf2f((u16)w[3])
             + qrow[d+4]*bf2f((u16)w[4]) + qrow[d+5]*bf2f((u16)w[5])
             + qrow[d+6]*bf2f((u16)w[6]) + qrow[d+7]*bf2f((u16)w[7]);
    }
    float v = x[row*256 + tid] + acc;      // post-attn residual (fp32)
    // LN2 over the 256 values (block reduce, head_kernel pattern)
    float s = v, sq = v*v;
    #pragma unroll
    for (int off = 32; off; off >>= 1) { s += __shfl_xor(s, off); sq += __shfl_xor(sq, off); }
    int wave = tid >> 6, lane = tid & 63;
    if (lane == 0) { red[wave] = s; red[4+wave] = sq; }
    __syncthreads();
    s  = red[0]+red[1]+red[2]+red[3];
    sq = red[4]+red[5]+red[6]+red[7];
    float mean = s*(1.f/256.f), var = sq*(1.f/256.f) - mean*mean;
    float rstd = rsqrtf(var + 1e-5f);
    y[tid] = (v - mean)*rstd*g2[tid] + bt2[tid];
    __syncthreads();
    // W1 + GELU: 4 hidden units per thread
    #pragma unroll
    for (int jj = 0; jj < 4; ++jj) {
        int j = tid*4 + jj;
        const u16* wrow = w1T + (size_t)j*256;
        float a = b1v[j];
        for (int k = 0; k < 256; k += 8) {
            short8 w = *(const short8*)(wrow + k);
            a += y[k+0]*bf2f((u16)w[0]) + y[k+1]*bf2f((u16)w[1])
               + y[k+2]*bf2f((u16)w[2]) + y[k+3]*bf2f((u16)w[3])
               + y[k+4]*bf2f((u16)w[4]) + y[k+5]*bf2f((u16)w[5])
               + y[k+6]*bf2f((u16)w[6]) + y[k+7]*bf2f((u16)w[7]);
        }
        h[j] = gelu_fast(a);
    }
    __syncthreads();
    // W2: col tid
    const u16* w2row = w2T + (size_t)tid*1024;
    float a2 = b2v[tid];
    for (int k = 0; k < 1024; k += 8) {
        short8 w = *(const short8*)(w2row + k);
        a2 += h[k+0]*bf2f((u16)w[0]) + h[k+1]*bf2f((u16)w[1])
            + h[k+2]*bf2f((u16)w[2]) + h[k+3]*bf2f((u16)w[3])
            + h[k+4]*bf2f((u16)w[4]) + h[k+5]*bf2f((u16)w[5])
            + h[k+6]*bf2f((u16)w[6]) + h[k+7]*bf2f((u16)w[7]);
    }
    x[row*256 + tid] = v + a2;             // final CLS-row value for head
}

// ---------------- head ----------------
__global__ void head_kernel(const float* __restrict__ x, const float* __restrict__ obs,
                            const float* __restrict__ fng, const float* __restrict__ fnb,
                            const float* __restrict__ ow, const float* __restrict__ ob,
                            float* __restrict__ out) {
    __shared__ float row[D_ + ADIM_];
    __shared__ float red[8];
    int b = blockIdx.x, tid = threadIdx.x;
    float v = x[((size_t)b*L_)*D_ + tid];
    float s = v, sq = v*v;
    #pragma unroll
    for (int off = 32; off; off >>= 1) { s += __shfl_xor(s, off); sq += __shfl_xor(sq, off); }
    int wave = tid >> 6, lane = tid & 63;
    if (lane == 0) { red[wave] = s; red[4+wave] = sq; }
    __syncthreads();
    s  = red[0]+red[1]+red[2]+red[3];
    sq = red[4]+red[5]+red[6]+red[7];
    float mean = s*(1.f/D_), var = sq*(1.f/D_) - mean*mean;
    float r = rsqrtf(var + 1e-5f);
    row[tid] = (v-mean)*r*fng[tid] + fnb[tid];
    if (tid < ADIM_) row[D_+tid] = obs[(size_t)b*OBSROW + VIS_ + tid];
    __syncthreads();
    float acc = ob[tid];
    for (int j = 0; j < D_+ADIM_; ++j) acc += row[j]*ow[j*OUT_ + tid];
    out[(size_t)b*OUT_ + tid] = acc;
}

// ---------------- launch ----------------
extern "C" void kernel_launch(void* const* d_in, const int* in_sizes, int n_in,
                              void* d_out, int out_size, void* d_ws, size_t ws_size,
                              hipStream_t stream) {
    const float* obs   = (const float*)d_in[0];
    const float* pw    = (const float*)d_in[1];
    const float* pb    = (const float*)d_in[2];
    const float* cls   = (const float*)d_in[3];
    const float* qw    = (const float*)d_in[4];
    const float* kw    = (const float*)d_in[5];
    const float* vw    = (const float*)d_in[6];
    const float* oww   = (const float*)d_in[7];
    const float* gq    = (const float*)d_in[8];
    const float* bq    = (const float*)d_in[9];
    const float* gk    = (const float*)d_in[10];
    const float* bk    = (const float*)d_in[11];
    const float* n1g   = (const float*)d_in[12];
    const float* n1b   = (const float*)d_in[13];
    const float* n2g   = (const float*)d_in[14];
    const float* n2b   = (const float*)d_in[15];
    const float* w1    = (const float*)d_in[16];
    const float* b1    = (const float*)d_in[17];
    const float* w2    = (const float*)d_in[18];
    const float* b2    = (const float*)d_in[19];
    const float* fng   = (const float*)d_in[20];
    const float* fnb   = (const float*)d_in[21];
    const float* outw  = (const float*)d_in[22];
    const float* outb  = (const float*)d_in[23];

    // ---- workspace layout ----
    float* x = (float*)d_ws;                               // NTOK*256 fp32
    u16* qkvT = (u16*)(x + (size_t)NTOK*D_);               // [NL][768][256]
    u16* w1T  = qkvT + (size_t)NL_*768*256;                // [NL][1024][256]
    u16* w2T  = w1T  + (size_t)NL_*262144;                 // [NL][256][1024]
    float* tab = (float*)(w2T + (size_t)NL_*262144);       // L*32*2 fp32
    u16* bufs = (u16*)(tab + (size_t)L_*32*2);

    size_t fixedB = (size_t)((char*)bufs - (char*)d_ws);
    auto needed = [&](int nb) -> size_t {
        size_t t = (size_t)nb * L_;
        return fixedB + (t*256 + (size_t)PADR*256)*2 + (t*1024 + (size_t)PADR*1024)*2
               + (size_t)nb*65536*2 + (size_t)nb*NH_*4096*4;
    };
    int nbc = 32;
    while (nbc > 1 && needed(nbc) > ws_size) nbc >>= 1;
    const int nch = B_ / nbc;
    const int RCn = nbc * L_;

    u16* Xn   = bufs;                                           // nb*L*256 (+pad)
    u16* QKVc = Xn + (size_t)RCn*256 + (size_t)PADR*256;        // ld=768 view
    u16* Hc   = QKVc;                                           // ld=1024 view (same region)
    u16* M2T  = QKVc + (size_t)RCn*1024 + (size_t)PADR*1024;    // nb*256*256
    float* kvf = (float*)(M2T + (size_t)nbc*65536);             // nb*4*4096 f32

    // ---- setup ----
    wcvt_kernel<<<(NL_*65536 + 255)/256, 256, 0, stream>>>(qw,  qkvT, 256, 256, 768*256, 0);
    wcvt_kernel<<<(NL_*65536 + 255)/256, 256, 0, stream>>>(kw,  qkvT, 256, 256, 768*256, 256);
    wcvt_kernel<<<(NL_*65536 + 255)/256, 256, 0, stream>>>(vw,  qkvT, 256, 256, 768*256, 512);
    wcvt_kernel<<<(NL_*262144 + 255)/256, 256, 0, stream>>>(w1, w1T, 1024, 256, 262144, 0);
    wcvt_kernel<<<(NL_*262144 + 255)/256, 256, 0, stream>>>(w2, w2T, 256, 1024, 262144, 0);
    rope_table_kernel<<<(L_*32 + 255)/256, 256, 0, stream>>>(tab);
    proj_kernel<<<(NTOK + 3)/4, 256, 0, stream>>>(obs, pw, pb, cls, x);

    const int gy  = (RCn + 127)/128;
    const int lnb = (RCn + 3)/4;
    const int nbh = nbc*NH_;

    // chunk OUTER, layer INNER: all Xn/QKVc/Hc/M2T/kvf state is consumed within
    // one chunk iteration, so the cross-layer Xn carry is race-free.
    for (int c = 0; c < nch; ++c) {
        float* xc = x + (size_t)c*RCn*D_;
        ln_f2b_kernel<<<lnb, 256, 0, stream>>>(xc, n1g, n1b, Xn, RCn);

        for (int layer = 0; layer < NL_; ++layer) {
            const u16* qkvT_l = qkvT + (size_t)layer*768*256;
            const u16* w1T_l  = w1T  + (size_t)layer*262144;
            const u16* w2T_l  = w2T  + (size_t)layer*262144;
            const float* ow_l = oww + (size_t)layer*65536;
            const float* b1_l = b1 + (size_t)layer*1024;
            const float* b2_l = b2 + (size_t)layer*D_;

            // QKV: wide tile (3 x 256-col tiles, large grid)
            gemm_wide<0,false><<<dim3(3, gy), 512, 0, stream>>>(Xn, 256, qkvT_l, nullptr, QKVc, RCn, 768, 256, 768);
            lnrope_kernel<<<dim3(lnb, 2), 256, 0, stream>>>(QKVc, gq + layer*D_, bq + layer*D_,
                                                            gk + layer*D_, bk + layer*D_, tab, RCn, 768);
            zero_kernel<<<(nbh*4096 + 255)/256, 256, 0, stream>>>(kvf, nbh*4096);
            kv_mfma_kernel<<<dim3(nbh, KV_LSPLIT), 256, 0, stream>>>(QKVc + 256, QKVc + 512, kvf, 768);
            m2_kernel<<<nbh, 256, 0, stream>>>(kvf, ow_l, M2T);

            if (layer < NL_-1) {
                // attn+O-proj delta (narrow, per-batch) -> Xn; x += delta; LN2
                gemm_bf16<0,true><<<dim3(2, 24, nbc), 256, 0, stream>>>(QKVc, 768, M2T, nullptr, Xn, nullptr, L_, 256, 256, 256);
                lnres_kernel<<<lnb, 256, 0, stream>>>(xc, Xn, n2g + layer*D_, n2b + layer*D_, RCn);
                // MLP: W1 wide (+bias,GELU) -> Hc; W2 narrow delta(+bias) -> Xn
                gemm_wide<1,false><<<dim3(4, gy), 512, 0, stream>>>(Xn, 256, w1T_l, b1_l, Hc, RCn, 1024, 256, 1024);
                gemm_bf16<4,false><<<dim3(2, gy), 256, 0, stream>>>(Hc, 1024, w2T_l, b2_l, Xn, nullptr, RCn, 256, 1024, 256);
                lnres_kernel<<<lnb, 256, 0, stream>>>(xc, Xn, n1g + (layer+1)*D_, n1b + (layer+1)*D_, RCn);
            } else {
                // LAST LAYER: only the CLS row (l=0) of each batch is ever read again.
                tail_kernel<<<nbc, 256, 0, stream>>>(QKVc, 768, M2T, xc,
                                                     n2g + layer*D_, n2b + layer*D_,
                                                     w1T_l, b1_l, w2T_l, b2_l);
            }
        }
    }

    head_kernel<<<B_, 256, 0, stream>>>(x, obs, fng, fnb, outw, outb, (float*)d_out);
}

// Round 24
// 2245.054 us; speedup vs baseline: 1.3615x; 1.0074x over previous
//
#include <hip/hip_runtime.h>
#include <math.h>

typedef unsigned short u16;
typedef __attribute__((ext_vector_type(8))) short short8;
typedef __attribute__((ext_vector_type(4))) short short4v;
typedef __attribute__((ext_vector_type(4))) float f32x4;

// ---------------- problem constants ----------------
constexpr int B_    = 32;
constexpr int HIST_ = 10, C_ = 11, H_ = 15, W_ = 20;
constexpr int D_    = 256, NH_ = 4, NL_ = 4, HD_ = 64;
constexpr int OUT_  = 256, ADIM_ = 20;
constexpr int L_    = HIST_*H_*W_ + 1;      // 3001
constexpr int VIS_  = HIST_*C_*H_*W_;       // 33000
constexpr int NTOK  = B_*L_;                // 96032
constexpr int OBSROW = VIS_ + ADIM_;        // 33020
constexpr int PADR  = 128;                  // pad rows so tile DMA stays in-bounds

// ---------------- bf16 helpers ----------------
__device__ __forceinline__ float bf2f(u16 u) {
    return __uint_as_float(((unsigned)u) << 16);
}
__device__ __forceinline__ u16 f2bf(float f) {
    unsigned u = __float_as_uint(f);
    u = u + 0x7FFFu + ((u >> 16) & 1u);
    return (u16)(u >> 16);
}
__device__ __forceinline__ f32x4 mfma16(short8 a, short8 b, f32x4 c) {
    return __builtin_amdgcn_mfma_f32_16x16x32_bf16(a, b, c, 0, 0, 0);
}
__device__ __forceinline__ void gload16(const u16* gsrc, u16* ldsdst) {
    __builtin_amdgcn_global_load_lds(
        (const __attribute__((address_space(1))) unsigned int*)gsrc,
        (__attribute__((address_space(3))) unsigned int*)ldsdst,
        16, 0, 0);
}
// tanh-form GELU: ~9 VALU ops (one v_exp). |err| <= ~3e-4.
__device__ __forceinline__ float gelu_fast(float v) {
    float t2 = 1.5957691216f*(v + 0.044715f*v*v*v);
    return v / (1.f + __expf(-t2));
}

// ---------------- setup kernels ----------------
__global__ void zero_kernel(float* __restrict__ p, int n) {
    int i = blockIdx.x*256 + threadIdx.x;
    if (i < n) p[i] = 0.f;
}

// dst[l][dstOff+n][k] = bf16(src[l][k][n]); dst layer stride dstLS
__global__ void wcvt_kernel(const float* __restrict__ src, u16* __restrict__ dst,
                            int Nn, int Kk, int dstLS, int dstOff) {
    int idx = blockIdx.x*256 + threadIdx.x;
    int tot = NL_*Nn*Kk;
    if (idx >= tot) return;
    int l = idx / (Nn*Kk);
    int rem = idx % (Nn*Kk);
    int n = rem / Kk, k = rem % Kk;
    dst[(size_t)l*dstLS + (size_t)(dstOff+n)*Kk + k] = f2bf(src[(size_t)l*Kk*Nn + (size_t)k*Nn + n]);
}

__global__ void rope_table_kernel(float* __restrict__ tab) {
    int idx = blockIdx.x*256 + threadIdx.x;
    if (idx >= L_*32) return;
    int t = idx >> 5, i = idx & 31;
    float freq = powf(10000.f, -2.f*(float)i/(float)HD_);
    float ang = (float)t * freq;
    tab[idx*2]   = cosf(ang);
    tab[idx*2+1] = sinf(ang);
}

// 4 tokens/block (1 per wave); lane owns 4 cols; float4 loads/stores.
__global__ __launch_bounds__(256) void proj_kernel(const float* __restrict__ obs,
        const float* __restrict__ pw, const float* __restrict__ pb,
        const float* __restrict__ cls, float* __restrict__ x) {
    int wave = threadIdx.x >> 6, lane = threadIdx.x & 63;
    int n = blockIdx.x*4 + wave;
    if (n >= NTOK) return;
    int b = n / L_, l = n % L_;
    float4 acc;
    if (l == 0) {
        acc = ((const float4*)cls)[lane];
    } else {
        int t = l - 1;
        int hist = t / (H_*W_);
        int rem  = t % (H_*W_);
        float vv = 0.f;
        if (lane < C_) vv = obs[(size_t)b*OBSROW + hist*(C_*H_*W_) + lane*(H_*W_) + rem];
        acc = ((const float4*)pb)[lane];
        #pragma unroll
        for (int c = 0; c < C_; ++c) {
            float vc = __shfl(vv, c);
            float4 w4 = ((const float4*)(pw + c*D_))[lane];
            acc.x += vc*w4.x; acc.y += vc*w4.y; acc.z += vc*w4.z; acc.w += vc*w4.w;
        }
    }
    ((float4*)(x + (size_t)n*D_))[lane] = acc;
}

// ---------------- LayerNorm fp32 -> bf16 (layer-0 LN1 per chunk) ----------------
__global__ __launch_bounds__(256) void ln_f2b_kernel(const float* __restrict__ in,
        const float* __restrict__ g, const float* __restrict__ bt,
        u16* __restrict__ out, int ntok) {
    int wave = threadIdx.x >> 6, lane = threadIdx.x & 63;
    int n = blockIdx.x*4 + wave;
    if (n >= ntok) return;
    float4 v = ((const float4*)(in + (size_t)n*D_))[lane];
    float s  = v.x + v.y + v.z + v.w;
    float sq = v.x*v.x + v.y*v.y + v.z*v.z + v.w*v.w;
    #pragma unroll
    for (int off = 32; off; off >>= 1) { s += __shfl_xor(s, off); sq += __shfl_xor(sq, off); }
    float mean = s * (1.f/D_);
    float var  = sq * (1.f/D_) - mean*mean;
    float r = rsqrtf(var + 1e-5f);
    float4 gg = ((const float4*)g)[lane];
    float4 bb = ((const float4*)bt)[lane];
    short4v o;
    o.x = (short)f2bf((v.x-mean)*r*gg.x + bb.x);
    o.y = (short)f2bf((v.y-mean)*r*gg.y + bb.y);
    o.z = (short)f2bf((v.z-mean)*r*gg.z + bb.z);
    o.w = (short)f2bf((v.w-mean)*r*gg.w + bb.w);
    *(short4v*)(out + (size_t)n*D_ + lane*4) = o;
}

// ---------------- residual add + LayerNorm: x += delta(bf16); Xn = LN(x) ----------------
// CHUNK-LOCAL only — safe under nch>1 with the chunk-OUTER loop.
__global__ __launch_bounds__(256) void lnres_kernel(float* __restrict__ x,
        u16* __restrict__ dx, const float* __restrict__ g, const float* __restrict__ bt,
        int ntok) {
    int wave = threadIdx.x >> 6, lane = threadIdx.x & 63;
    int n = blockIdx.x*4 + wave;
    if (n >= ntok) return;
    float4 v = ((const float4*)(x + (size_t)n*D_))[lane];
    short4v d = *(const short4v*)(dx + (size_t)n*D_ + lane*4);
    v.x += bf2f((u16)d.x); v.y += bf2f((u16)d.y);
    v.z += bf2f((u16)d.z); v.w += bf2f((u16)d.w);
    ((float4*)(x + (size_t)n*D_))[lane] = v;
    float s  = v.x + v.y + v.z + v.w;
    float sq = v.x*v.x + v.y*v.y + v.z*v.z + v.w*v.w;
    #pragma unroll
    for (int off = 32; off; off >>= 1) { s += __shfl_xor(s, off); sq += __shfl_xor(sq, off); }
    float mean = s * (1.f/D_);
    float var  = sq * (1.f/D_) - mean*mean;
    float r = rsqrtf(var + 1e-5f);
    float4 gg = ((const float4*)g)[lane];
    float4 bb = ((const float4*)bt)[lane];
    short4v o;
    o.x = (short)f2bf((v.x-mean)*r*gg.x + bb.x);
    o.y = (short)f2bf((v.y-mean)*r*gg.y + bb.y);
    o.z = (short)f2bf((v.z-mean)*r*gg.z + bb.z);
    o.w = (short)f2bf((v.w-mean)*r*gg.w + bb.w);
    *(short4v*)(dx + (size_t)n*D_ + lane*4) = o;
}

// ---------------- fused LN + RoPE + SiLU (merged Q/K: blockIdx.y selects) ----------------
__global__ __launch_bounds__(256) void lnrope_kernel(u16* __restrict__ qk,
        const float* __restrict__ gq, const float* __restrict__ bq,
        const float* __restrict__ gk, const float* __restrict__ bk,
        const float* __restrict__ tab, int ntok, int ld) {
    u16* q = qk + blockIdx.y*256;                  // y=0 -> Q, y=1 -> K
    const float* g  = blockIdx.y ? gk : gq;
    const float* bt = blockIdx.y ? bk : bq;
    int wave = threadIdx.x >> 6, lane = threadIdx.x & 63;
    int n = blockIdx.x*4 + wave;
    if (n >= ntok) return;
    int l = n % L_;
    short4v raw = *(const short4v*)(q + (size_t)n*ld + lane*4);
    float v0 = bf2f((u16)raw.x), v1 = bf2f((u16)raw.y), v2 = bf2f((u16)raw.z), v3 = bf2f((u16)raw.w);
    float s  = v0+v1+v2+v3;
    float sq = v0*v0+v1*v1+v2*v2+v3*v3;
    #pragma unroll
    for (int off = 32; off; off >>= 1) { s += __shfl_xor(s, off); sq += __shfl_xor(sq, off); }
    float mean = s * (1.f/D_);
    float var  = sq * (1.f/D_) - mean*mean;
    float r = rsqrtf(var + 1e-5f);
    float4 gg = ((const float4*)g)[lane];
    float4 bb = ((const float4*)bt)[lane];
    float o0 = (v0-mean)*r*gg.x + bb.x;
    float o1 = (v1-mean)*r*gg.y + bb.y;
    float o2 = (v2-mean)*r*gg.z + bb.z;
    float o3 = (v3-mean)*r*gg.w + bb.w;
    float p0 = __shfl_xor(o0, 8), p1 = __shfl_xor(o1, 8);
    float p2 = __shfl_xor(o2, 8), p3 = __shfl_xor(o3, 8);
    bool first = (lane & 15) < 8;
    const float4* tp = (const float4*)(tab + ((size_t)l*32 + (lane&7)*4)*2);
    float4 t01 = tp[0], t23 = tp[1];
    float r0 = first ? o0*t01.x - p0*t01.y : o0*t01.x + p0*t01.y;
    float r1 = first ? o1*t01.z - p1*t01.w : o1*t01.z + p1*t01.w;
    float r2 = first ? o2*t23.x - p2*t23.y : o2*t23.x + p2*t23.y;
    float r3 = first ? o3*t23.z - p3*t23.w : o3*t23.z + p3*t23.w;
    r0 = r0 / (1.f + expf(-r0));
    r1 = r1 / (1.f + expf(-r1));
    r2 = r2 / (1.f + expf(-r2));
    r3 = r3 / (1.f + expf(-r3));
    short4v o;
    o.x = (short)f2bf(r0); o.y = (short)f2bf(r1);
    o.z = (short)f2bf(r2); o.w = (short)f2bf(r3);
    *(short4v*)(q + (size_t)n*ld + lane*4) = o;
}

// ---------------- bf16 MFMA GEMM (PROVEN core): 128x128, BK=64, single-buffer ----------------
// EPI: 0 bf16 out; 1 +bias,GELU,bf16; 4 +bias, bf16 out
template<int EPI, bool PB>
__global__ __launch_bounds__(256) void gemm_bf16(const u16* __restrict__ A, int lda,
        const u16* __restrict__ Wt, const float* __restrict__ bias,
        u16* __restrict__ Cb, float* __restrict__ Xres, int M, int N, int K, int ldc) {
    __shared__ u16 As[2*128*32];
    __shared__ u16 Bs[2*128*32];
    const int gx = gridDim.x;
    int n = blockIdx.y * gx + blockIdx.x;
    const int nwg = gx * gridDim.y;
    if ((nwg & 7) == 0) n = (n & 7) * (nwg >> 3) + (n >> 3);
    const int bx = n % gx, by = n / gx;
    const int row0 = by*128, col0 = bx*128;

    size_t zrow = 0;
    if (PB) {
        int z = blockIdx.z;
        A  += (size_t)z * M * lda;
        Wt += (size_t)z * N * K;
        zrow = (size_t)z * M;
    }

    const int tid = threadIdx.x;
    const int wid = tid >> 6, lane = tid & 63;
    const int wr = wid >> 1, wc = wid & 1;

    f32x4 acc[4][4];
    #pragma unroll
    for (int i = 0; i < 4; ++i)
        #pragma unroll
        for (int j = 0; j < 4; ++j) {
            f32x4 z; z.x = 0.f; z.y = 0.f; z.z = 0.f; z.w = 0.f;
            acc[i][j] = z;
        }

    const int r0s = wid*32 + (lane>>2);
    const int r1s = r0s + 16;
    const int s0 = ((lane&3) - (r0s>>1)) & 3;
    const int s1 = ((lane&3) - (r1s>>1)) & 3;
    const u16* a0p = A  + (size_t)(row0 + r0s)*lda + s0*8;
    const u16* a1p = A  + (size_t)(row0 + r1s)*lda + s1*8;
    const u16* b0p = Wt + (size_t)(col0 + r0s)*K + s0*8;
    const u16* b1p = Wt + (size_t)(col0 + r1s)*K + s1*8;
    u16* lA0 = As + (wid*2+0)*512;
    u16* lA1 = As + (wid*2+1)*512;
    u16* lB0 = Bs + (wid*2+0)*512;
    u16* lB1 = Bs + (wid*2+1)*512;

    const int kg = lane >> 4, li = lane & 15;
    int aoff[4], boff[4];
    #pragma unroll
    for (int mi = 0; mi < 4; ++mi) {
        int row = wr*64 + mi*16 + li;
        aoff[mi] = row*32 + ((kg + (row>>1)) & 3)*8;
    }
    #pragma unroll
    for (int ni = 0; ni < 4; ++ni) {
        int row = wc*64 + ni*16 + li;
        boff[ni] = row*32 + ((kg + (row>>1)) & 3)*8;
    }

    auto stage = [&](int k0) {
        #pragma unroll
        for (int t = 0; t < 2; ++t) {
            const int ko = k0 + t*32;
            const int lo = t*4096;
            gload16(a0p + ko, lA0 + lo); gload16(a1p + ko, lA1 + lo);
            gload16(b0p + ko, lB0 + lo); gload16(b1p + ko, lB1 + lo);
        }
    };

    stage(0);
    const int nk2 = K >> 6;
    for (int ks = 0; ks < nk2; ++ks) {
        __syncthreads();
        short8 af[2][4], bfr[2][4];
        #pragma unroll
        for (int t = 0; t < 2; ++t) {
            #pragma unroll
            for (int mi = 0; mi < 4; ++mi) af[t][mi] = *(const short8*)(As + t*4096 + aoff[mi]);
            #pragma unroll
            for (int ni = 0; ni < 4; ++ni) bfr[t][ni] = *(const short8*)(Bs + t*4096 + boff[ni]);
        }
        __syncthreads();
        if (ks + 1 < nk2) stage((ks + 1) << 6);
        #pragma unroll
        for (int t = 0; t < 2; ++t)
            #pragma unroll
            for (int mi = 0; mi < 4; ++mi)
                #pragma unroll
                for (int ni = 0; ni < 4; ++ni)
                    acc[mi][ni] = mfma16(af[t][mi], bfr[t][ni], acc[mi][ni]);
    }

    #pragma unroll
    for (int mi = 0; mi < 4; ++mi) {
        int rbase = row0 + wr*64 + mi*16 + kg*4;
        #pragma unroll
        for (int ni = 0; ni < 4; ++ni) {
            int col = col0 + wc*64 + ni*16 + li;
            #pragma unroll
            for (int r = 0; r < 4; ++r) {
                int row = rbase + r;
                if (row >= M) continue;
                float v = acc[mi][ni][r];
                if (EPI == 1 || EPI == 4) v += bias[col];
                if (EPI == 1) v = gelu_fast(v);
                Cb[(zrow + row)*(size_t)ldc + col] = f2bf(v);
            }
        }
    }
}

// ---------------- WIDE GEMM: 128x256 tile, 512 thr (used where grid stays large) ----------------
// Stat-free epilogues. BK=64 (2 subtiles), single-buffered (48 KB LDS).
// EPI: 0 bf16; 1 +bias,GELU.
template<int EPI, bool PB>
__global__ __launch_bounds__(512) void gemm_wide(const u16* __restrict__ A, int lda,
        const u16* __restrict__ Wt, const float* __restrict__ bias,
        u16* __restrict__ Cb, int M, int N, int K, int ldc) {
    __shared__ u16 As[2*4096];             // [subtile][128*32]
    __shared__ u16 Bs[2*8192];             // [subtile][256*32]
    const int gx = gridDim.x;
    int n = blockIdx.y * gx + blockIdx.x;
    const int nwg = gx * gridDim.y;
    if ((nwg & 7) == 0) n = (n & 7) * (nwg >> 3) + (n >> 3);
    const int bx = n % gx, by = n / gx;
    const int row0 = by*128, col0 = bx*256;

    size_t zrow = 0;
    if (PB) {
        int z = blockIdx.z;
        A  += (size_t)z * M * lda;
        Wt += (size_t)z * N * K;
        zrow = (size_t)z * M;
    }

    const int tid = threadIdx.x;
    const int wid = tid >> 6, lane = tid & 63;
    const int kg = lane >> 4, li = lane & 15;

    f32x4 acc[16];
    #pragma unroll
    for (int i = 0; i < 16; ++i) { f32x4 z; z.x=0.f; z.y=0.f; z.z=0.f; z.w=0.f; acc[i]=z; }

    const int ra = wid*16 + (lane>>2);
    const int sa = ((lane&3) - (ra>>1)) & 3;
    const u16* agp = A + (size_t)(row0 + ra)*lda + sa*8;
    const int lAo = wid*512;
    const int rb0 = (wid*2+0)*16 + (lane>>2);
    const int rb1 = (wid*2+1)*16 + (lane>>2);
    const int sb0 = ((lane&3) - (rb0>>1)) & 3;
    const int sb1 = ((lane&3) - (rb1>>1)) & 3;
    const u16* bgp0 = Wt + (size_t)(col0 + rb0)*K + sb0*8;
    const u16* bgp1 = Wt + (size_t)(col0 + rb1)*K + sb1*8;
    const int lB0o = (wid*2+0)*512;
    const int lB1o = (wid*2+1)*512;

    const int arow = wid*16 + li;
    const int aoff = arow*32 + ((kg + (arow>>1)) & 3)*8;
    int boff[16];
    #pragma unroll
    for (int ni = 0; ni < 16; ++ni) {
        int row = ni*16 + li;
        boff[ni] = row*32 + ((kg + (row>>1)) & 3)*8;
    }

    auto stage = [&](int k0) {
        #pragma unroll
        for (int t = 0; t < 2; ++t) {
            const int ko = k0 + t*32;
            gload16(agp  + ko, As + t*4096 + lAo);
            gload16(bgp0 + ko, Bs + t*8192 + lB0o);
            gload16(bgp1 + ko, Bs + t*8192 + lB1o);
        }
    };

    stage(0);
    const int nk2 = K >> 6;
    for (int ks = 0; ks < nk2; ++ks) {
        __syncthreads();                    // DMA for this 64-K tile drained
        short8 af0 = *(const short8*)(As + aoff);
        short8 b0[8], b1[8];
        #pragma unroll
        for (int ni = 0; ni < 8; ++ni) b0[ni] = *(const short8*)(Bs + boff[ni]);
        #pragma unroll
        for (int ni = 0; ni < 8; ++ni) acc[ni] = mfma16(af0, b0[ni], acc[ni]);
        #pragma unroll
        for (int ni = 0; ni < 8; ++ni) b1[ni] = *(const short8*)(Bs + boff[8+ni]);
        #pragma unroll
        for (int ni = 0; ni < 8; ++ni) acc[8+ni] = mfma16(af0, b1[ni], acc[8+ni]);
        short8 af1 = *(const short8*)(As + 4096 + aoff);
        #pragma unroll
        for (int ni = 0; ni < 8; ++ni) b0[ni] = *(const short8*)(Bs + 8192 + boff[ni]);
        #pragma unroll
        for (int ni = 0; ni < 8; ++ni) b1[ni] = *(const short8*)(Bs + 8192 + boff[8+ni]);
        __syncthreads();                    // reads done; LDS reusable
        if (ks + 1 < nk2) stage((ks + 1) << 6);
        #pragma unroll
        for (int ni = 0; ni < 8; ++ni) acc[ni]   = mfma16(af1, b0[ni], acc[ni]);
        #pragma unroll
        for (int ni = 0; ni < 8; ++ni) acc[8+ni] = mfma16(af1, b1[ni], acc[8+ni]);
    }

    #pragma unroll
    for (int r = 0; r < 4; ++r) {
        const int row = row0 + wid*16 + kg*4 + r;
        if (row >= M) continue;
        #pragma unroll
        for (int ni = 0; ni < 16; ++ni) {
            int col = col0 + ni*16 + li;
            float v = acc[ni][r];
            if (EPI == 1) { v += bias[col]; v = gelu_fast(v); }
            Cb[(zrow + row)*(size_t)ldc + col] = f2bf(v);
        }
    }
}

// ---------------- kv = K^T V per (b,h) via MFMA (atomic merge, proven) ----------------
constexpr int KV_LSPLIT = 4;
constexpr int KV_PART   = 768;            // 24 tiles of 32; 4*768 >= L_
__global__ __launch_bounds__(256) void kv_mfma_kernel(const u16* __restrict__ Kt,
        const u16* __restrict__ Vt, float* __restrict__ kvf, int ld) {
    __shared__ u16 kT[64][34];            // [d][l'] transposed, pad 2
    __shared__ u16 vT[64][34];
    const int bh = blockIdx.x;
    const int b = bh >> 2, h = bh & 3;
    const int tid = threadIdx.x;
    const int wid = tid >> 6, lane = tid & 63;
    const int kg = lane >> 4, li = lane & 15;
    const int wm = (wid >> 1)*32, wn = (wid & 1)*32;
    const int sl = tid >> 3;              // 0..31
    const int sd = (tid & 7) * 8;
    const u16* kbase = Kt + ((size_t)b*L_)*ld + h*HD_ + sd;
    const u16* vbase = Vt + ((size_t)b*L_)*ld + h*HD_ + sd;

    f32x4 acc[2][2];
    #pragma unroll
    for (int i = 0; i < 2; ++i)
        #pragma unroll
        for (int j = 0; j < 2; ++j) {
            f32x4 z; z.x=0.f; z.y=0.f; z.z=0.f; z.w=0.f; acc[i][j] = z;
        }

    const int l0p = blockIdx.y * KV_PART;
    for (int t = 0; t < KV_PART/32; ++t) {
        int gl = l0p + t*32 + sl;
        short8 kk = {0,0,0,0,0,0,0,0}, vv = {0,0,0,0,0,0,0,0};
        if (gl < L_) {
            kk = *(const short8*)(kbase + (size_t)gl*ld);
            vv = *(const short8*)(vbase + (size_t)gl*ld);
        }
        __syncthreads();
        #pragma unroll
        for (int j = 0; j < 8; ++j) {
            kT[sd+j][sl] = (u16)kk[j];
            vT[sd+j][sl] = (u16)vv[j];
        }
        __syncthreads();
        short8 a0, a1, b0, b1;
        {
            uint* d0 = (uint*)&a0; const uint* p0 = (const uint*)&kT[wm + li][kg*8];
            uint* d1 = (uint*)&a1; const uint* p1 = (const uint*)&kT[wm + 16 + li][kg*8];
            uint* d2 = (uint*)&b0; const uint* p2 = (const uint*)&vT[wn + li][kg*8];
            uint* d3 = (uint*)&b1; const uint* p3 = (const uint*)&vT[wn + 16 + li][kg*8];
            #pragma unroll
            for (int j = 0; j < 4; ++j) { d0[j]=p0[j]; d1[j]=p1[j]; d2[j]=p2[j]; d3[j]=p3[j]; }
        }
        acc[0][0] = mfma16(a0, b0, acc[0][0]);
        acc[0][1] = mfma16(a0, b1, acc[0][1]);
        acc[1][0] = mfma16(a1, b0, acc[1][0]);
        acc[1][1] = mfma16(a1, b1, acc[1][1]);
    }
    float* base = kvf + (size_t)bh*4096;
    #pragma unroll
    for (int mi = 0; mi < 2; ++mi)
        #pragma unroll
        for (int ni = 0; ni < 2; ++ni)
            #pragma unroll
            for (int r = 0; r < 4; ++r)
                atomicAdd(base + (wm + mi*16 + kg*4 + r)*64 + wn + ni*16 + li,
                          acc[mi][ni][r]);
}

// ---------------- M2T[b][n][h*64+d] = bf16( (1/8) sum_e kv[b,h,d,e] * ow[h*64+e][n] ) ----------------
__global__ __launch_bounds__(256) void m2_kernel(const float* __restrict__ kvf,
        const float* __restrict__ ow, u16* __restrict__ m2t) {
    __shared__ float kvs[64][64];
    const int bh = blockIdx.x;
    const int b = bh >> 2, h = bh & 3;
    const int tid = threadIdx.x;          // n = tid
    #pragma unroll
    for (int p = 0; p < 16; ++p)
        ((float*)kvs)[p*256 + tid] = kvf[(size_t)bh*4096 + p*256 + tid];
    __syncthreads();
    float acc[64];
    #pragma unroll
    for (int d = 0; d < 64; ++d) acc[d] = 0.f;
    for (int e = 0; e < 64; ++e) {
        float w = ow[(size_t)(h*64 + e)*256 + tid];
        #pragma unroll
        for (int d = 0; d < 64; ++d) acc[d] += kvs[d][e] * w;
    }
    u16* dst = m2t + ((size_t)b*256 + tid)*256 + h*64;
    #pragma unroll
    for (int d = 0; d < 64; ++d) dst[d] = f2bf(acc[d]*0.125f);
}

// ---------------- LAST-LAYER TAIL: per CLS row (l=0), fused Q + attnO + LN2 + MLP ----------------
// Only x[b*L+0] is read after the last layer. Q is computed HERE for the CLS row
// only (RoPE is identity at l=0: t=0 -> cos=1, sin=0), so the last layer's QKV
// GEMM skips the Q columns entirely. One block per chunk-local batch; 256 threads.
__global__ __launch_bounds__(256) void tail_kernel(const u16* __restrict__ Xn,
        const u16* __restrict__ qwT,      // [256][256] bf16, n-major (layer's Q weights)
        const float* __restrict__ gqv, const float* __restrict__ bqv,
        const u16* __restrict__ m2t, float* __restrict__ x,
        const float* __restrict__ g2, const float* __restrict__ bt2,
        const u16* __restrict__ w1T, const float* __restrict__ b1v,
        const u16* __restrict__ w2T, const float* __restrict__ b2v) {
    __shared__ float xn0[256];
    __shared__ float qrow[256];
    __shared__ float y[256];
    __shared__ float h[1024];
    __shared__ float red[8];
    const int bl = blockIdx.x;             // chunk-local batch
    const int tid = threadIdx.x;
    const int wave = tid >> 6, lane = tid & 63;
    const size_t row = (size_t)bl * L_;    // chunk-local CLS token row
    // Xn CLS row (bf16, stride 256)
    xn0[tid] = bf2f(Xn[row*256 + tid]);
    __syncthreads();
    // q_raw[tid] = dot(xn0, qwT[tid][:])
    {
        const u16* qwrow = qwT + (size_t)tid*256;
        float qa = 0.f;
        for (int k = 0; k < 256; k += 8) {
            short8 w = *(const short8*)(qwrow + k);
            qa += xn0[k+0]*bf2f((u16)w[0]) + xn0[k+1]*bf2f((u16)w[1])
                + xn0[k+2]*bf2f((u16)w[2]) + xn0[k+3]*bf2f((u16)w[3])
                + xn0[k+4]*bf2f((u16)w[4]) + xn0[k+5]*bf2f((u16)w[5])
                + xn0[k+6]*bf2f((u16)w[6]) + xn0[k+7]*bf2f((u16)w[7]);
        }
        // LN(gq,bq) over q_raw, then SiLU (rope identity at l=0)
        float s = qa, sq = qa*qa;
        #pragma unroll
        for (int off = 32; off; off >>= 1) { s += __shfl_xor(s, off); sq += __shfl_xor(sq, off); }
        if (lane == 0) { red[wave] = s; red[4+wave] = sq; }
        __syncthreads();
        s  = red[0]+red[1]+red[2]+red[3];
        sq = red[4]+red[5]+red[6]+red[7];
        float mean = s*(1.f/256.f), var = sq*(1.f/256.f) - mean*mean;
        float rstd = rsqrtf(var + 1e-5f);
        float qn = (qa - mean)*rstd*gqv[tid] + bqv[tid];
        qrow[tid] = qn / (1.f + __expf(-qn));
    }
    __syncthreads();                       // qrow ready; red reads done (safe to reuse)
    // attn delta for col tid: dot(q row, M2T[bl][tid][:])
    const u16* mrow = m2t + ((size_t)bl*256 + tid)*256;
    float acc = 0.f;
    for (int d = 0; d < 256; d += 8) {
        short8 w = *(const short8*)(mrow + d);
        acc += qrow[d+0]*bf2f((u16)w[0]) + qrow[d+1]*bf2f((u16)w[1])
             + qrow[d+2]*bf2f((u16)w[2]) + qrow[d+3]*bf2f((u16)w[3])
             + qrow[d+4]*bf2f((u16)w[4]) + qrow[d+5]*bf2f((u16)w[5])
             + qrow[d+6]*bf2f((u16)w[6]) + qrow[d+7]*bf2f((u16)w[7]);
    }
    float v = x[row*256 + tid] + acc;      // post-attn residual (fp32)
    // LN2 over the 256 values (block reduce)
    float s = v, sq = v*v;
    #pragma unroll
    for (int off = 32; off; off >>= 1) { s += __shfl_xor(s, off); sq += __shfl_xor(sq, off); }
    if (lane == 0) { red[wave] = s; red[4+wave] = sq; }
    __syncthreads();
    s  = red[0]+red[1]+red[2]+red[3];
    sq = red[4]+red[5]+red[6]+red[7];
    float mean = s*(1.f/256.f), var = sq*(1.f/256.f) - mean*mean;
    float rstd = rsqrtf(var + 1e-5f);
    y[tid] = (v - mean)*rstd*g2[tid] + bt2[tid];
    __syncthreads();
    // W1 + GELU: 4 hidden units per thread
    #pragma unroll
    for (int jj = 0; jj < 4; ++jj) {
        int j = tid*4 + jj;
        const u16* wrow = w1T + (size_t)j*256;
        float a = b1v[j];
        for (int k = 0; k < 256; k += 8) {
            short8 w = *(const short8*)(wrow + k);
            a += y[k+0]*bf2f((u16)w[0]) + y[k+1]*bf2f((u16)w[1])
               + y[k+2]*bf2f((u16)w[2]) + y[k+3]*bf2f((u16)w[3])
               + y[k+4]*bf2f((u16)w[4]) + y[k+5]*bf2f((u16)w[5])
               + y[k+6]*bf2f((u16)w[6]) + y[k+7]*bf2f((u16)w[7]);
        }
        h[j] = gelu_fast(a);
    }
    __syncthreads();
    // W2: col tid
    const u16* w2row = w2T + (size_t)tid*1024;
    float a2 = b2v[tid];
    for (int k = 0; k < 1024; k += 8) {
        short8 w = *(const short8*)(w2row + k);
        a2 += h[k+0]*bf2f((u16)w[0]) + h[k+1]*bf2f((u16)w[1])
            + h[k+2]*bf2f((u16)w[2]) + h[k+3]*bf2f((u16)w[3])
            + h[k+4]*bf2f((u16)w[4]) + h[k+5]*bf2f((u16)w[5])
            + h[k+6]*bf2f((u16)w[6]) + h[k+7]*bf2f((u16)w[7]);
    }
    x[row*256 + tid] = v + a2;             // final CLS-row value for head
}

// ---------------- head ----------------
__global__ void head_kernel(const float* __restrict__ x, const float* __restrict__ obs,
                            const float* __restrict__ fng, const float* __restrict__ fnb,
                            const float* __restrict__ ow, const float* __restrict__ ob,
                            float* __restrict__ out) {
    __shared__ float row[D_ + ADIM_];
    __shared__ float red[8];
    int b = blockIdx.x, tid = threadIdx.x;
    float v = x[((size_t)b*L_)*D_ + tid];
    float s = v, sq = v*v;
    #pragma unroll
    for (int off = 32; off; off >>= 1) { s += __shfl_xor(s, off); sq += __shfl_xor(sq, off); }
    int wave = tid >> 6, lane = tid & 63;
    if (lane == 0) { red[wave] = s; red[4+wave] = sq; }
    __syncthreads();
    s  = red[0]+red[1]+red[2]+red[3];
    sq = red[4]+red[5]+red[6]+red[7];
    float mean = s*(1.f/D_), var = sq*(1.f/D_) - mean*mean;
    float r = rsqrtf(var + 1e-5f);
    row[tid] = (v-mean)*r*fng[tid] + fnb[tid];
    if (tid < ADIM_) row[D_+tid] = obs[(size_t)b*OBSROW + VIS_ + tid];
    __syncthreads();
    float acc = ob[tid];
    for (int j = 0; j < D_+ADIM_; ++j) acc += row[j]*ow[j*OUT_ + tid];
    out[(size_t)b*OUT_ + tid] = acc;
}

// ---------------- launch ----------------
extern "C" void kernel_launch(void* const* d_in, const int* in_sizes, int n_in,
                              void* d_out, int out_size, void* d_ws, size_t ws_size,
                              hipStream_t stream) {
    const float* obs   = (const float*)d_in[0];
    const float* pw    = (const float*)d_in[1];
    const float* pb    = (const float*)d_in[2];
    const float* cls   = (const float*)d_in[3];
    const float* qw    = (const float*)d_in[4];
    const float* kw    = (const float*)d_in[5];
    const float* vw    = (const float*)d_in[6];
    const float* oww   = (const float*)d_in[7];
    const float* gq    = (const float*)d_in[8];
    const float* bq    = (const float*)d_in[9];
    const float* gk    = (const float*)d_in[10];
    const float* bk    = (const float*)d_in[11];
    const float* n1g   = (const float*)d_in[12];
    const float* n1b   = (const float*)d_in[13];
    const float* n2g   = (const float*)d_in[14];
    const float* n2b   = (const float*)d_in[15];
    const float* w1    = (const float*)d_in[16];
    const float* b1    = (const float*)d_in[17];
    const float* w2    = (const float*)d_in[18];
    const float* b2    = (const float*)d_in[19];
    const float* fng   = (const float*)d_in[20];
    const float* fnb   = (const float*)d_in[21];
    const float* outw  = (const float*)d_in[22];
    const float* outb  = (const float*)d_in[23];

    // ---- workspace layout ----
    float* x = (float*)d_ws;                               // NTOK*256 fp32
    u16* qkvT = (u16*)(x + (size_t)NTOK*D_);               // [NL][768][256]
    u16* w1T  = qkvT + (size_t)NL_*768*256;                // [NL][1024][256]
    u16* w2T  = w1T  + (size_t)NL_*262144;                 // [NL][256][1024]
    float* tab = (float*)(w2T + (size_t)NL_*262144);       // L*32*2 fp32
    u16* bufs = (u16*)(tab + (size_t)L_*32*2);

    size_t fixedB = (size_t)((char*)bufs - (char*)d_ws);
    auto needed = [&](int nb) -> size_t {
        size_t t = (size_t)nb * L_;
        return fixedB + (t*256 + (size_t)PADR*256)*2 + (t*1024 + (size_t)PADR*1024)*2
               + (size_t)nb*65536*2 + (size_t)nb*NH_*4096*4;
    };
    int nbc = 32;
    while (nbc > 1 && needed(nbc) > ws_size) nbc >>= 1;
    const int nch = B_ / nbc;
    const int RCn = nbc * L_;

    u16* Xn   = bufs;                                           // nb*L*256 (+pad)
    u16* QKVc = Xn + (size_t)RCn*256 + (size_t)PADR*256;        // ld=768 view
    u16* Hc   = QKVc;                                           // ld=1024 view (same region)
    u16* M2T  = QKVc + (size_t)RCn*1024 + (size_t)PADR*1024;    // nb*256*256
    float* kvf = (float*)(M2T + (size_t)nbc*65536);             // nb*4*4096 f32

    // ---- setup ----
    wcvt_kernel<<<(NL_*65536 + 255)/256, 256, 0, stream>>>(qw,  qkvT, 256, 256, 768*256, 0);
    wcvt_kernel<<<(NL_*65536 + 255)/256, 256, 0, stream>>>(kw,  qkvT, 256, 256, 768*256, 256);
    wcvt_kernel<<<(NL_*65536 + 255)/256, 256, 0, stream>>>(vw,  qkvT, 256, 256, 768*256, 512);
    wcvt_kernel<<<(NL_*262144 + 255)/256, 256, 0, stream>>>(w1, w1T, 1024, 256, 262144, 0);
    wcvt_kernel<<<(NL_*262144 + 255)/256, 256, 0, stream>>>(w2, w2T, 256, 1024, 262144, 0);
    rope_table_kernel<<<(L_*32 + 255)/256, 256, 0, stream>>>(tab);
    proj_kernel<<<(NTOK + 3)/4, 256, 0, stream>>>(obs, pw, pb, cls, x);

    const int gy  = (RCn + 127)/128;
    const int lnb = (RCn + 3)/4;
    const int nbh = nbc*NH_;

    // chunk OUTER, layer INNER: all Xn/QKVc/Hc/M2T/kvf state is consumed within
    // one chunk iteration, so the cross-layer Xn carry is race-free.
    for (int c = 0; c < nch; ++c) {
        float* xc = x + (size_t)c*RCn*D_;
        ln_f2b_kernel<<<lnb, 256, 0, stream>>>(xc, n1g, n1b, Xn, RCn);

        for (int layer = 0; layer < NL_; ++layer) {
            const u16* qkvT_l = qkvT + (size_t)layer*768*256;
            const u16* w1T_l  = w1T  + (size_t)layer*262144;
            const u16* w2T_l  = w2T  + (size_t)layer*262144;
            const float* ow_l = oww + (size_t)layer*65536;
            const float* b1_l = b1 + (size_t)layer*1024;
            const float* b2_l = b2 + (size_t)layer*D_;

            if (layer < NL_-1) {
                // QKV: wide tile (3 x 256-col tiles, large grid)
                gemm_wide<0,false><<<dim3(3, gy), 512, 0, stream>>>(Xn, 256, qkvT_l, nullptr, QKVc, RCn, 768, 256, 768);
                lnrope_kernel<<<dim3(lnb, 2), 256, 0, stream>>>(QKVc, gq + layer*D_, bq + layer*D_,
                                                                gk + layer*D_, bk + layer*D_, tab, RCn, 768);
            } else {
                // LAST LAYER: Q dead except CLS row (computed in tail). KV only.
                gemm_wide<0,false><<<dim3(2, gy), 512, 0, stream>>>(Xn, 256, qkvT_l + 65536, nullptr, QKVc + 256, RCn, 512, 256, 768);
                lnrope_kernel<<<dim3(lnb, 1), 256, 0, stream>>>(QKVc + 256, gk + layer*D_, bk + layer*D_,
                                                                gk + layer*D_, bk + layer*D_, tab, RCn, 768);
            }
            zero_kernel<<<(nbh*4096 + 255)/256, 256, 0, stream>>>(kvf, nbh*4096);
            kv_mfma_kernel<<<dim3(nbh, KV_LSPLIT), 256, 0, stream>>>(QKVc + 256, QKVc + 512, kvf, 768);
            m2_kernel<<<nbh, 256, 0, stream>>>(kvf, ow_l, M2T);

            if (layer < NL_-1) {
                // attn+O-proj delta (narrow, per-batch) -> Xn; x += delta; LN2
                gemm_bf16<0,true><<<dim3(2, 24, nbc), 256, 0, stream>>>(QKVc, 768, M2T, nullptr, Xn, nullptr, L_, 256, 256, 256);
                lnres_kernel<<<lnb, 256, 0, stream>>>(xc, Xn, n2g + layer*D_, n2b + layer*D_, RCn);
                // MLP: W1 wide (+bias,GELU) -> Hc; W2 narrow delta(+bias) -> Xn
                gemm_wide<1,false><<<dim3(4, gy), 512, 0, stream>>>(Xn, 256, w1T_l, b1_l, Hc, RCn, 1024, 256, 1024);
                gemm_bf16<4,false><<<dim3(2, gy), 256, 0, stream>>>(Hc, 1024, w2T_l, b2_l, Xn, nullptr, RCn, 256, 1024, 256);
                lnres_kernel<<<lnb, 256, 0, stream>>>(xc, Xn, n1g + (layer+1)*D_, n1b + (layer+1)*D_, RCn);
            } else {
                // LAST LAYER tail: CLS row only (Q + attnO + LN2 + MLP fused)
                tail_kernel<<<nbc, 256, 0, stream>>>(Xn, qkvT_l, gq + layer*D_, bq + layer*D_,
                                                     M2T, xc, n2g + layer*D_, n2b + layer*D_,
                                                     w1T_l, b1_l, w2T_l, b2_l);
            }
        }
    }

    head_kernel<<<B_, 256, 0, stream>>>(x, obs, fng, fnb, outw, outb, (float*)d_out);
}

// Round 25
// 2144.256 us; speedup vs baseline: 1.4255x; 1.0470x over previous
//
#include <hip/hip_runtime.h>
#include <math.h>

typedef unsigned short u16;
typedef __attribute__((ext_vector_type(8))) short short8;
typedef __attribute__((ext_vector_type(4))) short short4v;
typedef __attribute__((ext_vector_type(4))) float f32x4;

// ---------------- problem constants ----------------
constexpr int B_    = 32;
constexpr int HIST_ = 10, C_ = 11, H_ = 15, W_ = 20;
constexpr int D_    = 256, NH_ = 4, NL_ = 4, HD_ = 64;
constexpr int OUT_  = 256, ADIM_ = 20;
constexpr int L_    = HIST_*H_*W_ + 1;      // 3001
constexpr int VIS_  = HIST_*C_*H_*W_;       // 33000
constexpr int NTOK  = B_*L_;                // 96032
constexpr int OBSROW = VIS_ + ADIM_;        // 33020
constexpr int PADR  = 128;                  // pad rows so tile DMA stays in-bounds

// ---------------- bf16 helpers ----------------
__device__ __forceinline__ float bf2f(u16 u) {
    return __uint_as_float(((unsigned)u) << 16);
}
__device__ __forceinline__ u16 f2bf(float f) {
    unsigned u = __float_as_uint(f);
    u = u + 0x7FFFu + ((u >> 16) & 1u);
    return (u16)(u >> 16);
}
__device__ __forceinline__ f32x4 mfma16(short8 a, short8 b, f32x4 c) {
    return __builtin_amdgcn_mfma_f32_16x16x32_bf16(a, b, c, 0, 0, 0);
}
__device__ __forceinline__ void gload16(const u16* gsrc, u16* ldsdst) {
    __builtin_amdgcn_global_load_lds(
        (const __attribute__((address_space(1))) unsigned int*)gsrc,
        (__attribute__((address_space(3))) unsigned int*)ldsdst,
        16, 0, 0);
}
// tanh-form GELU: ~9 VALU ops (one v_exp). |err| <= ~3e-4.
__device__ __forceinline__ float gelu_fast(float v) {
    float t2 = 1.5957691216f*(v + 0.044715f*v*v*v);
    return v / (1.f + __expf(-t2));
}

// ---------------- setup kernels ----------------
__global__ void zero_kernel(float* __restrict__ p, int n) {
    int i = blockIdx.x*256 + threadIdx.x;
    if (i < n) p[i] = 0.f;
}

// dst[l][dstOff+n][k] = bf16(src[l][k][n]); dst layer stride dstLS
__global__ void wcvt_kernel(const float* __restrict__ src, u16* __restrict__ dst,
                            int Nn, int Kk, int dstLS, int dstOff) {
    int idx = blockIdx.x*256 + threadIdx.x;
    int tot = NL_*Nn*Kk;
    if (idx >= tot) return;
    int l = idx / (Nn*Kk);
    int rem = idx % (Nn*Kk);
    int n = rem / Kk, k = rem % Kk;
    dst[(size_t)l*dstLS + (size_t)(dstOff+n)*Kk + k] = f2bf(src[(size_t)l*Kk*Nn + (size_t)k*Nn + n]);
}

__global__ void rope_table_kernel(float* __restrict__ tab) {
    int idx = blockIdx.x*256 + threadIdx.x;
    if (idx >= L_*32) return;
    int t = idx >> 5, i = idx & 31;
    float freq = powf(10000.f, -2.f*(float)i/(float)HD_);
    float ang = (float)t * freq;
    tab[idx*2]   = cosf(ang);
    tab[idx*2+1] = sinf(ang);
}

// 4 tokens/block (1 per wave); lane owns 4 cols; x is bf16 now.
__global__ __launch_bounds__(256) void proj_kernel(const float* __restrict__ obs,
        const float* __restrict__ pw, const float* __restrict__ pb,
        const float* __restrict__ cls, u16* __restrict__ x) {
    int wave = threadIdx.x >> 6, lane = threadIdx.x & 63;
    int n = blockIdx.x*4 + wave;
    if (n >= NTOK) return;
    int b = n / L_, l = n % L_;
    float4 acc;
    if (l == 0) {
        acc = ((const float4*)cls)[lane];
    } else {
        int t = l - 1;
        int hist = t / (H_*W_);
        int rem  = t % (H_*W_);
        float vv = 0.f;
        if (lane < C_) vv = obs[(size_t)b*OBSROW + hist*(C_*H_*W_) + lane*(H_*W_) + rem];
        acc = ((const float4*)pb)[lane];
        #pragma unroll
        for (int c = 0; c < C_; ++c) {
            float vc = __shfl(vv, c);
            float4 w4 = ((const float4*)(pw + c*D_))[lane];
            acc.x += vc*w4.x; acc.y += vc*w4.y; acc.z += vc*w4.z; acc.w += vc*w4.w;
        }
    }
    short4v o;
    o.x = (short)f2bf(acc.x); o.y = (short)f2bf(acc.y);
    o.z = (short)f2bf(acc.z); o.w = (short)f2bf(acc.w);
    *(short4v*)(x + (size_t)n*D_ + lane*4) = o;
}

// ---------------- LayerNorm bf16 -> bf16 (layer-0 LN1 per chunk) ----------------
__global__ __launch_bounds__(256) void ln_f2b_kernel(const u16* __restrict__ in,
        const float* __restrict__ g, const float* __restrict__ bt,
        u16* __restrict__ out, int ntok) {
    int wave = threadIdx.x >> 6, lane = threadIdx.x & 63;
    int n = blockIdx.x*4 + wave;
    if (n >= ntok) return;
    short4v raw = *(const short4v*)(in + (size_t)n*D_ + lane*4);
    float v0 = bf2f((u16)raw.x), v1 = bf2f((u16)raw.y), v2 = bf2f((u16)raw.z), v3 = bf2f((u16)raw.w);
    float s  = v0+v1+v2+v3;
    float sq = v0*v0+v1*v1+v2*v2+v3*v3;
    #pragma unroll
    for (int off = 32; off; off >>= 1) { s += __shfl_xor(s, off); sq += __shfl_xor(sq, off); }
    float mean = s * (1.f/D_);
    float var  = sq * (1.f/D_) - mean*mean;
    float r = rsqrtf(var + 1e-5f);
    float4 gg = ((const float4*)g)[lane];
    float4 bb = ((const float4*)bt)[lane];
    short4v o;
    o.x = (short)f2bf((v0-mean)*r*gg.x + bb.x);
    o.y = (short)f2bf((v1-mean)*r*gg.y + bb.y);
    o.z = (short)f2bf((v2-mean)*r*gg.z + bb.z);
    o.w = (short)f2bf((v3-mean)*r*gg.w + bb.w);
    *(short4v*)(out + (size_t)n*D_ + lane*4) = o;
}

// ---------------- residual add + LayerNorm: x(bf16) += delta(bf16); Xn = LN(x) ----------------
// CHUNK-LOCAL only — safe under nch>1 with the chunk-OUTER loop.
__global__ __launch_bounds__(256) void lnres_kernel(u16* __restrict__ x,
        u16* __restrict__ dx, const float* __restrict__ g, const float* __restrict__ bt,
        int ntok) {
    int wave = threadIdx.x >> 6, lane = threadIdx.x & 63;
    int n = blockIdx.x*4 + wave;
    if (n >= ntok) return;
    short4v xv = *(const short4v*)(x + (size_t)n*D_ + lane*4);
    short4v d  = *(const short4v*)(dx + (size_t)n*D_ + lane*4);
    float v0 = bf2f((u16)xv.x) + bf2f((u16)d.x);
    float v1 = bf2f((u16)xv.y) + bf2f((u16)d.y);
    float v2 = bf2f((u16)xv.z) + bf2f((u16)d.z);
    float v3 = bf2f((u16)xv.w) + bf2f((u16)d.w);
    short4v xo;
    xo.x = (short)f2bf(v0); xo.y = (short)f2bf(v1);
    xo.z = (short)f2bf(v2); xo.w = (short)f2bf(v3);
    *(short4v*)(x + (size_t)n*D_ + lane*4) = xo;
    float s  = v0+v1+v2+v3;
    float sq = v0*v0+v1*v1+v2*v2+v3*v3;
    #pragma unroll
    for (int off = 32; off; off >>= 1) { s += __shfl_xor(s, off); sq += __shfl_xor(sq, off); }
    float mean = s * (1.f/D_);
    float var  = sq * (1.f/D_) - mean*mean;
    float r = rsqrtf(var + 1e-5f);
    float4 gg = ((const float4*)g)[lane];
    float4 bb = ((const float4*)bt)[lane];
    short4v o;
    o.x = (short)f2bf((v0-mean)*r*gg.x + bb.x);
    o.y = (short)f2bf((v1-mean)*r*gg.y + bb.y);
    o.z = (short)f2bf((v2-mean)*r*gg.z + bb.z);
    o.w = (short)f2bf((v3-mean)*r*gg.w + bb.w);
    *(short4v*)(dx + (size_t)n*D_ + lane*4) = o;
}

// ---------------- fused LN + RoPE + SiLU (merged Q/K: blockIdx.y selects) ----------------
__global__ __launch_bounds__(256) void lnrope_kernel(u16* __restrict__ qk,
        const float* __restrict__ gq, const float* __restrict__ bq,
        const float* __restrict__ gk, const float* __restrict__ bk,
        const float* __restrict__ tab, int ntok, int ld) {
    u16* q = qk + blockIdx.y*256;                  // y=0 -> Q, y=1 -> K
    const float* g  = blockIdx.y ? gk : gq;
    const float* bt = blockIdx.y ? bk : bq;
    int wave = threadIdx.x >> 6, lane = threadIdx.x & 63;
    int n = blockIdx.x*4 + wave;
    if (n >= ntok) return;
    int l = n % L_;
    short4v raw = *(const short4v*)(q + (size_t)n*ld + lane*4);
    float v0 = bf2f((u16)raw.x), v1 = bf2f((u16)raw.y), v2 = bf2f((u16)raw.z), v3 = bf2f((u16)raw.w);
    float s  = v0+v1+v2+v3;
    float sq = v0*v0+v1*v1+v2*v2+v3*v3;
    #pragma unroll
    for (int off = 32; off; off >>= 1) { s += __shfl_xor(s, off); sq += __shfl_xor(sq, off); }
    float mean = s * (1.f/D_);
    float var  = sq * (1.f/D_) - mean*mean;
    float r = rsqrtf(var + 1e-5f);
    float4 gg = ((const float4*)g)[lane];
    float4 bb = ((const float4*)bt)[lane];
    float o0 = (v0-mean)*r*gg.x + bb.x;
    float o1 = (v1-mean)*r*gg.y + bb.y;
    float o2 = (v2-mean)*r*gg.z + bb.z;
    float o3 = (v3-mean)*r*gg.w + bb.w;
    float p0 = __shfl_xor(o0, 8), p1 = __shfl_xor(o1, 8);
    float p2 = __shfl_xor(o2, 8), p3 = __shfl_xor(o3, 8);
    bool first = (lane & 15) < 8;
    const float4* tp = (const float4*)(tab + ((size_t)l*32 + (lane&7)*4)*2);
    float4 t01 = tp[0], t23 = tp[1];
    float r0 = first ? o0*t01.x - p0*t01.y : o0*t01.x + p0*t01.y;
    float r1 = first ? o1*t01.z - p1*t01.w : o1*t01.z + p1*t01.w;
    float r2 = first ? o2*t23.x - p2*t23.y : o2*t23.x + p2*t23.y;
    float r3 = first ? o3*t23.z - p3*t23.w : o3*t23.z + p3*t23.w;
    r0 = r0 / (1.f + expf(-r0));
    r1 = r1 / (1.f + expf(-r1));
    r2 = r2 / (1.f + expf(-r2));
    r3 = r3 / (1.f + expf(-r3));
    short4v o;
    o.x = (short)f2bf(r0); o.y = (short)f2bf(r1);
    o.z = (short)f2bf(r2); o.w = (short)f2bf(r3);
    *(short4v*)(q + (size_t)n*ld + lane*4) = o;
}

// ---------------- bf16 MFMA GEMM (PROVEN core): 128x128, BK=64, single-buffer ----------------
// EPI: 0 bf16 out; 1 +bias,GELU,bf16; 4 +bias, bf16 out
template<int EPI, bool PB>
__global__ __launch_bounds__(256) void gemm_bf16(const u16* __restrict__ A, int lda,
        const u16* __restrict__ Wt, const float* __restrict__ bias,
        u16* __restrict__ Cb, float* __restrict__ Xres, int M, int N, int K, int ldc) {
    __shared__ u16 As[2*128*32];
    __shared__ u16 Bs[2*128*32];
    const int gx = gridDim.x;
    int n = blockIdx.y * gx + blockIdx.x;
    const int nwg = gx * gridDim.y;
    if ((nwg & 7) == 0) n = (n & 7) * (nwg >> 3) + (n >> 3);
    const int bx = n % gx, by = n / gx;
    const int row0 = by*128, col0 = bx*128;

    size_t zrow = 0;
    if (PB) {
        int z = blockIdx.z;
        A  += (size_t)z * M * lda;
        Wt += (size_t)z * N * K;
        zrow = (size_t)z * M;
    }

    const int tid = threadIdx.x;
    const int wid = tid >> 6, lane = tid & 63;
    const int wr = wid >> 1, wc = wid & 1;

    f32x4 acc[4][4];
    #pragma unroll
    for (int i = 0; i < 4; ++i)
        #pragma unroll
        for (int j = 0; j < 4; ++j) {
            f32x4 z; z.x = 0.f; z.y = 0.f; z.z = 0.f; z.w = 0.f;
            acc[i][j] = z;
        }

    const int r0s = wid*32 + (lane>>2);
    const int r1s = r0s + 16;
    const int s0 = ((lane&3) - (r0s>>1)) & 3;
    const int s1 = ((lane&3) - (r1s>>1)) & 3;
    const u16* a0p = A  + (size_t)(row0 + r0s)*lda + s0*8;
    const u16* a1p = A  + (size_t)(row0 + r1s)*lda + s1*8;
    const u16* b0p = Wt + (size_t)(col0 + r0s)*K + s0*8;
    const u16* b1p = Wt + (size_t)(col0 + r1s)*K + s1*8;
    u16* lA0 = As + (wid*2+0)*512;
    u16* lA1 = As + (wid*2+1)*512;
    u16* lB0 = Bs + (wid*2+0)*512;
    u16* lB1 = Bs + (wid*2+1)*512;

    const int kg = lane >> 4, li = lane & 15;
    int aoff[4], boff[4];
    #pragma unroll
    for (int mi = 0; mi < 4; ++mi) {
        int row = wr*64 + mi*16 + li;
        aoff[mi] = row*32 + ((kg + (row>>1)) & 3)*8;
    }
    #pragma unroll
    for (int ni = 0; ni < 4; ++ni) {
        int row = wc*64 + ni*16 + li;
        boff[ni] = row*32 + ((kg + (row>>1)) & 3)*8;
    }

    auto stage = [&](int k0) {
        #pragma unroll
        for (int t = 0; t < 2; ++t) {
            const int ko = k0 + t*32;
            const int lo = t*4096;
            gload16(a0p + ko, lA0 + lo); gload16(a1p + ko, lA1 + lo);
            gload16(b0p + ko, lB0 + lo); gload16(b1p + ko, lB1 + lo);
        }
    };

    stage(0);
    const int nk2 = K >> 6;
    for (int ks = 0; ks < nk2; ++ks) {
        __syncthreads();
        short8 af[2][4], bfr[2][4];
        #pragma unroll
        for (int t = 0; t < 2; ++t) {
            #pragma unroll
            for (int mi = 0; mi < 4; ++mi) af[t][mi] = *(const short8*)(As + t*4096 + aoff[mi]);
            #pragma unroll
            for (int ni = 0; ni < 4; ++ni) bfr[t][ni] = *(const short8*)(Bs + t*4096 + boff[ni]);
        }
        __syncthreads();
        if (ks + 1 < nk2) stage((ks + 1) << 6);
        #pragma unroll
        for (int t = 0; t < 2; ++t)
            #pragma unroll
            for (int mi = 0; mi < 4; ++mi)
                #pragma unroll
                for (int ni = 0; ni < 4; ++ni)
                    acc[mi][ni] = mfma16(af[t][mi], bfr[t][ni], acc[mi][ni]);
    }

    #pragma unroll
    for (int mi = 0; mi < 4; ++mi) {
        int rbase = row0 + wr*64 + mi*16 + kg*4;
        #pragma unroll
        for (int ni = 0; ni < 4; ++ni) {
            int col = col0 + wc*64 + ni*16 + li;
            #pragma unroll
            for (int r = 0; r < 4; ++r) {
                int row = rbase + r;
                if (row >= M) continue;
                float v = acc[mi][ni][r];
                if (EPI == 1 || EPI == 4) v += bias[col];
                if (EPI == 1) v = gelu_fast(v);
                Cb[(zrow + row)*(size_t)ldc + col] = f2bf(v);
            }
        }
    }
}

// ---------------- WIDE GEMM: 128x256 tile, 512 thr (used where grid stays large) ----------------
// Stat-free epilogues. BK=64 (2 subtiles), single-buffered (48 KB LDS).
// EPI: 0 bf16; 1 +bias,GELU.
template<int EPI, bool PB>
__global__ __launch_bounds__(512) void gemm_wide(const u16* __restrict__ A, int lda,
        const u16* __restrict__ Wt, const float* __restrict__ bias,
        u16* __restrict__ Cb, int M, int N, int K, int ldc) {
    __shared__ u16 As[2*4096];             // [subtile][128*32]
    __shared__ u16 Bs[2*8192];             // [subtile][256*32]
    const int gx = gridDim.x;
    int n = blockIdx.y * gx + blockIdx.x;
    const int nwg = gx * gridDim.y;
    if ((nwg & 7) == 0) n = (n & 7) * (nwg >> 3) + (n >> 3);
    const int bx = n % gx, by = n / gx;
    const int row0 = by*128, col0 = bx*256;

    size_t zrow = 0;
    if (PB) {
        int z = blockIdx.z;
        A  += (size_t)z * M * lda;
        Wt += (size_t)z * N * K;
        zrow = (size_t)z * M;
    }

    const int tid = threadIdx.x;
    const int wid = tid >> 6, lane = tid & 63;
    const int kg = lane >> 4, li = lane & 15;

    f32x4 acc[16];
    #pragma unroll
    for (int i = 0; i < 16; ++i) { f32x4 z; z.x=0.f; z.y=0.f; z.z=0.f; z.w=0.f; acc[i]=z; }

    const int ra = wid*16 + (lane>>2);
    const int sa = ((lane&3) - (ra>>1)) & 3;
    const u16* agp = A + (size_t)(row0 + ra)*lda + sa*8;
    const int lAo = wid*512;
    const int rb0 = (wid*2+0)*16 + (lane>>2);
    const int rb1 = (wid*2+1)*16 + (lane>>2);
    const int sb0 = ((lane&3) - (rb0>>1)) & 3;
    const int sb1 = ((lane&3) - (rb1>>1)) & 3;
    const u16* bgp0 = Wt + (size_t)(col0 + rb0)*K + sb0*8;
    const u16* bgp1 = Wt + (size_t)(col0 + rb1)*K + sb1*8;
    const int lB0o = (wid*2+0)*512;
    const int lB1o = (wid*2+1)*512;

    const int arow = wid*16 + li;
    const int aoff = arow*32 + ((kg + (arow>>1)) & 3)*8;
    int boff[16];
    #pragma unroll
    for (int ni = 0; ni < 16; ++ni) {
        int row = ni*16 + li;
        boff[ni] = row*32 + ((kg + (row>>1)) & 3)*8;
    }

    auto stage = [&](int k0) {
        #pragma unroll
        for (int t = 0; t < 2; ++t) {
            const int ko = k0 + t*32;
            gload16(agp  + ko, As + t*4096 + lAo);
            gload16(bgp0 + ko, Bs + t*8192 + lB0o);
            gload16(bgp1 + ko, Bs + t*8192 + lB1o);
        }
    };

    stage(0);
    const int nk2 = K >> 6;
    for (int ks = 0; ks < nk2; ++ks) {
        __syncthreads();                    // DMA for this 64-K tile drained
        short8 af0 = *(const short8*)(As + aoff);
        short8 b0[8], b1[8];
        #pragma unroll
        for (int ni = 0; ni < 8; ++ni) b0[ni] = *(const short8*)(Bs + boff[ni]);
        #pragma unroll
        for (int ni = 0; ni < 8; ++ni) acc[ni] = mfma16(af0, b0[ni], acc[ni]);
        #pragma unroll
        for (int ni = 0; ni < 8; ++ni) b1[ni] = *(const short8*)(Bs + boff[8+ni]);
        #pragma unroll
        for (int ni = 0; ni < 8; ++ni) acc[8+ni] = mfma16(af0, b1[ni], acc[8+ni]);
        short8 af1 = *(const short8*)(As + 4096 + aoff);
        #pragma unroll
        for (int ni = 0; ni < 8; ++ni) b0[ni] = *(const short8*)(Bs + 8192 + boff[ni]);
        #pragma unroll
        for (int ni = 0; ni < 8; ++ni) b1[ni] = *(const short8*)(Bs + 8192 + boff[8+ni]);
        __syncthreads();                    // reads done; LDS reusable
        if (ks + 1 < nk2) stage((ks + 1) << 6);
        #pragma unroll
        for (int ni = 0; ni < 8; ++ni) acc[ni]   = mfma16(af1, b0[ni], acc[ni]);
        #pragma unroll
        for (int ni = 0; ni < 8; ++ni) acc[8+ni] = mfma16(af1, b1[ni], acc[8+ni]);
    }

    #pragma unroll
    for (int r = 0; r < 4; ++r) {
        const int row = row0 + wid*16 + kg*4 + r;
        if (row >= M) continue;
        #pragma unroll
        for (int ni = 0; ni < 16; ++ni) {
            int col = col0 + ni*16 + li;
            float v = acc[ni][r];
            if (EPI == 1) { v += bias[col]; v = gelu_fast(v); }
            Cb[(zrow + row)*(size_t)ldc + col] = f2bf(v);
        }
    }
}

// ---------------- kv = K^T V per (b,h) via MFMA (atomic merge, proven) ----------------
constexpr int KV_LSPLIT = 4;
constexpr int KV_PART   = 768;            // 24 tiles of 32; 4*768 >= L_
__global__ __launch_bounds__(256) void kv_mfma_kernel(const u16* __restrict__ Kt,
        const u16* __restrict__ Vt, float* __restrict__ kvf, int ld) {
    __shared__ u16 kT[64][34];            // [d][l'] transposed, pad 2
    __shared__ u16 vT[64][34];
    const int bh = blockIdx.x;
    const int b = bh >> 2, h = bh & 3;
    const int tid = threadIdx.x;
    const int wid = tid >> 6, lane = tid & 63;
    const int kg = lane >> 4, li = lane & 15;
    const int wm = (wid >> 1)*32, wn = (wid & 1)*32;
    const int sl = tid >> 3;              // 0..31
    const int sd = (tid & 7) * 8;
    const u16* kbase = Kt + ((size_t)b*L_)*ld + h*HD_ + sd;
    const u16* vbase = Vt + ((size_t)b*L_)*ld + h*HD_ + sd;

    f32x4 acc[2][2];
    #pragma unroll
    for (int i = 0; i < 2; ++i)
        #pragma unroll
        for (int j = 0; j < 2; ++j) {
            f32x4 z; z.x=0.f; z.y=0.f; z.z=0.f; z.w=0.f; acc[i][j] = z;
        }

    const int l0p = blockIdx.y * KV_PART;
    for (int t = 0; t < KV_PART/32; ++t) {
        int gl = l0p + t*32 + sl;
        short8 kk = {0,0,0,0,0,0,0,0}, vv = {0,0,0,0,0,0,0,0};
        if (gl < L_) {
            kk = *(const short8*)(kbase + (size_t)gl*ld);
            vv = *(const short8*)(vbase + (size_t)gl*ld);
        }
        __syncthreads();
        #pragma unroll
        for (int j = 0; j < 8; ++j) {
            kT[sd+j][sl] = (u16)kk[j];
            vT[sd+j][sl] = (u16)vv[j];
        }
        __syncthreads();
        short8 a0, a1, b0, b1;
        {
            uint* d0 = (uint*)&a0; const uint* p0 = (const uint*)&kT[wm + li][kg*8];
            uint* d1 = (uint*)&a1; const uint* p1 = (const uint*)&kT[wm + 16 + li][kg*8];
            uint* d2 = (uint*)&b0; const uint* p2 = (const uint*)&vT[wn + li][kg*8];
            uint* d3 = (uint*)&b1; const uint* p3 = (const uint*)&vT[wn + 16 + li][kg*8];
            #pragma unroll
            for (int j = 0; j < 4; ++j) { d0[j]=p0[j]; d1[j]=p1[j]; d2[j]=p2[j]; d3[j]=p3[j]; }
        }
        acc[0][0] = mfma16(a0, b0, acc[0][0]);
        acc[0][1] = mfma16(a0, b1, acc[0][1]);
        acc[1][0] = mfma16(a1, b0, acc[1][0]);
        acc[1][1] = mfma16(a1, b1, acc[1][1]);
    }
    float* base = kvf + (size_t)bh*4096;
    #pragma unroll
    for (int mi = 0; mi < 2; ++mi)
        #pragma unroll
        for (int ni = 0; ni < 2; ++ni)
            #pragma unroll
            for (int r = 0; r < 4; ++r)
                atomicAdd(base + (wm + mi*16 + kg*4 + r)*64 + wn + ni*16 + li,
                          acc[mi][ni][r]);
}

// ---------------- M2T[b][n][h*64+d] = bf16( (1/8) sum_e kv[b,h,d,e] * ow[h*64+e][n] ) ----------------
__global__ __launch_bounds__(256) void m2_kernel(const float* __restrict__ kvf,
        const float* __restrict__ ow, u16* __restrict__ m2t) {
    __shared__ float kvs[64][64];
    const int bh = blockIdx.x;
    const int b = bh >> 2, h = bh & 3;
    const int tid = threadIdx.x;          // n = tid
    #pragma unroll
    for (int p = 0; p < 16; ++p)
        ((float*)kvs)[p*256 + tid] = kvf[(size_t)bh*4096 + p*256 + tid];
    __syncthreads();
    float acc[64];
    #pragma unroll
    for (int d = 0; d < 64; ++d) acc[d] = 0.f;
    for (int e = 0; e < 64; ++e) {
        float w = ow[(size_t)(h*64 + e)*256 + tid];
        #pragma unroll
        for (int d = 0; d < 64; ++d) acc[d] += kvs[d][e] * w;
    }
    u16* dst = m2t + ((size_t)b*256 + tid)*256 + h*64;
    #pragma unroll
    for (int d = 0; d < 64; ++d) dst[d] = f2bf(acc[d]*0.125f);
}

// ---------------- LAST-LAYER TAIL: per CLS row (l=0), fused Q + attnO + LN2 + MLP ----------------
// x is bf16 now. One block per chunk-local batch; 256 threads.
__global__ __launch_bounds__(256) void tail_kernel(const u16* __restrict__ Xn,
        const u16* __restrict__ qwT,      // [256][256] bf16, n-major (layer's Q weights)
        const float* __restrict__ gqv, const float* __restrict__ bqv,
        const u16* __restrict__ m2t, u16* __restrict__ x,
        const float* __restrict__ g2, const float* __restrict__ bt2,
        const u16* __restrict__ w1T, const float* __restrict__ b1v,
        const u16* __restrict__ w2T, const float* __restrict__ b2v) {
    __shared__ float xn0[256];
    __shared__ float qrow[256];
    __shared__ float y[256];
    __shared__ float h[1024];
    __shared__ float red[8];
    const int bl = blockIdx.x;             // chunk-local batch
    const int tid = threadIdx.x;
    const int wave = tid >> 6, lane = tid & 63;
    const size_t row = (size_t)bl * L_;    // chunk-local CLS token row
    xn0[tid] = bf2f(Xn[row*256 + tid]);
    __syncthreads();
    // q_raw[tid] = dot(xn0, qwT[tid][:])
    {
        const u16* qwrow = qwT + (size_t)tid*256;
        float qa = 0.f;
        for (int k = 0; k < 256; k += 8) {
            short8 w = *(const short8*)(qwrow + k);
            qa += xn0[k+0]*bf2f((u16)w[0]) + xn0[k+1]*bf2f((u16)w[1])
                + xn0[k+2]*bf2f((u16)w[2]) + xn0[k+3]*bf2f((u16)w[3])
                + xn0[k+4]*bf2f((u16)w[4]) + xn0[k+5]*bf2f((u16)w[5])
                + xn0[k+6]*bf2f((u16)w[6]) + xn0[k+7]*bf2f((u16)w[7]);
        }
        float s = qa, sq = qa*qa;
        #pragma unroll
        for (int off = 32; off; off >>= 1) { s += __shfl_xor(s, off); sq += __shfl_xor(sq, off); }
        if (lane == 0) { red[wave] = s; red[4+wave] = sq; }
        __syncthreads();
        s  = red[0]+red[1]+red[2]+red[3];
        sq = red[4]+red[5]+red[6]+red[7];
        float mean = s*(1.f/256.f), var = sq*(1.f/256.f) - mean*mean;
        float rstd = rsqrtf(var + 1e-5f);
        float qn = (qa - mean)*rstd*gqv[tid] + bqv[tid];
        qrow[tid] = qn / (1.f + __expf(-qn));
    }
    __syncthreads();
    // attn delta for col tid: dot(q row, M2T[bl][tid][:])
    const u16* mrow = m2t + ((size_t)bl*256 + tid)*256;
    float acc = 0.f;
    for (int d = 0; d < 256; d += 8) {
        short8 w = *(const short8*)(mrow + d);
        acc += qrow[d+0]*bf2f((u16)w[0]) + qrow[d+1]*bf2f((u16)w[1])
             + qrow[d+2]*bf2f((u16)w[2]) + qrow[d+3]*bf2f((u16)w[3])
             + qrow[d+4]*bf2f((u16)w[4]) + qrow[d+5]*bf2f((u16)w[5])
             + qrow[d+6]*bf2f((u16)w[6]) + qrow[d+7]*bf2f((u16)w[7]);
    }
    float v = bf2f(x[row*256 + tid]) + acc;   // post-attn residual
    // LN2 over the 256 values (block reduce)
    float s = v, sq = v*v;
    #pragma unroll
    for (int off = 32; off; off >>= 1) { s += __shfl_xor(s, off); sq += __shfl_xor(sq, off); }
    if (lane == 0) { red[wave] = s; red[4+wave] = sq; }
    __syncthreads();
    s  = red[0]+red[1]+red[2]+red[3];
    sq = red[4]+red[5]+red[6]+red[7];
    float mean = s*(1.f/256.f), var = sq*(1.f/256.f) - mean*mean;
    float rstd = rsqrtf(var + 1e-5f);
    y[tid] = (v - mean)*rstd*g2[tid] + bt2[tid];
    __syncthreads();
    // W1 + GELU: 4 hidden units per thread
    #pragma unroll
    for (int jj = 0; jj < 4; ++jj) {
        int j = tid*4 + jj;
        const u16* wrow = w1T + (size_t)j*256;
        float a = b1v[j];
        for (int k = 0; k < 256; k += 8) {
            short8 w = *(const short8*)(wrow + k);
            a += y[k+0]*bf2f((u16)w[0]) + y[k+1]*bf2f((u16)w[1])
               + y[k+2]*bf2f((u16)w[2]) + y[k+3]*bf2f((u16)w[3])
               + y[k+4]*bf2f((u16)w[4]) + y[k+5]*bf2f((u16)w[5])
               + y[k+6]*bf2f((u16)w[6]) + y[k+7]*bf2f((u16)w[7]);
        }
        h[j] = gelu_fast(a);
    }
    __syncthreads();
    // W2: col tid
    const u16* w2row = w2T + (size_t)tid*1024;
    float a2 = b2v[tid];
    for (int k = 0; k < 1024; k += 8) {
        short8 w = *(const short8*)(w2row + k);
        a2 += h[k+0]*bf2f((u16)w[0]) + h[k+1]*bf2f((u16)w[1])
            + h[k+2]*bf2f((u16)w[2]) + h[k+3]*bf2f((u16)w[3])
            + h[k+4]*bf2f((u16)w[4]) + h[k+5]*bf2f((u16)w[5])
            + h[k+6]*bf2f((u16)w[6]) + h[k+7]*bf2f((u16)w[7]);
    }
    x[row*256 + tid] = f2bf(v + a2);       // final CLS-row value for head
}

// ---------------- head (x bf16) ----------------
__global__ void head_kernel(const u16* __restrict__ x, const float* __restrict__ obs,
                            const float* __restrict__ fng, const float* __restrict__ fnb,
                            const float* __restrict__ ow, const float* __restrict__ ob,
                            float* __restrict__ out) {
    __shared__ float row[D_ + ADIM_];
    __shared__ float red[8];
    int b = blockIdx.x, tid = threadIdx.x;
    float v = bf2f(x[((size_t)b*L_)*D_ + tid]);
    float s = v, sq = v*v;
    #pragma unroll
    for (int off = 32; off; off >>= 1) { s += __shfl_xor(s, off); sq += __shfl_xor(sq, off); }
    int wave = tid >> 6, lane = tid & 63;
    if (lane == 0) { red[wave] = s; red[4+wave] = sq; }
    __syncthreads();
    s  = red[0]+red[1]+red[2]+red[3];
    sq = red[4]+red[5]+red[6]+red[7];
    float mean = s*(1.f/D_), var = sq*(1.f/D_) - mean*mean;
    float r = rsqrtf(var + 1e-5f);
    row[tid] = (v-mean)*r*fng[tid] + fnb[tid];
    if (tid < ADIM_) row[D_+tid] = obs[(size_t)b*OBSROW + VIS_ + tid];
    __syncthreads();
    float acc = ob[tid];
    for (int j = 0; j < D_+ADIM_; ++j) acc += row[j]*ow[j*OUT_ + tid];
    out[(size_t)b*OUT_ + tid] = acc;
}

// ---------------- launch ----------------
extern "C" void kernel_launch(void* const* d_in, const int* in_sizes, int n_in,
                              void* d_out, int out_size, void* d_ws, size_t ws_size,
                              hipStream_t stream) {
    const float* obs   = (const float*)d_in[0];
    const float* pw    = (const float*)d_in[1];
    const float* pb    = (const float*)d_in[2];
    const float* cls   = (const float*)d_in[3];
    const float* qw    = (const float*)d_in[4];
    const float* kw    = (const float*)d_in[5];
    const float* vw    = (const float*)d_in[6];
    const float* oww   = (const float*)d_in[7];
    const float* gq    = (const float*)d_in[8];
    const float* bq    = (const float*)d_in[9];
    const float* gk    = (const float*)d_in[10];
    const float* bk    = (const float*)d_in[11];
    const float* n1g   = (const float*)d_in[12];
    const float* n1b   = (const float*)d_in[13];
    const float* n2g   = (const float*)d_in[14];
    const float* n2b   = (const float*)d_in[15];
    const float* w1    = (const float*)d_in[16];
    const float* b1    = (const float*)d_in[17];
    const float* w2    = (const float*)d_in[18];
    const float* b2    = (const float*)d_in[19];
    const float* fng   = (const float*)d_in[20];
    const float* fnb   = (const float*)d_in[21];
    const float* outw  = (const float*)d_in[22];
    const float* outb  = (const float*)d_in[23];

    // ---- workspace layout ----
    u16* x    = (u16*)d_ws;                                // NTOK*256 bf16
    u16* qkvT = x + (size_t)NTOK*D_;                       // [NL][768][256]
    u16* w1T  = qkvT + (size_t)NL_*768*256;                // [NL][1024][256]
    u16* w2T  = w1T  + (size_t)NL_*262144;                 // [NL][256][1024]
    float* tab = (float*)(w2T + (size_t)NL_*262144);       // L*32*2 fp32
    float* kvf_all = tab + (size_t)L_*32*2;                // NL_*B_*NH_*4096 fp32 (zeroed once)
    u16* bufs = (u16*)(kvf_all + (size_t)NL_*B_*NH_*4096);

    size_t fixedB = (size_t)((char*)bufs - (char*)d_ws);
    auto needed = [&](int nb) -> size_t {
        size_t t = (size_t)nb * L_;
        return fixedB + (t*256 + (size_t)PADR*256)*2 + (t*1024 + (size_t)PADR*1024)*2
               + (size_t)nb*65536*2;
    };
    int nbc = 32;
    while (nbc > 1 && needed(nbc) > ws_size) nbc >>= 1;
    const int nch = B_ / nbc;
    const int RCn = nbc * L_;

    u16* Xn   = bufs;                                           // nb*L*256 (+pad)
    u16* QKVc = Xn + (size_t)RCn*256 + (size_t)PADR*256;        // ld=768 view
    u16* Hc   = QKVc;                                           // ld=1024 view (same region)
    u16* M2T  = QKVc + (size_t)RCn*1024 + (size_t)PADR*1024;    // nb*256*256

    // ---- setup ----
    wcvt_kernel<<<(NL_*65536 + 255)/256, 256, 0, stream>>>(qw,  qkvT, 256, 256, 768*256, 0);
    wcvt_kernel<<<(NL_*65536 + 255)/256, 256, 0, stream>>>(kw,  qkvT, 256, 256, 768*256, 256);
    wcvt_kernel<<<(NL_*65536 + 255)/256, 256, 0, stream>>>(vw,  qkvT, 256, 256, 768*256, 512);
    wcvt_kernel<<<(NL_*262144 + 255)/256, 256, 0, stream>>>(w1, w1T, 1024, 256, 262144, 0);
    wcvt_kernel<<<(NL_*262144 + 255)/256, 256, 0, stream>>>(w2, w2T, 256, 1024, 262144, 0);
    rope_table_kernel<<<(L_*32 + 255)/256, 256, 0, stream>>>(tab);
    zero_kernel<<<(NL_*B_*NH_*4096 + 255)/256, 256, 0, stream>>>(kvf_all, NL_*B_*NH_*4096);
    proj_kernel<<<(NTOK + 3)/4, 256, 0, stream>>>(obs, pw, pb, cls, x);

    const int gy  = (RCn + 127)/128;
    const int lnb = (RCn + 3)/4;
    const int nbh = nbc*NH_;

    // chunk OUTER, layer INNER: all Xn/QKVc/Hc/M2T state is consumed within
    // one chunk iteration, so the cross-layer Xn carry is race-free.
    for (int c = 0; c < nch; ++c) {
        u16* xc = x + (size_t)c*RCn*D_;
        ln_f2b_kernel<<<lnb, 256, 0, stream>>>(xc, n1g, n1b, Xn, RCn);

        for (int layer = 0; layer < NL_; ++layer) {
            const u16* qkvT_l = qkvT + (size_t)layer*768*256;
            const u16* w1T_l  = w1T  + (size_t)layer*262144;
            const u16* w2T_l  = w2T  + (size_t)layer*262144;
            const float* ow_l = oww + (size_t)layer*65536;
            const float* b1_l = b1 + (size_t)layer*1024;
            const float* b2_l = b2 + (size_t)layer*D_;
            float* kvf = kvf_all + ((size_t)(c*NL_ + layer))*nbh*4096;

            if (layer < NL_-1) {
                // QKV: wide tile (3 x 256-col tiles, large grid)
                gemm_wide<0,false><<<dim3(3, gy), 512, 0, stream>>>(Xn, 256, qkvT_l, nullptr, QKVc, RCn, 768, 256, 768);
                lnrope_kernel<<<dim3(lnb, 2), 256, 0, stream>>>(QKVc, gq + layer*D_, bq + layer*D_,
                                                                gk + layer*D_, bk + layer*D_, tab, RCn, 768);
            } else {
                // LAST LAYER: Q dead except CLS row (computed in tail). KV only.
                gemm_wide<0,false><<<dim3(2, gy), 512, 0, stream>>>(Xn, 256, qkvT_l + 65536, nullptr, QKVc + 256, RCn, 512, 256, 768);
                lnrope_kernel<<<dim3(lnb, 1), 256, 0, stream>>>(QKVc + 256, gk + layer*D_, bk + layer*D_,
                                                                gk + layer*D_, bk + layer*D_, tab, RCn, 768);
            }
            kv_mfma_kernel<<<dim3(nbh, KV_LSPLIT), 256, 0, stream>>>(QKVc + 256, QKVc + 512, kvf, 768);
            m2_kernel<<<nbh, 256, 0, stream>>>(kvf, ow_l, M2T);

            if (layer < NL_-1) {
                // attn+O-proj delta (narrow, per-batch) -> Xn; x += delta; LN2
                gemm_bf16<0,true><<<dim3(2, 24, nbc), 256, 0, stream>>>(QKVc, 768, M2T, nullptr, Xn, nullptr, L_, 256, 256, 256);
                lnres_kernel<<<lnb, 256, 0, stream>>>(xc, Xn, n2g + layer*D_, n2b + layer*D_, RCn);
                // MLP: W1 wide (+bias,GELU) -> Hc; W2 narrow delta(+bias) -> Xn
                gemm_wide<1,false><<<dim3(4, gy), 512, 0, stream>>>(Xn, 256, w1T_l, b1_l, Hc, RCn, 1024, 256, 1024);
                gemm_bf16<4,false><<<dim3(2, gy), 256, 0, stream>>>(Hc, 1024, w2T_l, b2_l, Xn, nullptr, RCn, 256, 1024, 256);
                lnres_kernel<<<lnb, 256, 0, stream>>>(xc, Xn, n1g + (layer+1)*D_, n1b + (layer+1)*D_, RCn);
            } else {
                // LAST LAYER tail: CLS row only (Q + attnO + LN2 + MLP fused)
                tail_kernel<<<nbc, 256, 0, stream>>>(Xn, qkvT_l, gq + layer*D_, bq + layer*D_,
                                                     M2T, xc, n2g + layer*D_, n2b + layer*D_,
                                                     w1T_l, b1_l, w2T_l, b2_l);
            }
        }
    }

    head_kernel<<<B_, 256, 0, stream>>>(x, obs, fng, fnb, outw, outb, (float*)d_out);
}

// Round 26
// 2069.781 us; speedup vs baseline: 1.4768x; 1.0360x over previous
//
#include <hip/hip_runtime.h>
#include <math.h>

typedef unsigned short u16;
typedef __attribute__((ext_vector_type(8))) short short8;
typedef __attribute__((ext_vector_type(4))) short short4v;
typedef __attribute__((ext_vector_type(4))) float f32x4;

// ---------------- problem constants ----------------
constexpr int B_    = 32;
constexpr int HIST_ = 10, C_ = 11, H_ = 15, W_ = 20;
constexpr int D_    = 256, NH_ = 4, NL_ = 4, HD_ = 64;
constexpr int OUT_  = 256, ADIM_ = 20;
constexpr int L_    = HIST_*H_*W_ + 1;      // 3001
constexpr int VIS_  = HIST_*C_*H_*W_;       // 33000
constexpr int NTOK  = B_*L_;                // 96032
constexpr int OBSROW = VIS_ + ADIM_;        // 33020
constexpr int PADR  = 128;                  // pad rows so tile DMA stays in-bounds

// ---------------- bf16 helpers ----------------
__device__ __forceinline__ float bf2f(u16 u) {
    return __uint_as_float(((unsigned)u) << 16);
}
__device__ __forceinline__ u16 f2bf(float f) {
    unsigned u = __float_as_uint(f);
    u = u + 0x7FFFu + ((u >> 16) & 1u);
    return (u16)(u >> 16);
}
__device__ __forceinline__ f32x4 mfma16(short8 a, short8 b, f32x4 c) {
    return __builtin_amdgcn_mfma_f32_16x16x32_bf16(a, b, c, 0, 0, 0);
}
__device__ __forceinline__ void gload16(const u16* gsrc, u16* ldsdst) {
    __builtin_amdgcn_global_load_lds(
        (const __attribute__((address_space(1))) unsigned int*)gsrc,
        (__attribute__((address_space(3))) unsigned int*)ldsdst,
        16, 0, 0);
}
// tanh-form GELU: ~9 VALU ops (one v_exp). |err| <= ~3e-4.
__device__ __forceinline__ float gelu_fast(float v) {
    float t2 = 1.5957691216f*(v + 0.044715f*v*v*v);
    return v / (1.f + __expf(-t2));
}

// ---------------- setup kernels ----------------
__global__ void zero_kernel(float* __restrict__ p, int n) {
    int i = blockIdx.x*256 + threadIdx.x;
    if (i < n) p[i] = 0.f;
}

// dst[l][dstOff+n][k] = bf16(src[l][k][n]); dst layer stride dstLS
__global__ void wcvt_kernel(const float* __restrict__ src, u16* __restrict__ dst,
                            int Nn, int Kk, int dstLS, int dstOff) {
    int idx = blockIdx.x*256 + threadIdx.x;
    int tot = NL_*Nn*Kk;
    if (idx >= tot) return;
    int l = idx / (Nn*Kk);
    int rem = idx % (Nn*Kk);
    int n = rem / Kk, k = rem % Kk;
    dst[(size_t)l*dstLS + (size_t)(dstOff+n)*Kk + k] = f2bf(src[(size_t)l*Kk*Nn + (size_t)k*Nn + n]);
}

__global__ void rope_table_kernel(float* __restrict__ tab) {
    int idx = blockIdx.x*256 + threadIdx.x;
    if (idx >= L_*32) return;
    int t = idx >> 5, i = idx & 31;
    float freq = powf(10000.f, -2.f*(float)i/(float)HD_);
    float ang = (float)t * freq;
    tab[idx*2]   = cosf(ang);
    tab[idx*2+1] = sinf(ang);
}

// 4 tokens/block (1 per wave); lane owns 4 cols; x is bf16.
__global__ __launch_bounds__(256) void proj_kernel(const float* __restrict__ obs,
        const float* __restrict__ pw, const float* __restrict__ pb,
        const float* __restrict__ cls, u16* __restrict__ x) {
    int wave = threadIdx.x >> 6, lane = threadIdx.x & 63;
    int n = blockIdx.x*4 + wave;
    if (n >= NTOK) return;
    int b = n / L_, l = n % L_;
    float4 acc;
    if (l == 0) {
        acc = ((const float4*)cls)[lane];
    } else {
        int t = l - 1;
        int hist = t / (H_*W_);
        int rem  = t % (H_*W_);
        float vv = 0.f;
        if (lane < C_) vv = obs[(size_t)b*OBSROW + hist*(C_*H_*W_) + lane*(H_*W_) + rem];
        acc = ((const float4*)pb)[lane];
        #pragma unroll
        for (int c = 0; c < C_; ++c) {
            float vc = __shfl(vv, c);
            float4 w4 = ((const float4*)(pw + c*D_))[lane];
            acc.x += vc*w4.x; acc.y += vc*w4.y; acc.z += vc*w4.z; acc.w += vc*w4.w;
        }
    }
    short4v o;
    o.x = (short)f2bf(acc.x); o.y = (short)f2bf(acc.y);
    o.z = (short)f2bf(acc.z); o.w = (short)f2bf(acc.w);
    *(short4v*)(x + (size_t)n*D_ + lane*4) = o;
}

// ---------------- LayerNorm bf16 -> bf16 (layer-0 LN1 per chunk) ----------------
__global__ __launch_bounds__(256) void ln_f2b_kernel(const u16* __restrict__ in,
        const float* __restrict__ g, const float* __restrict__ bt,
        u16* __restrict__ out, int ntok) {
    int wave = threadIdx.x >> 6, lane = threadIdx.x & 63;
    int n = blockIdx.x*4 + wave;
    if (n >= ntok) return;
    short4v raw = *(const short4v*)(in + (size_t)n*D_ + lane*4);
    float v0 = bf2f((u16)raw.x), v1 = bf2f((u16)raw.y), v2 = bf2f((u16)raw.z), v3 = bf2f((u16)raw.w);
    float s  = v0+v1+v2+v3;
    float sq = v0*v0+v1*v1+v2*v2+v3*v3;
    #pragma unroll
    for (int off = 32; off; off >>= 1) { s += __shfl_xor(s, off); sq += __shfl_xor(sq, off); }
    float mean = s * (1.f/D_);
    float var  = sq * (1.f/D_) - mean*mean;
    float r = rsqrtf(var + 1e-5f);
    float4 gg = ((const float4*)g)[lane];
    float4 bb = ((const float4*)bt)[lane];
    short4v o;
    o.x = (short)f2bf((v0-mean)*r*gg.x + bb.x);
    o.y = (short)f2bf((v1-mean)*r*gg.y + bb.y);
    o.z = (short)f2bf((v2-mean)*r*gg.z + bb.z);
    o.w = (short)f2bf((v3-mean)*r*gg.w + bb.w);
    *(short4v*)(out + (size_t)n*D_ + lane*4) = o;
}

// ---------------- residual add + LayerNorm: x(bf16) += delta(bf16); Xn = LN(x) ----------------
// CHUNK-LOCAL only — safe under nch>1 with the chunk-OUTER loop.
__global__ __launch_bounds__(256) void lnres_kernel(u16* __restrict__ x,
        u16* __restrict__ dx, const float* __restrict__ g, const float* __restrict__ bt,
        int ntok) {
    int wave = threadIdx.x >> 6, lane = threadIdx.x & 63;
    int n = blockIdx.x*4 + wave;
    if (n >= ntok) return;
    short4v xv = *(const short4v*)(x + (size_t)n*D_ + lane*4);
    short4v d  = *(const short4v*)(dx + (size_t)n*D_ + lane*4);
    float v0 = bf2f((u16)xv.x) + bf2f((u16)d.x);
    float v1 = bf2f((u16)xv.y) + bf2f((u16)d.y);
    float v2 = bf2f((u16)xv.z) + bf2f((u16)d.z);
    float v3 = bf2f((u16)xv.w) + bf2f((u16)d.w);
    short4v xo;
    xo.x = (short)f2bf(v0); xo.y = (short)f2bf(v1);
    xo.z = (short)f2bf(v2); xo.w = (short)f2bf(v3);
    *(short4v*)(x + (size_t)n*D_ + lane*4) = xo;
    float s  = v0+v1+v2+v3;
    float sq = v0*v0+v1*v1+v2*v2+v3*v3;
    #pragma unroll
    for (int off = 32; off; off >>= 1) { s += __shfl_xor(s, off); sq += __shfl_xor(sq, off); }
    float mean = s * (1.f/D_);
    float var  = sq * (1.f/D_) - mean*mean;
    float r = rsqrtf(var + 1e-5f);
    float4 gg = ((const float4*)g)[lane];
    float4 bb = ((const float4*)bt)[lane];
    short4v o;
    o.x = (short)f2bf((v0-mean)*r*gg.x + bb.x);
    o.y = (short)f2bf((v1-mean)*r*gg.y + bb.y);
    o.z = (short)f2bf((v2-mean)*r*gg.z + bb.z);
    o.w = (short)f2bf((v3-mean)*r*gg.w + bb.w);
    *(short4v*)(dx + (size_t)n*D_ + lane*4) = o;
}

// ---------------- bf16 MFMA GEMM (PROVEN core): 128x128, BK=64, single-buffer ----------------
// EPI: 0 bf16 out; 1 +bias,GELU,bf16; 4 +bias, bf16 out
template<int EPI, bool PB>
__global__ __launch_bounds__(256) void gemm_bf16(const u16* __restrict__ A, int lda,
        const u16* __restrict__ Wt, const float* __restrict__ bias,
        u16* __restrict__ Cb, float* __restrict__ Xres, int M, int N, int K, int ldc) {
    __shared__ u16 As[2*128*32];
    __shared__ u16 Bs[2*128*32];
    const int gx = gridDim.x;
    int n = blockIdx.y * gx + blockIdx.x;
    const int nwg = gx * gridDim.y;
    if ((nwg & 7) == 0) n = (n & 7) * (nwg >> 3) + (n >> 3);
    const int bx = n % gx, by = n / gx;
    const int row0 = by*128, col0 = bx*128;

    size_t zrow = 0;
    if (PB) {
        int z = blockIdx.z;
        A  += (size_t)z * M * lda;
        Wt += (size_t)z * N * K;
        zrow = (size_t)z * M;
    }

    const int tid = threadIdx.x;
    const int wid = tid >> 6, lane = tid & 63;
    const int wr = wid >> 1, wc = wid & 1;

    f32x4 acc[4][4];
    #pragma unroll
    for (int i = 0; i < 4; ++i)
        #pragma unroll
        for (int j = 0; j < 4; ++j) {
            f32x4 z; z.x = 0.f; z.y = 0.f; z.z = 0.f; z.w = 0.f;
            acc[i][j] = z;
        }

    const int r0s = wid*32 + (lane>>2);
    const int r1s = r0s + 16;
    const int s0 = ((lane&3) - (r0s>>1)) & 3;
    const int s1 = ((lane&3) - (r1s>>1)) & 3;
    const u16* a0p = A  + (size_t)(row0 + r0s)*lda + s0*8;
    const u16* a1p = A  + (size_t)(row0 + r1s)*lda + s1*8;
    const u16* b0p = Wt + (size_t)(col0 + r0s)*K + s0*8;
    const u16* b1p = Wt + (size_t)(col0 + r1s)*K + s1*8;
    u16* lA0 = As + (wid*2+0)*512;
    u16* lA1 = As + (wid*2+1)*512;
    u16* lB0 = Bs + (wid*2+0)*512;
    u16* lB1 = Bs + (wid*2+1)*512;

    const int kg = lane >> 4, li = lane & 15;
    int aoff[4], boff[4];
    #pragma unroll
    for (int mi = 0; mi < 4; ++mi) {
        int row = wr*64 + mi*16 + li;
        aoff[mi] = row*32 + ((kg + (row>>1)) & 3)*8;
    }
    #pragma unroll
    for (int ni = 0; ni < 4; ++ni) {
        int row = wc*64 + ni*16 + li;
        boff[ni] = row*32 + ((kg + (row>>1)) & 3)*8;
    }

    auto stage = [&](int k0) {
        #pragma unroll
        for (int t = 0; t < 2; ++t) {
            const int ko = k0 + t*32;
            const int lo = t*4096;
            gload16(a0p + ko, lA0 + lo); gload16(a1p + ko, lA1 + lo);
            gload16(b0p + ko, lB0 + lo); gload16(b1p + ko, lB1 + lo);
        }
    };

    stage(0);
    const int nk2 = K >> 6;
    for (int ks = 0; ks < nk2; ++ks) {
        __syncthreads();
        short8 af[2][4], bfr[2][4];
        #pragma unroll
        for (int t = 0; t < 2; ++t) {
            #pragma unroll
            for (int mi = 0; mi < 4; ++mi) af[t][mi] = *(const short8*)(As + t*4096 + aoff[mi]);
            #pragma unroll
            for (int ni = 0; ni < 4; ++ni) bfr[t][ni] = *(const short8*)(Bs + t*4096 + boff[ni]);
        }
        __syncthreads();
        if (ks + 1 < nk2) stage((ks + 1) << 6);
        #pragma unroll
        for (int t = 0; t < 2; ++t)
            #pragma unroll
            for (int mi = 0; mi < 4; ++mi)
                #pragma unroll
                for (int ni = 0; ni < 4; ++ni)
                    acc[mi][ni] = mfma16(af[t][mi], bfr[t][ni], acc[mi][ni]);
    }

    #pragma unroll
    for (int mi = 0; mi < 4; ++mi) {
        int rbase = row0 + wr*64 + mi*16 + kg*4;
        #pragma unroll
        for (int ni = 0; ni < 4; ++ni) {
            int col = col0 + wc*64 + ni*16 + li;
            #pragma unroll
            for (int r = 0; r < 4; ++r) {
                int row = rbase + r;
                if (row >= M) continue;
                float v = acc[mi][ni][r];
                if (EPI == 1 || EPI == 4) v += bias[col];
                if (EPI == 1) v = gelu_fast(v);
                Cb[(zrow + row)*(size_t)ldc + col] = f2bf(v);
            }
        }
    }
}

// ---------------- WIDE GEMM: 128x256 tile, 512 thr ----------------
// BK=64 (2 subtiles), single-buffered (48 KB LDS). Sections: col0 = bx*256.
// EPI: 0 bf16 | 1 +bias,GELU | 2 QKV-fused (sec0: LN(gq)+rope+silu, sec1: LN(gk)+rope+silu,
//      sec2: plain) | 3 KV-fused (sec0: LN(gk)+rope+silu, sec1: plain).
// For EPI 2/3 each wave owns 16 FULL rows of ONE section -> row stats via
// in-thread sum + 16-lane shfl (epilogue pattern proven in r21 gemm_w64).
// RoPE partner col +-32 = ni^2 (same thread); table idx (ni&1)*16+li.
template<int EPI, bool PB>
__global__ __launch_bounds__(512) void gemm_wide(const u16* __restrict__ A, int lda,
        const u16* __restrict__ Wt, const float* __restrict__ bias,
        u16* __restrict__ Cb, int M, int N, int K, int ldc,
        const float* __restrict__ gqv = nullptr, const float* __restrict__ bqv = nullptr,
        const float* __restrict__ gkv = nullptr, const float* __restrict__ bkv = nullptr,
        const float* __restrict__ tab = nullptr) {
    __shared__ u16 As[2*4096];             // [subtile][128*32]
    __shared__ u16 Bs[2*8192];             // [subtile][256*32]
    const int gx = gridDim.x;
    int n = blockIdx.y * gx + blockIdx.x;
    const int nwg = gx * gridDim.y;
    if ((nwg & 7) == 0) n = (n & 7) * (nwg >> 3) + (n >> 3);
    const int bx = n % gx, by = n / gx;
    const int row0 = by*128, col0 = bx*256;

    size_t zrow = 0;
    if (PB) {
        int z = blockIdx.z;
        A  += (size_t)z * M * lda;
        Wt += (size_t)z * N * K;
        zrow = (size_t)z * M;
    }

    const int tid = threadIdx.x;
    const int wid = tid >> 6, lane = tid & 63;
    const int kg = lane >> 4, li = lane & 15;

    f32x4 acc[16];
    #pragma unroll
    for (int i = 0; i < 16; ++i) { f32x4 z; z.x=0.f; z.y=0.f; z.z=0.f; z.w=0.f; acc[i]=z; }

    const int ra = wid*16 + (lane>>2);
    const int sa = ((lane&3) - (ra>>1)) & 3;
    const u16* agp = A + (size_t)(row0 + ra)*lda + sa*8;
    const int lAo = wid*512;
    const int rb0 = (wid*2+0)*16 + (lane>>2);
    const int rb1 = (wid*2+1)*16 + (lane>>2);
    const int sb0 = ((lane&3) - (rb0>>1)) & 3;
    const int sb1 = ((lane&3) - (rb1>>1)) & 3;
    const u16* bgp0 = Wt + (size_t)(col0 + rb0)*K + sb0*8;
    const u16* bgp1 = Wt + (size_t)(col0 + rb1)*K + sb1*8;
    const int lB0o = (wid*2+0)*512;
    const int lB1o = (wid*2+1)*512;

    const int arow = wid*16 + li;
    const int aoff = arow*32 + ((kg + (arow>>1)) & 3)*8;
    int boff[16];
    #pragma unroll
    for (int ni = 0; ni < 16; ++ni) {
        int row = ni*16 + li;
        boff[ni] = row*32 + ((kg + (row>>1)) & 3)*8;
    }

    auto stage = [&](int k0) {
        #pragma unroll
        for (int t = 0; t < 2; ++t) {
            const int ko = k0 + t*32;
            gload16(agp  + ko, As + t*4096 + lAo);
            gload16(bgp0 + ko, Bs + t*8192 + lB0o);
            gload16(bgp1 + ko, Bs + t*8192 + lB1o);
        }
    };

    stage(0);
    const int nk2 = K >> 6;
    for (int ks = 0; ks < nk2; ++ks) {
        __syncthreads();                    // DMA for this 64-K tile drained
        short8 af0 = *(const short8*)(As + aoff);
        short8 b0[8], b1[8];
        #pragma unroll
        for (int ni = 0; ni < 8; ++ni) b0[ni] = *(const short8*)(Bs + boff[ni]);
        #pragma unroll
        for (int ni = 0; ni < 8; ++ni) acc[ni] = mfma16(af0, b0[ni], acc[ni]);
        #pragma unroll
        for (int ni = 0; ni < 8; ++ni) b1[ni] = *(const short8*)(Bs + boff[8+ni]);
        #pragma unroll
        for (int ni = 0; ni < 8; ++ni) acc[8+ni] = mfma16(af0, b1[ni], acc[8+ni]);
        short8 af1 = *(const short8*)(As + 4096 + aoff);
        #pragma unroll
        for (int ni = 0; ni < 8; ++ni) b0[ni] = *(const short8*)(Bs + 8192 + boff[ni]);
        #pragma unroll
        for (int ni = 0; ni < 8; ++ni) b1[ni] = *(const short8*)(Bs + 8192 + boff[8+ni]);
        __syncthreads();                    // reads done; LDS reusable
        if (ks + 1 < nk2) stage((ks + 1) << 6);
        #pragma unroll
        for (int ni = 0; ni < 8; ++ni) acc[ni]   = mfma16(af1, b0[ni], acc[ni]);
        #pragma unroll
        for (int ni = 0; ni < 8; ++ni) acc[8+ni] = mfma16(af1, b1[ni], acc[8+ni]);
    }

    if constexpr (EPI == 2 || EPI == 3) {
        const bool doLN = (EPI == 2) ? (bx < 2) : (bx == 0);
        const float* g  = (EPI == 2) ? (bx ? gkv : gqv) : gkv;
        const float* bt = (EPI == 2) ? (bx ? bkv : bqv) : bkv;
        #pragma unroll
        for (int r = 0; r < 4; ++r) {
            const int row = row0 + wid*16 + kg*4 + r;
            const bool ok = row < M;
            if (doLN) {
                float o[16];
                float s = 0.f, sq = 0.f;
                #pragma unroll
                for (int ni = 0; ni < 16; ++ni) { float v = acc[ni][r]; o[ni] = v; s += v; sq += v*v; }
                s += __shfl_xor(s, 1); sq += __shfl_xor(sq, 1);
                s += __shfl_xor(s, 2); sq += __shfl_xor(sq, 2);
                s += __shfl_xor(s, 4); sq += __shfl_xor(sq, 4);
                s += __shfl_xor(s, 8); sq += __shfl_xor(sq, 8);
                float mean = s * (1.f/256.f);
                float var  = sq * (1.f/256.f) - mean*mean;
                float rstd = rsqrtf(var + 1e-5f);
                #pragma unroll
                for (int ni = 0; ni < 16; ++ni) {
                    int col = ni*16 + li;
                    o[ni] = (o[ni] - mean)*rstd*g[col] + bt[col];
                }
                if (ok) {
                    int l = row % L_;
                    #pragma unroll
                    for (int ni = 0; ni < 16; ++ni) {
                        int i32 = (ni&1)*16 + li;
                        float cs = tab[((size_t)l*32 + i32)*2];
                        float sn = tab[((size_t)l*32 + i32)*2 + 1];
                        float prt = o[ni^2];
                        float rv = ((ni&3) < 2) ? o[ni]*cs - prt*sn : o[ni]*cs + prt*sn;
                        rv = rv / (1.f + __expf(-rv));
                        Cb[(size_t)row*ldc + col0 + ni*16 + li] = f2bf(rv);
                    }
                }
            } else if (ok) {
                #pragma unroll
                for (int ni = 0; ni < 16; ++ni)
                    Cb[(size_t)row*ldc + col0 + ni*16 + li] = f2bf(acc[ni][r]);
            }
        }
        return;
    }

    #pragma unroll
    for (int r = 0; r < 4; ++r) {
        const int row = row0 + wid*16 + kg*4 + r;
        if (row >= M) continue;
        #pragma unroll
        for (int ni = 0; ni < 16; ++ni) {
            int col = col0 + ni*16 + li;
            float v = acc[ni][r];
            if (EPI == 1) { v += bias[col]; v = gelu_fast(v); }
            Cb[(zrow + row)*(size_t)ldc + col] = f2bf(v);
        }
    }
}

// ---------------- kv = K^T V per (b,h) via MFMA (atomic merge, proven) ----------------
constexpr int KV_LSPLIT = 4;
constexpr int KV_PART   = 768;            // 24 tiles of 32; 4*768 >= L_
__global__ __launch_bounds__(256) void kv_mfma_kernel(const u16* __restrict__ Kt,
        const u16* __restrict__ Vt, float* __restrict__ kvf, int ld) {
    __shared__ u16 kT[64][34];            // [d][l'] transposed, pad 2
    __shared__ u16 vT[64][34];
    const int bh = blockIdx.x;
    const int b = bh >> 2, h = bh & 3;
    const int tid = threadIdx.x;
    const int wid = tid >> 6, lane = tid & 63;
    const int kg = lane >> 4, li = lane & 15;
    const int wm = (wid >> 1)*32, wn = (wid & 1)*32;
    const int sl = tid >> 3;              // 0..31
    const int sd = (tid & 7) * 8;
    const u16* kbase = Kt + ((size_t)b*L_)*ld + h*HD_ + sd;
    const u16* vbase = Vt + ((size_t)b*L_)*ld + h*HD_ + sd;

    f32x4 acc[2][2];
    #pragma unroll
    for (int i = 0; i < 2; ++i)
        #pragma unroll
        for (int j = 0; j < 2; ++j) {
            f32x4 z; z.x=0.f; z.y=0.f; z.z=0.f; z.w=0.f; acc[i][j] = z;
        }

    const int l0p = blockIdx.y * KV_PART;
    for (int t = 0; t < KV_PART/32; ++t) {
        int gl = l0p + t*32 + sl;
        short8 kk = {0,0,0,0,0,0,0,0}, vv = {0,0,0,0,0,0,0,0};
        if (gl < L_) {
            kk = *(const short8*)(kbase + (size_t)gl*ld);
            vv = *(const short8*)(vbase + (size_t)gl*ld);
        }
        __syncthreads();
        #pragma unroll
        for (int j = 0; j < 8; ++j) {
            kT[sd+j][sl] = (u16)kk[j];
            vT[sd+j][sl] = (u16)vv[j];
        }
        __syncthreads();
        short8 a0, a1, b0, b1;
        {
            uint* d0 = (uint*)&a0; const uint* p0 = (const uint*)&kT[wm + li][kg*8];
            uint* d1 = (uint*)&a1; const uint* p1 = (const uint*)&kT[wm + 16 + li][kg*8];
            uint* d2 = (uint*)&b0; const uint* p2 = (const uint*)&vT[wn + li][kg*8];
            uint* d3 = (uint*)&b1; const uint* p3 = (const uint*)&vT[wn + 16 + li][kg*8];
            #pragma unroll
            for (int j = 0; j < 4; ++j) { d0[j]=p0[j]; d1[j]=p1[j]; d2[j]=p2[j]; d3[j]=p3[j]; }
        }
        acc[0][0] = mfma16(a0, b0, acc[0][0]);
        acc[0][1] = mfma16(a0, b1, acc[0][1]);
        acc[1][0] = mfma16(a1, b0, acc[1][0]);
        acc[1][1] = mfma16(a1, b1, acc[1][1]);
    }
    float* base = kvf + (size_t)bh*4096;
    #pragma unroll
    for (int mi = 0; mi < 2; ++mi)
        #pragma unroll
        for (int ni = 0; ni < 2; ++ni)
            #pragma unroll
            for (int r = 0; r < 4; ++r)
                atomicAdd(base + (wm + mi*16 + kg*4 + r)*64 + wn + ni*16 + li,
                          acc[mi][ni][r]);
}

// ---------------- M2T[b][n][h*64+d] = bf16( (1/8) sum_e kv[b,h,d,e] * ow[h*64+e][n] ) ----------------
__global__ __launch_bounds__(256) void m2_kernel(const float* __restrict__ kvf,
        const float* __restrict__ ow, u16* __restrict__ m2t) {
    __shared__ float kvs[64][64];
    const int bh = blockIdx.x;
    const int b = bh >> 2, h = bh & 3;
    const int tid = threadIdx.x;          // n = tid
    #pragma unroll
    for (int p = 0; p < 16; ++p)
        ((float*)kvs)[p*256 + tid] = kvf[(size_t)bh*4096 + p*256 + tid];
    __syncthreads();
    float acc[64];
    #pragma unroll
    for (int d = 0; d < 64; ++d) acc[d] = 0.f;
    for (int e = 0; e < 64; ++e) {
        float w = ow[(size_t)(h*64 + e)*256 + tid];
        #pragma unroll
        for (int d = 0; d < 64; ++d) acc[d] += kvs[d][e] * w;
    }
    u16* dst = m2t + ((size_t)b*256 + tid)*256 + h*64;
    #pragma unroll
    for (int d = 0; d < 64; ++d) dst[d] = f2bf(acc[d]*0.125f);
}

// ---------------- LAST-LAYER TAIL: per CLS row (l=0), fused Q + attnO + LN2 + MLP ----------------
__global__ __launch_bounds__(256) void tail_kernel(const u16* __restrict__ Xn,
        const u16* __restrict__ qwT,      // [256][256] bf16, n-major (layer's Q weights)
        const float* __restrict__ gqv, const float* __restrict__ bqv,
        const u16* __restrict__ m2t, u16* __restrict__ x,
        const float* __restrict__ g2, const float* __restrict__ bt2,
        const u16* __restrict__ w1T, const float* __restrict__ b1v,
        const u16* __restrict__ w2T, const float* __restrict__ b2v) {
    __shared__ float xn0[256];
    __shared__ float qrow[256];
    __shared__ float y[256];
    __shared__ float h[1024];
    __shared__ float red[8];
    const int bl = blockIdx.x;             // chunk-local batch
    const int tid = threadIdx.x;
    const int wave = tid >> 6, lane = tid & 63;
    const size_t row = (size_t)bl * L_;    // chunk-local CLS token row
    xn0[tid] = bf2f(Xn[row*256 + tid]);
    __syncthreads();
    {
        const u16* qwrow = qwT + (size_t)tid*256;
        float qa = 0.f;
        for (int k = 0; k < 256; k += 8) {
            short8 w = *(const short8*)(qwrow + k);
            qa += xn0[k+0]*bf2f((u16)w[0]) + xn0[k+1]*bf2f((u16)w[1])
                + xn0[k+2]*bf2f((u16)w[2]) + xn0[k+3]*bf2f((u16)w[3])
                + xn0[k+4]*bf2f((u16)w[4]) + xn0[k+5]*bf2f((u16)w[5])
                + xn0[k+6]*bf2f((u16)w[6]) + xn0[k+7]*bf2f((u16)w[7]);
        }
        float s = qa, sq = qa*qa;
        #pragma unroll
        for (int off = 32; off; off >>= 1) { s += __shfl_xor(s, off); sq += __shfl_xor(sq, off); }
        if (lane == 0) { red[wave] = s; red[4+wave] = sq; }
        __syncthreads();
        s  = red[0]+red[1]+red[2]+red[3];
        sq = red[4]+red[5]+red[6]+red[7];
        float mean = s*(1.f/256.f), var = sq*(1.f/256.f) - mean*mean;
        float rstd = rsqrtf(var + 1e-5f);
        float qn = (qa - mean)*rstd*gqv[tid] + bqv[tid];
        qrow[tid] = qn / (1.f + __expf(-qn));
    }
    __syncthreads();
    const u16* mrow = m2t + ((size_t)bl*256 + tid)*256;
    float acc = 0.f;
    for (int d = 0; d < 256; d += 8) {
        short8 w = *(const short8*)(mrow + d);
        acc += qrow[d+0]*bf2f((u16)w[0]) + qrow[d+1]*bf2f((u16)w[1])
             + qrow[d+2]*bf2f((u16)w[2]) + qrow[d+3]*bf2f((u16)w[3])
             + qrow[d+4]*bf2f((u16)w[4]) + qrow[d+5]*bf2f((u16)w[5])
             + qrow[d+6]*bf2f((u16)w[6]) + qrow[d+7]*bf2f((u16)w[7]);
    }
    float v = bf2f(x[row*256 + tid]) + acc;   // post-attn residual
    float s = v, sq = v*v;
    #pragma unroll
    for (int off = 32; off; off >>= 1) { s += __shfl_xor(s, off); sq += __shfl_xor(sq, off); }
    if (lane == 0) { red[wave] = s; red[4+wave] = sq; }
    __syncthreads();
    s  = red[0]+red[1]+red[2]+red[3];
    sq = red[4]+red[5]+red[6]+red[7];
    float mean = s*(1.f/256.f), var = sq*(1.f/256.f) - mean*mean;
    float rstd = rsqrtf(var + 1e-5f);
    y[tid] = (v - mean)*rstd*g2[tid] + bt2[tid];
    __syncthreads();
    #pragma unroll
    for (int jj = 0; jj < 4; ++jj) {
        int j = tid*4 + jj;
        const u16* wrow = w1T + (size_t)j*256;
        float a = b1v[j];
        for (int k = 0; k < 256; k += 8) {
            short8 w = *(const short8*)(wrow + k);
            a += y[k+0]*bf2f((u16)w[0]) + y[k+1]*bf2f((u16)w[1])
               + y[k+2]*bf2f((u16)w[2]) + y[k+3]*bf2f((u16)w[3])
               + y[k+4]*bf2f((u16)w[4]) + y[k+5]*bf2f((u16)w[5])
               + y[k+6]*bf2f((u16)w[6]) + y[k+7]*bf2f((u16)w[7]);
        }
        h[j] = gelu_fast(a);
    }
    __syncthreads();
    const u16* w2row = w2T + (size_t)tid*1024;
    float a2 = b2v[tid];
    for (int k = 0; k < 1024; k += 8) {
        short8 w = *(const short8*)(w2row + k);
        a2 += h[k+0]*bf2f((u16)w[0]) + h[k+1]*bf2f((u16)w[1])
            + h[k+2]*bf2f((u16)w[2]) + h[k+3]*bf2f((u16)w[3])
            + h[k+4]*bf2f((u16)w[4]) + h[k+5]*bf2f((u16)w[5])
            + h[k+6]*bf2f((u16)w[6]) + h[k+7]*bf2f((u16)w[7]);
    }
    x[row*256 + tid] = f2bf(v + a2);       // final CLS-row value for head
}

// ---------------- head (x bf16) ----------------
__global__ void head_kernel(const u16* __restrict__ x, const float* __restrict__ obs,
                            const float* __restrict__ fng, const float* __restrict__ fnb,
                            const float* __restrict__ ow, const float* __restrict__ ob,
                            float* __restrict__ out) {
    __shared__ float row[D_ + ADIM_];
    __shared__ float red[8];
    int b = blockIdx.x, tid = threadIdx.x;
    float v = bf2f(x[((size_t)b*L_)*D_ + tid]);
    float s = v, sq = v*v;
    #pragma unroll
    for (int off = 32; off; off >>= 1) { s += __shfl_xor(s, off); sq += __shfl_xor(sq, off); }
    int wave = tid >> 6, lane = tid & 63;
    if (lane == 0) { red[wave] = s; red[4+wave] = sq; }
    __syncthreads();
    s  = red[0]+red[1]+red[2]+red[3];
    sq = red[4]+red[5]+red[6]+red[7];
    float mean = s*(1.f/D_), var = sq*(1.f/D_) - mean*mean;
    float r = rsqrtf(var + 1e-5f);
    row[tid] = (v-mean)*r*fng[tid] + fnb[tid];
    if (tid < ADIM_) row[D_+tid] = obs[(size_t)b*OBSROW + VIS_ + tid];
    __syncthreads();
    float acc = ob[tid];
    for (int j = 0; j < D_+ADIM_; ++j) acc += row[j]*ow[j*OUT_ + tid];
    out[(size_t)b*OUT_ + tid] = acc;
}

// ---------------- launch ----------------
extern "C" void kernel_launch(void* const* d_in, const int* in_sizes, int n_in,
                              void* d_out, int out_size, void* d_ws, size_t ws_size,
                              hipStream_t stream) {
    const float* obs   = (const float*)d_in[0];
    const float* pw    = (const float*)d_in[1];
    const float* pb    = (const float*)d_in[2];
    const float* cls   = (const float*)d_in[3];
    const float* qw    = (const float*)d_in[4];
    const float* kw    = (const float*)d_in[5];
    const float* vw    = (const float*)d_in[6];
    const float* oww   = (const float*)d_in[7];
    const float* gq    = (const float*)d_in[8];
    const float* bq    = (const float*)d_in[9];
    const float* gk    = (const float*)d_in[10];
    const float* bk    = (const float*)d_in[11];
    const float* n1g   = (const float*)d_in[12];
    const float* n1b   = (const float*)d_in[13];
    const float* n2g   = (const float*)d_in[14];
    const float* n2b   = (const float*)d_in[15];
    const float* w1    = (const float*)d_in[16];
    const float* b1    = (const float*)d_in[17];
    const float* w2    = (const float*)d_in[18];
    const float* b2    = (const float*)d_in[19];
    const float* fng   = (const float*)d_in[20];
    const float* fnb   = (const float*)d_in[21];
    const float* outw  = (const float*)d_in[22];
    const float* outb  = (const float*)d_in[23];

    // ---- workspace layout ----
    u16* x    = (u16*)d_ws;                                // NTOK*256 bf16
    u16* qkvT = x + (size_t)NTOK*D_;                       // [NL][768][256]
    u16* w1T  = qkvT + (size_t)NL_*768*256;                // [NL][1024][256]
    u16* w2T  = w1T  + (size_t)NL_*262144;                 // [NL][256][1024]
    float* tab = (float*)(w2T + (size_t)NL_*262144);       // L*32*2 fp32
    float* kvf_all = tab + (size_t)L_*32*2;                // NL_*B_*NH_*4096 fp32 (zeroed once)
    u16* bufs = (u16*)(kvf_all + (size_t)NL_*B_*NH_*4096);

    size_t fixedB = (size_t)((char*)bufs - (char*)d_ws);
    auto needed = [&](int nb) -> size_t {
        size_t t = (size_t)nb * L_;
        return fixedB + (t*256 + (size_t)PADR*256)*2 + (t*1024 + (size_t)PADR*1024)*2
               + (size_t)nb*65536*2;
    };
    int nbc = 32;
    while (nbc > 1 && needed(nbc) > ws_size) nbc >>= 1;
    const int nch = B_ / nbc;
    const int RCn = nbc * L_;

    u16* Xn   = bufs;                                           // nb*L*256 (+pad)
    u16* QKVc = Xn + (size_t)RCn*256 + (size_t)PADR*256;        // ld=768 view
    u16* Hc   = QKVc;                                           // ld=1024 view (same region)
    u16* M2T  = QKVc + (size_t)RCn*1024 + (size_t)PADR*1024;    // nb*256*256

    // ---- setup ----
    wcvt_kernel<<<(NL_*65536 + 255)/256, 256, 0, stream>>>(qw,  qkvT, 256, 256, 768*256, 0);
    wcvt_kernel<<<(NL_*65536 + 255)/256, 256, 0, stream>>>(kw,  qkvT, 256, 256, 768*256, 256);
    wcvt_kernel<<<(NL_*65536 + 255)/256, 256, 0, stream>>>(vw,  qkvT, 256, 256, 768*256, 512);
    wcvt_kernel<<<(NL_*262144 + 255)/256, 256, 0, stream>>>(w1, w1T, 1024, 256, 262144, 0);
    wcvt_kernel<<<(NL_*262144 + 255)/256, 256, 0, stream>>>(w2, w2T, 256, 1024, 262144, 0);
    rope_table_kernel<<<(L_*32 + 255)/256, 256, 0, stream>>>(tab);
    zero_kernel<<<(NL_*B_*NH_*4096 + 255)/256, 256, 0, stream>>>(kvf_all, NL_*B_*NH_*4096);
    proj_kernel<<<(NTOK + 3)/4, 256, 0, stream>>>(obs, pw, pb, cls, x);

    const int gy  = (RCn + 127)/128;
    const int lnb = (RCn + 3)/4;
    const int nbh = nbc*NH_;

    // chunk OUTER, layer INNER: all Xn/QKVc/Hc/M2T state is consumed within
    // one chunk iteration, so the cross-layer Xn carry is race-free.
    for (int c = 0; c < nch; ++c) {
        u16* xc = x + (size_t)c*RCn*D_;
        ln_f2b_kernel<<<lnb, 256, 0, stream>>>(xc, n1g, n1b, Xn, RCn);

        for (int layer = 0; layer < NL_; ++layer) {
            const u16* qkvT_l = qkvT + (size_t)layer*768*256;
            const u16* w1T_l  = w1T  + (size_t)layer*262144;
            const u16* w2T_l  = w2T  + (size_t)layer*262144;
            const float* ow_l = oww + (size_t)layer*65536;
            const float* b1_l = b1 + (size_t)layer*1024;
            const float* b2_l = b2 + (size_t)layer*D_;
            float* kvf = kvf_all + ((size_t)(c*NL_ + layer))*nbh*4096;

            if (layer < NL_-1) {
                // QKV GEMM with FUSED LN+RoPE+SiLU epilogue on Q/K sections
                gemm_wide<2,false><<<dim3(3, gy), 512, 0, stream>>>(Xn, 256, qkvT_l, nullptr,
                        QKVc, RCn, 768, 256, 768,
                        gq + layer*D_, bq + layer*D_, gk + layer*D_, bk + layer*D_, tab);
            } else {
                // LAST LAYER: KV only; K section gets fused LN+rope+silu
                gemm_wide<3,false><<<dim3(2, gy), 512, 0, stream>>>(Xn, 256, qkvT_l + 65536, nullptr,
                        QKVc + 256, RCn, 512, 256, 768,
                        nullptr, nullptr, gk + layer*D_, bk + layer*D_, tab);
            }
            kv_mfma_kernel<<<dim3(nbh, KV_LSPLIT), 256, 0, stream>>>(QKVc + 256, QKVc + 512, kvf, 768);
            m2_kernel<<<nbh, 256, 0, stream>>>(kvf, ow_l, M2T);

            if (layer < NL_-1) {
                // attn+O-proj delta (narrow, per-batch) -> Xn; x += delta; LN2
                gemm_bf16<0,true><<<dim3(2, 24, nbc), 256, 0, stream>>>(QKVc, 768, M2T, nullptr, Xn, nullptr, L_, 256, 256, 256);
                lnres_kernel<<<lnb, 256, 0, stream>>>(xc, Xn, n2g + layer*D_, n2b + layer*D_, RCn);
                // MLP: W1 wide (+bias,GELU) -> Hc; W2 narrow delta(+bias) -> Xn
                gemm_wide<1,false><<<dim3(4, gy), 512, 0, stream>>>(Xn, 256, w1T_l, b1_l, Hc, RCn, 1024, 256, 1024);
                gemm_bf16<4,false><<<dim3(2, gy), 256, 0, stream>>>(Hc, 1024, w2T_l, b2_l, Xn, nullptr, RCn, 256, 1024, 256);
                lnres_kernel<<<lnb, 256, 0, stream>>>(xc, Xn, n1g + (layer+1)*D_, n1b + (layer+1)*D_, RCn);
            } else {
                // LAST LAYER tail: CLS row only (Q + attnO + LN2 + MLP fused)
                tail_kernel<<<nbc, 256, 0, stream>>>(Xn, qkvT_l, gq + layer*D_, bq + layer*D_,
                                                     M2T, xc, n2g + layer*D_, n2b + layer*D_,
                                                     w1T_l, b1_l, w2T_l, b2_l);
            }
        }
    }

    head_kernel<<<B_, 256, 0, stream>>>(x, obs, fng, fnb, outw, outb, (float*)d_out);
}